// Round 7
// baseline (401.219 us; speedup 1.0000x reference)
//
#include <hip/hip_runtime.h>
#include <cstdint>
#include <cstddef>

#define DEVINL __device__ __forceinline__

typedef float    f32x4 __attribute__((ext_vector_type(4)));
typedef _Float16 f16x8 __attribute__((ext_vector_type(8)));
typedef _Float16 f16x4 __attribute__((ext_vector_type(4)));

// ---------------- constants ----------------
constexpr int BB = 16, NN = 2048, MM = 32768;

// ---------------- ws layout (bytes) ----------------
constexpr size_t OFF_WE1 = 0;                           // 128x64 f16 (Kp padded 6->64)
constexpr size_t OFF_WE2 = OFF_WE1 + 128 * 64 * 2;
constexpr size_t OFF_W1  = OFF_WE2 + 128 * 128 * 2;
constexpr size_t OFF_W2  = OFF_W1  + 3 * 128 * 128 * 2;
constexpr size_t OFF_WF  = OFF_W2  + 3 * 128 * 128 * 2;
constexpr size_t OFF_WC1 = OFF_WF  + 1024 * 384 * 2;
constexpr size_t OFF_WC2 = OFF_WC1 + 512 * 1024 * 2;
constexpr size_t OFF_WC3 = OFF_WC2 + 256 * 512 * 2;     // 128x256 (Opad 50->128)
constexpr size_t OFF_BC2 = OFF_WC3 + 128 * 256 * 2;     // 256 f32
constexpr size_t OFF_BC3 = OFF_BC2 + 256 * 4;           // 128 f32
constexpr size_t OFF_CVEC= OFF_BC3 + 128 * 4;           // 16x512 f32
constexpr size_t OFF_PMAX= OFF_CVEC+ 16 * 512 * 4;      // 16 b x 16 mtile x 1024 o f32 (128-row tiles)
constexpr size_t OFF_PSUM= OFF_PMAX+ 16 * 16 * 1024 * 4;
constexpr size_t OFF_IDX = OFF_PSUM+ 16 * 16 * 1024 * 4;
constexpr size_t OFF_R1  = 8ull << 20;                  // > OFF_IDX + 2MB
constexpr size_t OFF_X0  = OFF_R1;                      // 4MB  (M x 64 f16, k-padded)
constexpr size_t OFF_HT  = OFF_R1 + (4ull  << 20);      // 8MB  (M x 128 f16)
constexpr size_t OFF_TT  = OFF_R1 + (12ull << 20);      // 8MB
constexpr size_t OFF_MT  = OFF_R1 + (20ull << 20);      // 8MB
constexpr size_t OFF_C1  = OFF_R1;                      // 32MB (M x 512 f16), aliases x0/h/t/m (dead)
constexpr size_t OFF_XCAT= OFF_R1 + (32ull << 20);      // 24MB (M x 384 f16)
constexpr size_t OFF_C2  = OFF_XCAT;                    // 16MB (M x 256 f16), aliases xcat (dead)
constexpr size_t OFF_XF  = OFF_XCAT + (24ull << 20);    // 64MB (M x 1024 f16)

// ---------------- fold-all: weights (f16, BN-folded), biases, x0 prep ----------------
__global__ __launch_bounds__(256) void fold_all_kernel(
    const float* We1, const float* ge1, const float* We2, const float* ge2,
    const float* W1,  const float* g1,  const float* W2,  const float* g2,
    const float* Wf,  const float* gf,  const float* Wc1, const float* gc1,
    const float* Wc2, const float* gc2, const float* Wc3,
    const float* gc2b, const float* bc2, const float* bb2, const float* bc3,
    const float* pts, char* ws)
{
    const int bid = blockIdx.x;
    const int tid = threadIdx.x;

    if (bid == 4704) {
        ((float*)(ws + OFF_BC2))[tid] = gc2b[tid] * bc2[tid] + bb2[tid];
        return;
    }
    if (bid == 4705) {
        if (tid < 128) ((float*)(ws + OFF_BC3))[tid] = (tid < 50) ? bc3[tid] : 0.f;
        return;
    }
    if (bid >= 4706) {           // x0 prep: (B,6,N) f32 -> (M x 64) f16 K-contig, zero pad
        int m = (bid - 4706) * 256 + tid;
        int b = m >> 11, n = m & 2047;
        const float* ps = pts + (size_t)b * 6 * 2048 + n;
        _Float16 tmp[64];
#pragma unroll
        for (int c = 0; c < 64; ++c) tmp[c] = (_Float16)0.f;
#pragma unroll
        for (int c = 0; c < 6; ++c) tmp[c] = (_Float16)ps[(size_t)c << 11];
        _Float16* dst = (_Float16*)(ws + OFF_X0) + (size_t)m * 64;
#pragma unroll
        for (int v = 0; v < 8; ++v) *(f16x8*)(dst + v * 8) = *(const f16x8*)(tmp + v * 8);
        return;
    }

    int id, base;
    if      (bid < 32)   { id = 0;  base = 0;    }
    else if (bid < 96)   { id = 1;  base = 32;   }
    else if (bid < 160)  { id = 2;  base = 96;   }
    else if (bid < 224)  { id = 3;  base = 160;  }
    else if (bid < 288)  { id = 4;  base = 224;  }
    else if (bid < 352)  { id = 5;  base = 288;  }
    else if (bid < 416)  { id = 6;  base = 352;  }
    else if (bid < 480)  { id = 7;  base = 416;  }
    else if (bid < 2016) { id = 8;  base = 480;  }
    else if (bid < 4064) { id = 9;  base = 2016; }
    else if (bid < 4576) { id = 10; base = 4064; }
    else                 { id = 11; base = 4576; }

    const float* src = nullptr; const float* g = nullptr; _Float16* dst = nullptr;
    int O = 0, K = 0, lds = 0, Kp = 0;
    switch (id) {
        case 0:  src = We1; g = ge1; O = 128; K = 6;    lds = 6;    Kp = 64;   dst = (_Float16*)(ws + OFF_WE1); break;
        case 1:  src = We2; g = ge2; O = 128; K = 128;  lds = 128;  Kp = 128;  dst = (_Float16*)(ws + OFF_WE2); break;
        case 2: case 3: case 4: {
            int i = id - 2;
            src = W1 + (size_t)i * 16384; g = g1 + i * 128; O = 128; K = 128; lds = 128; Kp = 128;
            dst = (_Float16*)(ws + OFF_W1) + (size_t)i * 16384; break; }
        case 5: case 6: case 7: {
            int i = id - 5;
            src = W2 + (size_t)i * 16384; g = g2 + i * 128; O = 128; K = 128; lds = 128; Kp = 128;
            dst = (_Float16*)(ws + OFF_W2) + (size_t)i * 16384; break; }
        case 8:  src = Wf;  g = gf;  O = 1024; K = 384;  lds = 384;  Kp = 384;  dst = (_Float16*)(ws + OFF_WF);  break;
        case 9:  src = Wc1; g = gc1; O = 512;  K = 1024; lds = 3136; Kp = 1024; dst = (_Float16*)(ws + OFF_WC1); break;
        case 10: src = Wc2; g = gc2; O = 256;  K = 512;  lds = 512;  Kp = 512;  dst = (_Float16*)(ws + OFF_WC2); break;
        default: src = Wc3; g = nullptr; O = 50; K = 256; lds = 256; Kp = 256;  dst = (_Float16*)(ws + OFF_WC3); break;
    }
    int e = (bid - base) * 256 + tid;
    int o = e / Kp, k = e - o * Kp;
    float v = 0.f;
    if (o < O && k < K) {
        v = src[(size_t)o * lds + k];
        if (g) v *= g[o];
    }
    dst[e] = (_Float16)v;
}

// ---------------- KNN v8: top-4 bound pass -> survivor buffer -> exact select ----------------
DEVINL float knn_dist(const float4 pq, const float4 pm) {
    float t = pq.x * pm.x;
    t = fmaf(pq.y, pm.y, t);
    t = fmaf(pq.z, pm.z, t);
    return fmaf(-2.f, t, pm.w);
}

#define KNN_DINS(X) do { \
    const float x_ = (X); \
    d15 = __builtin_amdgcn_fmed3f(x_, d14, d15); \
    d14 = __builtin_amdgcn_fmed3f(x_, d13, d14); \
    d13 = __builtin_amdgcn_fmed3f(x_, d12, d13); \
    d12 = __builtin_amdgcn_fmed3f(x_, d11, d12); \
    d11 = __builtin_amdgcn_fmed3f(x_, d10, d11); \
    d10 = __builtin_amdgcn_fmed3f(x_, d9,  d10); \
    d9  = __builtin_amdgcn_fmed3f(x_, d8,  d9);  \
    d8  = __builtin_amdgcn_fmed3f(x_, d7,  d8);  \
    d7  = __builtin_amdgcn_fmed3f(x_, d6,  d7);  \
    d6  = __builtin_amdgcn_fmed3f(x_, d5,  d6);  \
    d5  = __builtin_amdgcn_fmed3f(x_, d4,  d5);  \
    d4  = __builtin_amdgcn_fmed3f(x_, d3,  d4);  \
    d3  = __builtin_amdgcn_fmed3f(x_, d2,  d3);  \
    d2  = __builtin_amdgcn_fmed3f(x_, d1,  d2);  \
    d1  = __builtin_amdgcn_fmed3f(x_, d0,  d1);  \
    d0  = __builtin_amdgcn_fmed3f(x_, -3.4e38f, d0); \
} while (0)

// compare-exchange (ascending)
#define KNN_CE(A, B) { const float lo_ = fminf(A, B), hi_ = fmaxf(A, B); A = lo_; B = hi_; }

// merge own ascending d0..d15 with lane^OFF's ascending list, keep lowest 16 sorted.
#define KNN_MERGE(OFF) do { \
    const float n0  = __shfl_xor(d0,  OFF), n1  = __shfl_xor(d1,  OFF), \
                n2  = __shfl_xor(d2,  OFF), n3  = __shfl_xor(d3,  OFF), \
                n4  = __shfl_xor(d4,  OFF), n5  = __shfl_xor(d5,  OFF), \
                n6  = __shfl_xor(d6,  OFF), n7  = __shfl_xor(d7,  OFF), \
                n8  = __shfl_xor(d8,  OFF), n9  = __shfl_xor(d9,  OFF), \
                n10 = __shfl_xor(d10, OFF), n11 = __shfl_xor(d11, OFF), \
                n12 = __shfl_xor(d12, OFF), n13 = __shfl_xor(d13, OFF), \
                n14 = __shfl_xor(d14, OFF), n15 = __shfl_xor(d15, OFF); \
    d0  = fminf(d0,  n15); d1  = fminf(d1,  n14); d2  = fminf(d2,  n13); d3  = fminf(d3,  n12); \
    d4  = fminf(d4,  n11); d5  = fminf(d5,  n10); d6  = fminf(d6,  n9);  d7  = fminf(d7,  n8);  \
    d8  = fminf(d8,  n7);  d9  = fminf(d9,  n6);  d10 = fminf(d10, n5);  d11 = fminf(d11, n4);  \
    d12 = fminf(d12, n3);  d13 = fminf(d13, n2);  d14 = fminf(d14, n1);  d15 = fminf(d15, n0);  \
    KNN_CE(d0, d8)  KNN_CE(d1, d9)  KNN_CE(d2, d10) KNN_CE(d3, d11) \
    KNN_CE(d4, d12) KNN_CE(d5, d13) KNN_CE(d6, d14) KNN_CE(d7, d15) \
    KNN_CE(d0, d4)  KNN_CE(d1, d5)  KNN_CE(d2, d6)  KNN_CE(d3, d7)  \
    KNN_CE(d8, d12) KNN_CE(d9, d13) KNN_CE(d10,d14) KNN_CE(d11,d15) \
    KNN_CE(d0, d2)  KNN_CE(d1, d3)  KNN_CE(d4, d6)  KNN_CE(d5, d7)  \
    KNN_CE(d8, d10) KNN_CE(d9, d11) KNN_CE(d12,d14) KNN_CE(d13,d15) \
    KNN_CE(d0, d1)  KNN_CE(d2, d3)  KNN_CE(d4, d5)  KNN_CE(d6, d7)  \
    KNN_CE(d8, d9)  KNN_CE(d10,d11) KNN_CE(d12,d13) KNN_CE(d14,d15) \
} while (0)

__global__ __launch_bounds__(256) void knn_kernel(const float* __restrict__ pts, int* __restrict__ idxout)
{
    __shared__ float4 P[2048];              // 32KB, stays intact for all passes
    __shared__ unsigned short buf[32][96];  // 6KB survivor indices per query
    __shared__ int cnt[32];
    __shared__ int wcnt[32];
    const int tid = threadIdx.x;
    const int b = blockIdx.x;
    const float* pb = pts + (size_t)b * 6 * 2048;
    for (int i = tid; i < 2048; i += 256) {
        float x = pb[i];
        float y = pb[2048 + i];
        float z = pb[4096 + i];
        P[i] = make_float4(x, y, z, x * x + y * y + z * z);
    }
    if (tid < 32) { cnt[tid] = 0; wcnt[tid] = 0; }
    __syncthreads();

    const int p = tid & 7;          // candidate partition (m == 8*it + p)
    const int g = tid >> 3;         // query within block (0..31); group = 8 consecutive lanes
    const int q = blockIdx.y * 32 + g;
    const float4 pq = P[q];

    // ---- pass 1: per-lane top-4 over this lane's 256-candidate partition ----
    float d0 = 3.4e38f, d1 = 3.4e38f, d2 = 3.4e38f, d3 = 3.4e38f;
#pragma unroll 4
    for (int it = 0; it < 256; ++it) {
        const float4 pm = P[it * 8 + p];
        const float x = knn_dist(pq, pm);
        d3 = __builtin_amdgcn_fmed3f(x, d2, d3);
        d2 = __builtin_amdgcn_fmed3f(x, d1, d2);
        d1 = __builtin_amdgcn_fmed3f(x, d0, d1);
        d0 = fminf(x, d0);
    }
    float d4 = 3.4e38f, d5 = 3.4e38f, d6 = 3.4e38f, d7 = 3.4e38f,
          d8 = 3.4e38f, d9 = 3.4e38f, d10 = 3.4e38f, d11 = 3.4e38f,
          d12 = 3.4e38f, d13 = 3.4e38f, d14 = 3.4e38f, d15 = 3.4e38f;
    KNN_MERGE(1);
    KNN_MERGE(2);
    KNN_MERGE(4);
    const float tub = d15;          // 16th-smallest of union of top-4s; tub >= d*

    // ---- pass 2: collect survivor indices (d <= tub) ----
#pragma unroll 4
    for (int it = 0; it < 256; ++it) {
        const int m = it * 8 + p;
        const float d = knn_dist(pq, P[m]);
        if (d <= tub) {
            const int pos = atomicAdd(&cnt[g], 1);
            if (pos < 96) buf[g][pos] = (unsigned short)m;
        }
    }
    int C = cnt[g];                 // same-wave LDS ops: no barrier needed
    if (C > 96) C = 96;

    // ---- pass 3: exact top-16 among the C survivors (8 lanes split them) ----
    d0 = 3.4e38f; d1 = 3.4e38f; d2 = 3.4e38f; d3 = 3.4e38f;
    d4 = 3.4e38f; d5 = 3.4e38f; d6 = 3.4e38f; d7 = 3.4e38f;
    d8 = 3.4e38f; d9 = 3.4e38f; d10 = 3.4e38f; d11 = 3.4e38f;
    d12 = 3.4e38f; d13 = 3.4e38f; d14 = 3.4e38f; d15 = 3.4e38f;
    for (int j = p; j < C; j += 8) {
        const int m = buf[g][j];
        const float x = knn_dist(pq, P[m]);
        KNN_DINS(x);
    }
    KNN_MERGE(1);
    KNN_MERGE(2);
    KNN_MERGE(4);
    const float t = d15;            // exact 16th-smallest distance

    // ---- final write: survivors with d <= t, capped at 16 (tie-arbitrary, as before) ----
    int* op = idxout + (((size_t)(b << 11) + q) << 4);
    for (int j = p; j < C; j += 8) {
        const int m = buf[g][j];
        const float d = knn_dist(pq, P[m]);
        if (d <= t) {
            const int pos = atomicAdd(&wcnt[g], 1);
            if (pos < 16) op[pos] = m;   // order-scrambled: consumer is a max over the set
        }
    }
}

// ---------------- GEMM v7 (256x256, 8-wave, dbuf counted-vmcnt): used for Wc1 (long-K) ----------------
__global__ __launch_bounds__(512, 2) void gemm256(
    const _Float16* __restrict__ W, const _Float16* __restrict__ X,
    _Float16* __restrict__ Y, const float* __restrict__ bias,
    int Kp, int ldX, int ldY, int Opad, int act, int biasPerBatch)
{
    constexpr int ASZ = 256 * 64;               // A-tile f16 elems (= B-tile)
    __shared__ _Float16 SH[65536];              // 2 x (ASZ + ASZ) = 128KB
    const int tid  = threadIdx.x;
    const int lane = tid & 63, wave = tid >> 6;
    const int r = lane & 15, quad = lane >> 4;
    const int wo = wave & 3, wm = wave >> 2;    // wave: o [wo*64,+64), m [wm*128,+128)
    const int m_blk = blockIdx.x * 256, o_blk = blockIdx.y * 256;
    const int nt = Kp >> 6;

    f32x4 acc[4][8];
#pragma unroll
    for (int a = 0; a < 4; ++a)
#pragma unroll
        for (int c = 0; c < 8; ++c) acc[a][c] = (f32x4){0.f, 0.f, 0.f, 0.f};

    const int srow  = wave * 8 + (lane >> 3);   // 0..63
    const int sslot = lane & 7;

    auto STAGE = [&](int bufi, int k0) {
        _Float16* As = SH + bufi * (2 * ASZ);
        _Float16* Bs = As + ASZ;
#pragma unroll
        for (int t = 0; t < 4; ++t) {           // A: 256 rows, 64/instr
            const int rowA = t * 64 + srow;
            const int gk = k0 + ((sslot ^ (rowA & 7)) << 3);
            const _Float16* gA = W + (size_t)(o_blk + rowA) * Kp + gk;
            __builtin_amdgcn_global_load_lds(
                (const __attribute__((address_space(1))) unsigned int*)gA,
                (__attribute__((address_space(3))) unsigned int*)(As + t * 4096 + wave * 512),
                16, 0, 0);
        }
#pragma unroll
        for (int t = 0; t < 4; ++t) {           // B: 256 rows
            const int rowB = t * 64 + srow;
            const int gk = k0 + ((sslot ^ (rowB & 7)) << 3);
            const _Float16* gB = X + (size_t)(m_blk + rowB) * ldX + gk;
            __builtin_amdgcn_global_load_lds(
                (const __attribute__((address_space(1))) unsigned int*)gB,
                (__attribute__((address_space(3))) unsigned int*)(Bs + t * 4096 + wave * 512),
                16, 0, 0);
        }
    };

    STAGE(0, 0);
    int cur = 0;
    for (int t = 0; t < nt; ++t) {
        if (t + 1 < nt) {
            STAGE(cur ^ 1, (t + 1) << 6);       // issue next tile's loads early
            asm volatile("s_waitcnt vmcnt(8)" ::: "memory");   // drain current tile only
        } else {
            asm volatile("s_waitcnt vmcnt(0)" ::: "memory");
        }
        __builtin_amdgcn_sched_barrier(0);
        __builtin_amdgcn_s_barrier();
        asm volatile("" ::: "memory");          // ds_reads stay BELOW the barrier

        const _Float16* As = SH + cur * (2 * ASZ);
        const _Float16* Bs = As + ASZ;
        __builtin_amdgcn_s_setprio(1);
#pragma unroll
        for (int ks = 0; ks < 2; ++ks) {
            f16x8 af[4], bf[8];
#pragma unroll
            for (int oi = 0; oi < 4; ++oi) {
                const int row = (wo << 6) + (oi << 4) + r;
                const int slot = (ks * 4 + quad) ^ (row & 7);
                af[oi] = *(const f16x8*)(As + row * 64 + slot * 8);
            }
#pragma unroll
            for (int mi = 0; mi < 8; ++mi) {
                const int row = (wm << 7) + (mi << 4) + r;
                const int slot = (ks * 4 + quad) ^ (row & 7);
                bf[mi] = *(const f16x8*)(Bs + row * 64 + slot * 8);
            }
#pragma unroll
            for (int oi = 0; oi < 4; ++oi)
#pragma unroll
                for (int mi = 0; mi < 8; ++mi)
                    acc[oi][mi] = __builtin_amdgcn_mfma_f32_16x16x32_f16(af[oi], bf[mi], acc[oi][mi], 0, 0, 0);
        }
        __builtin_amdgcn_s_setprio(0);
        asm volatile("" ::: "memory");          // ds_reads stay ABOVE the barrier
        __builtin_amdgcn_s_barrier();           // all waves done reading buf[cur]
        cur ^= 1;
    }
    __syncthreads();   // SH reusable as output tile

    // epilogue: stage [256m][256o] f16 tile in LDS (XOR-swizzled), coalesced writeback
    const int bb = biasPerBatch ? (m_blk >> 11) * Opad : 0;
    _Float16* OT = SH;
#pragma unroll
    for (int oi = 0; oi < 4; ++oi) {
        const int ol = (wo << 6) + (oi << 4) + (quad << 2);    // local o, 4-aligned
        const f32x4 bv = *(const f32x4*)(bias + bb + o_blk + ol);
#pragma unroll
        for (int mi = 0; mi < 8; ++mi) {
            const int row = (wm << 7) + (mi << 4) + r;         // local m
            f32x4 v = acc[oi][mi] + bv;
            f16x4 ov;
#pragma unroll
            for (int j = 0; j < 4; ++j) {
                float x = v[j];
                if (act == 1)      x = (x > 0.f) ? x : 0.0f;
                else if (act == 2) x = (x > 0.f) ? x : 0.2f * x;
                ov[j] = (_Float16)x;
            }
            const int s = (ol >> 2) ^ (row & 31);              // swizzled 8B slot (0..63)
            *(f16x4*)(OT + row * 256 + s * 4) = ov;
        }
    }
    __syncthreads();
#pragma unroll
    for (int p2 = 0; p2 < 16; ++p2) {
        const int g = (p2 << 9) + tid;
        const int row = g >> 5, c = g & 31;                    // 32 x 16B granules per row
        const int s0 = ((c << 1)) ^ (row & 31);
        const int s1 = ((c << 1) | 1) ^ (row & 31);
        f16x4 a  = *(const f16x4*)(OT + row * 256 + s0 * 4);
        f16x4 b2 = *(const f16x4*)(OT + row * 256 + s1 * 4);
        f16x8 o8;
        o8[0] = a[0]; o8[1] = a[1]; o8[2] = a[2]; o8[3] = a[3];
        o8[4] = b2[0]; o8[5] = b2[1]; o8[6] = b2[2]; o8[7] = b2[3];
        *(f16x8*)(Y + (size_t)(m_blk + row) * ldY + o_blk + (c << 3)) = o8;
    }
}

// ---------------- GEMM v5b: TM(64|128) x 128o tile, BK=64, dbuf, counted vmcnt, fused pooling ----------------
template<int TM>
__global__ __launch_bounds__(256) void gemm_tile(
    const _Float16* __restrict__ W, const _Float16* __restrict__ X,
    _Float16* __restrict__ Y, float* __restrict__ Y32,
    const float* __restrict__ bias, const _Float16* __restrict__ Res,
    int Kp, int ldX, int xoff, int ldY, int yoff, int Opad,
    int act, int biasPerBatch, int ldR, int roff, int Olimit,
    float* __restrict__ pmax, float* __restrict__ psum)
{
    constexpr int MI = TM / 32;                 // m-frags per wave
    constexpr int ASZ = 128 * 64;               // A-tile f16 elems
    constexpr int BSZ = TM * 64;                // B-tile f16 elems
    __shared__ _Float16 SH[2 * (ASZ + BSZ)];    // double-buffered As|Bs ; reused as output tile

    const int tid  = threadIdx.x;
    const int lane = tid & 63, wave = tid >> 6;
    const int r = lane & 15, quad = lane >> 4;
    const int m_blk = blockIdx.x * TM, o_blk = blockIdx.y * 128;
    const int oh = (wave >> 1) * 64, mh = (wave & 1) * (TM / 2);

    f32x4 acc[4][MI];
#pragma unroll
    for (int a = 0; a < 4; ++a)
#pragma unroll
        for (int c = 0; c < MI; ++c) acc[a][c] = (f32x4){0.f, 0.f, 0.f, 0.f};

    const int srow  = wave * 8 + (lane >> 3);
    const int sslot = lane & 7;

    auto STAGE = [&](int bufi, int k0) {
        _Float16* As = SH + bufi * (ASZ + BSZ);
        _Float16* Bs = As + ASZ;
#pragma unroll
        for (int t = 0; t < 4; ++t) {           // A: 128 rows
            const int rowA = t * 32 + srow;
            const int gk = k0 + ((sslot ^ (rowA & 7)) << 3);
            const _Float16* gA = W + (size_t)(o_blk + rowA) * Kp + gk;
            __builtin_amdgcn_global_load_lds(
                (const __attribute__((address_space(1))) unsigned int*)gA,
                (__attribute__((address_space(3))) unsigned int*)(As + t * 2048 + wave * 512),
                16, 0, 0);
        }
#pragma unroll
        for (int t = 0; t < TM / 32; ++t) {     // B: TM rows
            const int rowB = t * 32 + srow;
            const int gk = k0 + ((sslot ^ (rowB & 7)) << 3);
            const _Float16* gB = X + (size_t)(m_blk + rowB) * ldX + xoff + gk;
            __builtin_amdgcn_global_load_lds(
                (const __attribute__((address_space(1))) unsigned int*)gB,
                (__attribute__((address_space(3))) unsigned int*)(Bs + t * 2048 + wave * 512),
                16, 0, 0);
        }
    };

    const int nt = Kp >> 6;
    STAGE(0, 0);
    int cur = 0;
    for (int t = 0; t < nt; ++t) {
        if (t + 1 < nt) {
            STAGE(cur ^ 1, (t + 1) << 6);       // issue next tile's loads early
            if constexpr (TM == 128) asm volatile("s_waitcnt vmcnt(8)" ::: "memory");
            else                     asm volatile("s_waitcnt vmcnt(6)" ::: "memory");
        } else {
            asm volatile("s_waitcnt vmcnt(0)" ::: "memory");
        }
        __builtin_amdgcn_sched_barrier(0);
        __builtin_amdgcn_s_barrier();
        asm volatile("" ::: "memory");

        const _Float16* As = SH + cur * (ASZ + BSZ);
        const _Float16* Bs = As + ASZ;
        __builtin_amdgcn_s_setprio(1);
#pragma unroll
        for (int ks = 0; ks < 2; ++ks) {
            f16x8 af[4], bf[MI];
#pragma unroll
            for (int oi = 0; oi < 4; ++oi) {
                const int row = oh + oi * 16 + r;
                const int slot = (ks * 4 + quad) ^ (row & 7);
                af[oi] = *(const f16x8*)(As + row * 64 + slot * 8);
            }
#pragma unroll
            for (int mi = 0; mi < MI; ++mi) {
                const int row = mh + mi * 16 + r;
                const int slot = (ks * 4 + quad) ^ (row & 7);
                bf[mi] = *(const f16x8*)(Bs + row * 64 + slot * 8);
            }
#pragma unroll
            for (int oi = 0; oi < 4; ++oi)
#pragma unroll
                for (int mi = 0; mi < MI; ++mi)
                    acc[oi][mi] = __builtin_amdgcn_mfma_f32_16x16x32_f16(af[oi], bf[mi], acc[oi][mi], 0, 0, 0);
        }
        __builtin_amdgcn_s_setprio(0);
        asm volatile("" ::: "memory");
        __builtin_amdgcn_s_barrier();
        cur ^= 1;
    }

    const int bb = biasPerBatch ? (m_blk >> 11) * Opad : 0;
    __syncthreads();   // done reading As/Bs; SH is reusable

    if (Y32) {
        // f32 path: store transposed to (B, 50, N): Y32[(b*50+o)*2048 + n], o < Olimit
#pragma unroll
        for (int oi = 0; oi < 4; ++oi) {
            const int og = o_blk + oh + oi * 16 + quad * 4;
            const f32x4 bv = *(const f32x4*)(bias + bb + og);
#pragma unroll
            for (int mi = 0; mi < MI; ++mi) {
                const int m = m_blk + mh + mi * 16 + r;
                const int bidx = m >> 11, n = m & 2047;
                f32x4 v = acc[oi][mi] + bv;
#pragma unroll
                for (int j = 0; j < 4; ++j) {
                    float x = v[j];
                    if (act == 1)      x = (x > 0.f) ? x : 0.0f;
                    else if (act == 2) x = (x > 0.f) ? x : 0.2f * x;
                    const int o = og + j;
                    if (o < Olimit)
                        Y32[((size_t)(bidx * 50 + o) << 11) + n] = x;
                }
            }
        }
        return;
    }

    // f16 path: stage [TM][128] tile in LDS (XOR-swizzled), then coalesced writeback
    _Float16* OT = SH;
#pragma unroll
    for (int oi = 0; oi < 4; ++oi) {
        const int ol = oh + oi * 16 + quad * 4;       // local o (0..127), 4-aligned
        const f32x4 bv = *(const f32x4*)(bias + bb + o_blk + ol);
#pragma unroll
        for (int mi = 0; mi < MI; ++mi) {
            const int row = mh + mi * 16 + r;         // local m
            f32x4 v = acc[oi][mi] + bv;
            if (Res) {
                f16x4 rr = *(const f16x4*)(Res + (size_t)(m_blk + row) * ldR + roff + o_blk + ol);
#pragma unroll
                for (int j = 0; j < 4; ++j) v[j] += (float)rr[j];
            }
            f16x4 ov;
#pragma unroll
            for (int j = 0; j < 4; ++j) {
                float x = v[j];
                if (act == 1)      x = (x > 0.f) ? x : 0.0f;
                else if (act == 2) x = (x > 0.f) ? x : 0.2f * x;
                ov[j] = (_Float16)x;
            }
            const int s = ((ol >> 2) ^ (row & 31)) << 2;   // swizzled 8B slot
            *(f16x4*)(OT + row * 128 + s) = ov;
        }
    }
    __syncthreads();
#pragma unroll
    for (int it2 = 0; it2 < TM / 16; ++it2) {
        const int row = it2 * 16 + (tid >> 4);
        const int c = tid & 15;                        // 8 f16 per lane, contiguous
        const int s0 = ((c * 2) ^ (row & 31)) << 2;
        const int s1 = ((c * 2 + 1) ^ (row & 31)) << 2;
        f16x4 a = *(const f16x4*)(OT + row * 128 + s0);
        f16x4 b2 = *(const f16x4*)(OT + row * 128 + s1);
        f16x8 o8;
        o8[0] = a[0]; o8[1] = a[1]; o8[2] = a[2]; o8[3] = a[3];
        o8[4] = b2[0]; o8[5] = b2[1]; o8[6] = b2[2]; o8[7] = b2[3];
        *(f16x8*)(Y + (size_t)(m_blk + row) * ldY + yoff + o_blk + c * 8) = o8;
    }

    // ---- fused pooling (Wf only): per-block max/sum over the TM rows of this o-slice ----
    if constexpr (TM == 128) {
        if (pmax) {
            const int cg = tid & 31, h = tid >> 5;     // 32 col-groups x 8 row-groups
            float mx0 = -3.4e38f, mx1 = -3.4e38f, mx2 = -3.4e38f, mx3 = -3.4e38f;
            float sm0 = 0.f, sm1 = 0.f, sm2 = 0.f, sm3 = 0.f;
#pragma unroll
            for (int rr = 0; rr < 16; ++rr) {
                const int r2 = h * 16 + rr;
                const f16x4 v = *(const f16x4*)(OT + r2 * 128 + ((cg ^ (r2 & 31)) << 2));
                const float x0 = (float)v[0], x1 = (float)v[1], x2 = (float)v[2], x3 = (float)v[3];
                mx0 = fmaxf(mx0, x0); sm0 += x0;
                mx1 = fmaxf(mx1, x1); sm1 += x1;
                mx2 = fmaxf(mx2, x2); sm2 += x2;
                mx3 = fmaxf(mx3, x3); sm3 += x3;
            }
            __syncthreads();                 // done reading OT; reuse SH as partial buffer
            float* PR = (float*)SH;          // [8 h][128 c][2] = 2048 f32 = 8 KB
            float* pw = PR + (size_t)(h * 128 + cg * 4) * 2;
            pw[0] = mx0; pw[1] = sm0; pw[2] = mx1; pw[3] = sm1;
            pw[4] = mx2; pw[5] = sm2; pw[6] = mx3; pw[7] = sm3;
            __syncthreads();
            if (tid < 128) {
                float M = -3.4e38f, S = 0.f;
#pragma unroll
                for (int h2 = 0; h2 < 8; ++h2) {
                    M = fmaxf(M, PR[(size_t)(h2 * 128 + tid) * 2]);
                    S += PR[(size_t)(h2 * 128 + tid) * 2 + 1];
                }
                const int b2 = m_blk >> 11, mt = (m_blk >> 7) & 15;
                pmax[((size_t)(b2 * 16 + mt) << 10) + o_blk + tid] = M;
                psum[((size_t)(b2 * 16 + mt) << 10) + o_blk + tid] = S;
            }
        }
    }
}

// ---------------- neighbor gather + channel max (relu outputs => ushort-monotonic f16 bits) ----------------
typedef short s16x8 __attribute__((ext_vector_type(8)));
__global__ __launch_bounds__(256) void gather_max_kernel(
    const short* __restrict__ T, const int* __restrict__ idx, short* __restrict__ Mo)
{
    const int tid = threadIdx.x;
    const int p = blockIdx.x * 16 + (tid >> 4);
    const int l = tid & 15;
    const int b = p >> 11;
    const int* ip = idx + (size_t)p * 16;
    size_t row = (size_t)((b << 11) + ip[0]);
    s16x8 cur = *(const s16x8*)(T + row * 128 + l * 8);
    unsigned short best[8];
#pragma unroll
    for (int e = 0; e < 8; ++e) best[e] = (unsigned short)cur[e];
#pragma unroll
    for (int j = 1; j < 16; ++j) {
        row = (size_t)((b << 11) + ip[j]);
        s16x8 v = *(const s16x8*)(T + row * 128 + l * 8);
#pragma unroll
        for (int e = 0; e < 8; ++e) {
            unsigned short u = (unsigned short)v[e];
            if (u > best[e]) best[e] = u;
        }
    }
    s16x8 ov;
#pragma unroll
    for (int e = 0; e < 8; ++e) ov[e] = (short)best[e];
    *(s16x8*)(Mo + (size_t)p * 128 + l * 8) = ov;
}

// ---------------- per-batch constant vector for Wc1 (absorbs reduce2 + label path) ----------------
__global__ __launch_bounds__(256) void cvec_kernel(
    const float* __restrict__ label, const float* __restrict__ Wl, const float* __restrict__ gl, const float* __restrict__ bl,
    const float* __restrict__ Wc1, const float* __restrict__ bc1, const float* __restrict__ gc1, const float* __restrict__ bb1,
    const float* __restrict__ pmax, const float* __restrict__ psum, float* __restrict__ cvec)
{
    __shared__ float v[2112];
    __shared__ float red[256];
    const int b = blockIdx.x, og = blockIdx.y, tid = threadIdx.x;
    for (int i = tid; i < 1024; i += 256) {
        float mx = -3.4e38f, sm = 0.f;
#pragma unroll
        for (int c = 0; c < 16; ++c) {
            mx = fmaxf(mx, pmax[((size_t)(b * 16 + c) << 10) + i]);
            sm += psum[((size_t)(b * 16 + c) << 10) + i];
        }
        v[i] = mx;
        v[1024 + i] = sm * (1.f / 2048.f);
    }
    if (tid < 64) {
        float s = 0.f;
        for (int i = 0; i < 16; ++i) s += Wl[tid * 16 + i] * label[b * 16 + i];
        s = gl[tid] * s + bl[tid];
        v[2048 + tid] = (s > 0.f) ? s : 0.2f * s;
    }
    __syncthreads();
    const int o = og * 64 + (tid >> 2), part = tid & 3;
    const float* wrow = Wc1 + (size_t)o * 3136 + 1024 + part * 528;
    float s = 0.f;
    for (int j = 0; j < 528; ++j) s += wrow[j] * v[part * 528 + j];
    red[tid] = s;
    __syncthreads();
    if (part == 0) {
        float tot = red[tid] + red[tid + 1] + red[tid + 2] + red[tid + 3];
        cvec[((size_t)b << 9) + o] = gc1[o] * (tot + bc1[o]) + bb1[o];
    }
}

// ---------------- launch ----------------
extern "C" void kernel_launch(void* const* d_in, const int* in_sizes, int n_in,
                              void* d_out, int out_size, void* d_ws, size_t ws_size,
                              hipStream_t stream)
{
    (void)in_sizes; (void)n_in; (void)out_size; (void)ws_size;
    const float* points = (const float*)d_in[0];
    const float* label  = (const float*)d_in[1];
    const float* We1 = (const float*)d_in[2];
    const float* ge1 = (const float*)d_in[3];
    const float* be1 = (const float*)d_in[4];
    const float* We2 = (const float*)d_in[5];
    const float* ge2 = (const float*)d_in[6];
    const float* be2 = (const float*)d_in[7];
    const float* W1  = (const float*)d_in[8];
    const float* g1  = (const float*)d_in[9];
    const float* b1  = (const float*)d_in[10];
    const float* W2  = (const float*)d_in[11];
    const float* g2  = (const float*)d_in[12];
    const float* b2  = (const float*)d_in[13];
    const float* Wf  = (const float*)d_in[14];
    const float* gf  = (const float*)d_in[15];
    const float* bfv = (const float*)d_in[16];
    const float* Wl  = (const float*)d_in[17];
    const float* gl  = (const float*)d_in[18];
    const float* bl  = (const float*)d_in[19];
    const float* Wc1 = (const float*)d_in[20];
    const float* bc1 = (const float*)d_in[21];
    const float* gc1 = (const float*)d_in[22];
    const float* bb1 = (const float*)d_in[23];
    const float* Wc2 = (const float*)d_in[24];
    const float* bc2 = (const float*)d_in[25];
    const float* gc2 = (const float*)d_in[26];
    const float* bb2 = (const float*)d_in[27];
    const float* Wc3 = (const float*)d_in[28];
    const float* bc3 = (const float*)d_in[29];

    char* ws = (char*)d_ws;
    _Float16* hT  = (_Float16*)(ws + OFF_HT);
    _Float16* tT  = (_Float16*)(ws + OFF_TT);
    _Float16* mT  = (_Float16*)(ws + OFF_MT);
    _Float16* xct = (_Float16*)(ws + OFF_XCAT);
    _Float16* xf  = (_Float16*)(ws + OFF_XF);
    _Float16* c1  = (_Float16*)(ws + OFF_C1);
    _Float16* c2  = (_Float16*)(ws + OFF_C2);
    int*      idx = (int*)     (ws + OFF_IDX);
    _Float16* x0  = (_Float16*)(ws + OFF_X0);

    _Float16* wE1 = (_Float16*)(ws + OFF_WE1);
    _Float16* wE2 = (_Float16*)(ws + OFF_WE2);
    _Float16* w1f = (_Float16*)(ws + OFF_W1);
    _Float16* w2f = (_Float16*)(ws + OFF_W2);
    _Float16* wF  = (_Float16*)(ws + OFF_WF);
    _Float16* wC1 = (_Float16*)(ws + OFF_WC1);
    _Float16* wC2 = (_Float16*)(ws + OFF_WC2);
    _Float16* wC3 = (_Float16*)(ws + OFF_WC3);
    float* bC2 = (float*)(ws + OFF_BC2);
    float* bC3 = (float*)(ws + OFF_BC3);
    float* cv  = (float*)(ws + OFF_CVEC);
    float* pmx = (float*)(ws + OFF_PMAX);
    float* psm = (float*)(ws + OFF_PSUM);

    // prep (weights + biases + x0, one launch)
    fold_all_kernel<<<dim3(4834), 256, 0, stream>>>(We1, ge1, We2, ge2, W1, g1, W2, g2,
                                                    Wf, gf, Wc1, gc1, Wc2, gc2, Wc3,
                                                    gc2, bc2, bb2, bc3, points, ws);
    knn_kernel<<<dim3(BB, NN / 32), 256, 0, stream>>>(points, idx);

    // e1: x0(Mx64,pad) -> tT(Mx128), relu
    gemm_tile<64><<<dim3(512, 1), 256, 0, stream>>>(wE1, x0, tT, nullptr, be1, nullptr, 64, 64, 0, 128, 0, 128, 1, 0, 0, 0, 128, nullptr, nullptr);
    // e2: tT -> hT, relu
    gemm_tile<64><<<dim3(512, 1), 256, 0, stream>>>(wE2, tT, hT, nullptr, be2, nullptr, 128, 128, 0, 128, 0, 128, 1, 0, 0, 0, 128, nullptr, nullptr);

    for (int i = 0; i < 3; ++i) {
        const _Float16* hin = (i == 0) ? hT : xct;
        int ldH  = (i == 0) ? 128 : 384;
        int offH = (i == 0) ? 0 : (i - 1) * 128;
        // t = relu(bn(W1 h))
        gemm_tile<64><<<dim3(512, 1), 256, 0, stream>>>(w1f + (size_t)i * 16384, hin, tT, nullptr, b1 + i * 128, nullptr,
                                                        128, ldH, offH, 128, 0, 128, 1, 0, 0, 0, 128, nullptr, nullptr);
        // m = neighbor max
        gather_max_kernel<<<dim3(MM / 16), 256, 0, stream>>>((const short*)tT, idx, (short*)mT);
        // h' = relu(bn(W2 m) + h) -> xcat slice i
        gemm_tile<64><<<dim3(512, 1), 256, 0, stream>>>(w2f + (size_t)i * 16384, mT, xct, nullptr, b2 + i * 128, hin,
                                                        128, 128, 0, 384, i * 128, 128, 1, 0, ldH, offH, 128, nullptr, nullptr);
    }

    // xf = leaky(bn(Wf xcat)) with fused pooling partials (max/sum per 128-row tile) — proven v5b
    gemm_tile<128><<<dim3(256, 8), 256, 0, stream>>>(wF, xct, xf, nullptr, bfv, nullptr, 384, 384, 0, 1024, 0, 1024, 2, 0, 0, 0, 1024, pmx, psm);

    // per-batch classifier constant (absorbs pooled stats + label path)
    cvec_kernel<<<dim3(BB, 8), 256, 0, stream>>>(label, Wl, gl, bl, Wc1, bc1, gc1, bb1, pmx, psm, cv);

    // c1 = relu(gc1*Wc1[:, :1024] xf + cvec[b]) — 256² long-K GEMM (nt=16)
    gemm256<<<dim3(128, 2), 512, 0, stream>>>(wC1, xf, c1, cv, 1024, 1024, 512, 512, 1, 1);

    // c2 = relu(bn(Wc2 c1 + bc2))
    gemm_tile<128><<<dim3(256, 2), 256, 0, stream>>>(wC2, c1, c2, nullptr, bC2, nullptr, 512, 512, 0, 256, 0, 256, 1, 0, 0, 0, 256, nullptr, nullptr);
    // c3 = Wc3 c2 + bc3 (no act), f32, stored transposed directly to (B,50,N) output
    gemm_tile<128><<<dim3(256, 1), 256, 0, stream>>>(wC3, c2, nullptr, (float*)d_out, bC3, nullptr, 256, 256, 0, 0, 0, 128, 0, 0, 0, 0, 50, nullptr, nullptr);
}

// Round 8
// 379.215 us; speedup vs baseline: 1.0580x; 1.0580x over previous
//
#include <hip/hip_runtime.h>
#include <cstdint>
#include <cstddef>

#define DEVINL __device__ __forceinline__

typedef float    f32x4 __attribute__((ext_vector_type(4)));
typedef _Float16 f16x8 __attribute__((ext_vector_type(8)));
typedef _Float16 f16x4 __attribute__((ext_vector_type(4)));

// ---------------- constants ----------------
constexpr int BB = 16, NN = 2048, MM = 32768;

// ---------------- ws layout (bytes) ----------------
constexpr size_t OFF_WE1 = 0;                           // 128x64 f16 (Kp padded 6->64)
constexpr size_t OFF_WE2 = OFF_WE1 + 128 * 64 * 2;
constexpr size_t OFF_W1  = OFF_WE2 + 128 * 128 * 2;
constexpr size_t OFF_W2  = OFF_W1  + 3 * 128 * 128 * 2;
constexpr size_t OFF_WF  = OFF_W2  + 3 * 128 * 128 * 2;
constexpr size_t OFF_WC1 = OFF_WF  + 1024 * 384 * 2;
constexpr size_t OFF_WC2 = OFF_WC1 + 512 * 1024 * 2;
constexpr size_t OFF_WC3 = OFF_WC2 + 256 * 512 * 2;     // 128x256 (Opad 50->128)
constexpr size_t OFF_BC2 = OFF_WC3 + 128 * 256 * 2;     // 256 f32
constexpr size_t OFF_BC3 = OFF_BC2 + 256 * 4;           // 128 f32
constexpr size_t OFF_CVEC= OFF_BC3 + 128 * 4;           // 16x512 f32
constexpr size_t OFF_PMAX= OFF_CVEC+ 16 * 512 * 4;      // 16 b x 8 mtile x 1024 o f32 (256-row tiles)
constexpr size_t OFF_PSUM= OFF_PMAX+ 16 * 16 * 1024 * 4;
constexpr size_t OFF_IDX = OFF_PSUM+ 16 * 16 * 1024 * 4;
constexpr size_t OFF_R1  = 8ull << 20;                  // > OFF_IDX + 2MB
constexpr size_t OFF_X0  = OFF_R1;                      // 4MB  (M x 64 f16, k-padded)
constexpr size_t OFF_HT  = OFF_R1 + (4ull  << 20);      // 8MB  (M x 128 f16)
constexpr size_t OFF_TT  = OFF_R1 + (12ull << 20);      // 8MB
constexpr size_t OFF_MT  = OFF_R1 + (20ull << 20);      // 8MB
constexpr size_t OFF_C1  = OFF_R1;                      // 32MB (M x 512 f16), aliases x0/h/t/m (dead)
constexpr size_t OFF_XCAT= OFF_R1 + (32ull << 20);      // 24MB (M x 384 f16)
constexpr size_t OFF_C2  = OFF_XCAT;                    // 16MB (M x 256 f16), aliases xcat (dead)
constexpr size_t OFF_XF  = OFF_XCAT + (24ull << 20);    // 64MB (M x 1024 f16)

// ---------------- fold-all: weights (f16, BN-folded), biases, x0 prep ----------------
__global__ __launch_bounds__(256) void fold_all_kernel(
    const float* We1, const float* ge1, const float* We2, const float* ge2,
    const float* W1,  const float* g1,  const float* W2,  const float* g2,
    const float* Wf,  const float* gf,  const float* Wc1, const float* gc1,
    const float* Wc2, const float* gc2, const float* Wc3,
    const float* gc2b, const float* bc2, const float* bb2, const float* bc3,
    const float* pts, char* ws)
{
    const int bid = blockIdx.x;
    const int tid = threadIdx.x;

    if (bid == 4704) {
        ((float*)(ws + OFF_BC2))[tid] = gc2b[tid] * bc2[tid] + bb2[tid];
        return;
    }
    if (bid == 4705) {
        if (tid < 128) ((float*)(ws + OFF_BC3))[tid] = (tid < 50) ? bc3[tid] : 0.f;
        return;
    }
    if (bid >= 4706) {           // x0 prep: (B,6,N) f32 -> (M x 64) f16 K-contig, zero pad
        int m = (bid - 4706) * 256 + tid;
        int b = m >> 11, n = m & 2047;
        const float* ps = pts + (size_t)b * 6 * 2048 + n;
        _Float16 tmp[64];
#pragma unroll
        for (int c = 0; c < 64; ++c) tmp[c] = (_Float16)0.f;
#pragma unroll
        for (int c = 0; c < 6; ++c) tmp[c] = (_Float16)ps[(size_t)c << 11];
        _Float16* dst = (_Float16*)(ws + OFF_X0) + (size_t)m * 64;
#pragma unroll
        for (int v = 0; v < 8; ++v) *(f16x8*)(dst + v * 8) = *(const f16x8*)(tmp + v * 8);
        return;
    }

    int id, base;
    if      (bid < 32)   { id = 0;  base = 0;    }
    else if (bid < 96)   { id = 1;  base = 32;   }
    else if (bid < 160)  { id = 2;  base = 96;   }
    else if (bid < 224)  { id = 3;  base = 160;  }
    else if (bid < 288)  { id = 4;  base = 224;  }
    else if (bid < 352)  { id = 5;  base = 288;  }
    else if (bid < 416)  { id = 6;  base = 352;  }
    else if (bid < 480)  { id = 7;  base = 416;  }
    else if (bid < 2016) { id = 8;  base = 480;  }
    else if (bid < 4064) { id = 9;  base = 2016; }
    else if (bid < 4576) { id = 10; base = 4064; }
    else                 { id = 11; base = 4576; }

    const float* src = nullptr; const float* g = nullptr; _Float16* dst = nullptr;
    int O = 0, K = 0, lds = 0, Kp = 0;
    switch (id) {
        case 0:  src = We1; g = ge1; O = 128; K = 6;    lds = 6;    Kp = 64;   dst = (_Float16*)(ws + OFF_WE1); break;
        case 1:  src = We2; g = ge2; O = 128; K = 128;  lds = 128;  Kp = 128;  dst = (_Float16*)(ws + OFF_WE2); break;
        case 2: case 3: case 4: {
            int i = id - 2;
            src = W1 + (size_t)i * 16384; g = g1 + i * 128; O = 128; K = 128; lds = 128; Kp = 128;
            dst = (_Float16*)(ws + OFF_W1) + (size_t)i * 16384; break; }
        case 5: case 6: case 7: {
            int i = id - 5;
            src = W2 + (size_t)i * 16384; g = g2 + i * 128; O = 128; K = 128; lds = 128; Kp = 128;
            dst = (_Float16*)(ws + OFF_W2) + (size_t)i * 16384; break; }
        case 8:  src = Wf;  g = gf;  O = 1024; K = 384;  lds = 384;  Kp = 384;  dst = (_Float16*)(ws + OFF_WF);  break;
        case 9:  src = Wc1; g = gc1; O = 512;  K = 1024; lds = 3136; Kp = 1024; dst = (_Float16*)(ws + OFF_WC1); break;
        case 10: src = Wc2; g = gc2; O = 256;  K = 512;  lds = 512;  Kp = 512;  dst = (_Float16*)(ws + OFF_WC2); break;
        default: src = Wc3; g = nullptr; O = 50; K = 256; lds = 256; Kp = 256;  dst = (_Float16*)(ws + OFF_WC3); break;
    }
    int e = (bid - base) * 256 + tid;
    int o = e / Kp, k = e - o * Kp;
    float v = 0.f;
    if (o < O && k < K) {
        v = src[(size_t)o * lds + k];
        if (g) v *= g[o];
    }
    dst[e] = (_Float16)v;
}

// ---------------- KNN v8: top-4 bound pass -> survivor buffer -> exact select ----------------
DEVINL float knn_dist(const float4 pq, const float4 pm) {
    float t = pq.x * pm.x;
    t = fmaf(pq.y, pm.y, t);
    t = fmaf(pq.z, pm.z, t);
    return fmaf(-2.f, t, pm.w);
}

#define KNN_DINS(X) do { \
    const float x_ = (X); \
    d15 = __builtin_amdgcn_fmed3f(x_, d14, d15); \
    d14 = __builtin_amdgcn_fmed3f(x_, d13, d14); \
    d13 = __builtin_amdgcn_fmed3f(x_, d12, d13); \
    d12 = __builtin_amdgcn_fmed3f(x_, d11, d12); \
    d11 = __builtin_amdgcn_fmed3f(x_, d10, d11); \
    d10 = __builtin_amdgcn_fmed3f(x_, d9,  d10); \
    d9  = __builtin_amdgcn_fmed3f(x_, d8,  d9);  \
    d8  = __builtin_amdgcn_fmed3f(x_, d7,  d8);  \
    d7  = __builtin_amdgcn_fmed3f(x_, d6,  d7);  \
    d6  = __builtin_amdgcn_fmed3f(x_, d5,  d6);  \
    d5  = __builtin_amdgcn_fmed3f(x_, d4,  d5);  \
    d4  = __builtin_amdgcn_fmed3f(x_, d3,  d4);  \
    d3  = __builtin_amdgcn_fmed3f(x_, d2,  d3);  \
    d2  = __builtin_amdgcn_fmed3f(x_, d1,  d2);  \
    d1  = __builtin_amdgcn_fmed3f(x_, d0,  d1);  \
    d0  = __builtin_amdgcn_fmed3f(x_, -3.4e38f, d0); \
} while (0)

// compare-exchange (ascending)
#define KNN_CE(A, B) { const float lo_ = fminf(A, B), hi_ = fmaxf(A, B); A = lo_; B = hi_; }

// merge own ascending d0..d15 with lane^OFF's ascending list, keep lowest 16 sorted.
#define KNN_MERGE(OFF) do { \
    const float n0  = __shfl_xor(d0,  OFF), n1  = __shfl_xor(d1,  OFF), \
                n2  = __shfl_xor(d2,  OFF), n3  = __shfl_xor(d3,  OFF), \
                n4  = __shfl_xor(d4,  OFF), n5  = __shfl_xor(d5,  OFF), \
                n6  = __shfl_xor(d6,  OFF), n7  = __shfl_xor(d7,  OFF), \
                n8  = __shfl_xor(d8,  OFF), n9  = __shfl_xor(d9,  OFF), \
                n10 = __shfl_xor(d10, OFF), n11 = __shfl_xor(d11, OFF), \
                n12 = __shfl_xor(d12, OFF), n13 = __shfl_xor(d13, OFF), \
                n14 = __shfl_xor(d14, OFF), n15 = __shfl_xor(d15, OFF); \
    d0  = fminf(d0,  n15); d1  = fminf(d1,  n14); d2  = fminf(d2,  n13); d3  = fminf(d3,  n12); \
    d4  = fminf(d4,  n11); d5  = fminf(d5,  n10); d6  = fminf(d6,  n9);  d7  = fminf(d7,  n8);  \
    d8  = fminf(d8,  n7);  d9  = fminf(d9,  n6);  d10 = fminf(d10, n5);  d11 = fminf(d11, n4);  \
    d12 = fminf(d12, n3);  d13 = fminf(d13, n2);  d14 = fminf(d14, n1);  d15 = fminf(d15, n0);  \
    KNN_CE(d0, d8)  KNN_CE(d1, d9)  KNN_CE(d2, d10) KNN_CE(d3, d11) \
    KNN_CE(d4, d12) KNN_CE(d5, d13) KNN_CE(d6, d14) KNN_CE(d7, d15) \
    KNN_CE(d0, d4)  KNN_CE(d1, d5)  KNN_CE(d2, d6)  KNN_CE(d3, d7)  \
    KNN_CE(d8, d12) KNN_CE(d9, d13) KNN_CE(d10,d14) KNN_CE(d11,d15) \
    KNN_CE(d0, d2)  KNN_CE(d1, d3)  KNN_CE(d4, d6)  KNN_CE(d5, d7)  \
    KNN_CE(d8, d10) KNN_CE(d9, d11) KNN_CE(d12,d14) KNN_CE(d13,d15) \
    KNN_CE(d0, d1)  KNN_CE(d2, d3)  KNN_CE(d4, d5)  KNN_CE(d6, d7)  \
    KNN_CE(d8, d9)  KNN_CE(d10,d11) KNN_CE(d12,d13) KNN_CE(d14,d15) \
} while (0)

__global__ __launch_bounds__(256) void knn_kernel(const float* __restrict__ pts, int* __restrict__ idxout)
{
    __shared__ float4 P[2048];              // 32KB, stays intact for all passes
    __shared__ unsigned short buf[32][96];  // 6KB survivor indices per query
    __shared__ int cnt[32];
    __shared__ int wcnt[32];
    const int tid = threadIdx.x;
    const int b = blockIdx.x;
    const float* pb = pts + (size_t)b * 6 * 2048;
    for (int i = tid; i < 2048; i += 256) {
        float x = pb[i];
        float y = pb[2048 + i];
        float z = pb[4096 + i];
        P[i] = make_float4(x, y, z, x * x + y * y + z * z);
    }
    if (tid < 32) { cnt[tid] = 0; wcnt[tid] = 0; }
    __syncthreads();

    const int p = tid & 7;          // candidate partition (m == 8*it + p)
    const int g = tid >> 3;         // query within block (0..31); group = 8 consecutive lanes
    const int q = blockIdx.y * 32 + g;
    const float4 pq = P[q];

    // ---- pass 1: per-lane top-4 over this lane's 256-candidate partition ----
    float d0 = 3.4e38f, d1 = 3.4e38f, d2 = 3.4e38f, d3 = 3.4e38f;
#pragma unroll 4
    for (int it = 0; it < 256; ++it) {
        const float4 pm = P[it * 8 + p];
        const float x = knn_dist(pq, pm);
        d3 = __builtin_amdgcn_fmed3f(x, d2, d3);
        d2 = __builtin_amdgcn_fmed3f(x, d1, d2);
        d1 = __builtin_amdgcn_fmed3f(x, d0, d1);
        d0 = fminf(x, d0);
    }
    float d4 = 3.4e38f, d5 = 3.4e38f, d6 = 3.4e38f, d7 = 3.4e38f,
          d8 = 3.4e38f, d9 = 3.4e38f, d10 = 3.4e38f, d11 = 3.4e38f,
          d12 = 3.4e38f, d13 = 3.4e38f, d14 = 3.4e38f, d15 = 3.4e38f;
    KNN_MERGE(1);
    KNN_MERGE(2);
    KNN_MERGE(4);
    const float tub = d15;          // 16th-smallest of union of top-4s; tub >= d*

    // ---- pass 2: collect survivor indices (d <= tub) ----
#pragma unroll 4
    for (int it = 0; it < 256; ++it) {
        const int m = it * 8 + p;
        const float d = knn_dist(pq, P[m]);
        if (d <= tub) {
            const int pos = atomicAdd(&cnt[g], 1);
            if (pos < 96) buf[g][pos] = (unsigned short)m;
        }
    }
    int C = cnt[g];                 // same-wave LDS ops: no barrier needed
    if (C > 96) C = 96;

    // ---- pass 3: exact top-16 among the C survivors (8 lanes split them) ----
    d0 = 3.4e38f; d1 = 3.4e38f; d2 = 3.4e38f; d3 = 3.4e38f;
    d4 = 3.4e38f; d5 = 3.4e38f; d6 = 3.4e38f; d7 = 3.4e38f;
    d8 = 3.4e38f; d9 = 3.4e38f; d10 = 3.4e38f; d11 = 3.4e38f;
    d12 = 3.4e38f; d13 = 3.4e38f; d14 = 3.4e38f; d15 = 3.4e38f;
    for (int j = p; j < C; j += 8) {
        const int m = buf[g][j];
        const float x = knn_dist(pq, P[m]);
        KNN_DINS(x);
    }
    KNN_MERGE(1);
    KNN_MERGE(2);
    KNN_MERGE(4);
    const float t = d15;            // exact 16th-smallest distance

    // ---- final write: survivors with d <= t, capped at 16 (tie-arbitrary, as before) ----
    int* op = idxout + (((size_t)(b << 11) + q) << 4);
    for (int j = p; j < C; j += 8) {
        const int m = buf[g][j];
        const float d = knn_dist(pq, P[m]);
        if (d <= t) {
            const int pos = atomicAdd(&wcnt[g], 1);
            if (pos < 16) op[pos] = m;   // order-scrambled: consumer is a max over the set
        }
    }
}

// ---------------- fused e1+e2: h = relu(We2 · relu(We1 · x0)) ; t stays in LDS ----------------
// 256 threads, 64 m-rows/block, grid 512. LDS: A1 16K | B1 8K | A2 32K | B2(t) 16K = 72KB
// (2 blocks/CU). t is written into B2 in the staged-B layout (slot^(row&7)) so GEMM2's
// fragment reads are the verified zero-conflict pattern. Same f16 rounding as the old
// HBM round-trip => bit-identical results.
__global__ __launch_bounds__(256) void e12_kernel(
    const _Float16* __restrict__ W1e, const _Float16* __restrict__ W2e,
    const _Float16* __restrict__ X, _Float16* __restrict__ Y,
    const float* __restrict__ b1v, const float* __restrict__ b2v)
{
    __shared__ _Float16 SH[36864];
    _Float16* A1s = SH;             // 8192  (We1 128x64)
    _Float16* B1s = SH + 8192;      // 4096  (x0 64x64)
    _Float16* A2s = SH + 12288;     // 16384 (We2 128x128, 2 ktiles)
    _Float16* B2s = SH + 28672;     // 8192  (t 64x128, 2 ktiles)

    const int tid = threadIdx.x;
    const int lane = tid & 63, wave = tid >> 6;
    const int r = lane & 15, quad = lane >> 4;
    const int m_blk = blockIdx.x * 64;
    const int oh = (wave >> 1) * 64, mh = (wave & 1) * 32;

    const int srow  = wave * 8 + (lane >> 3);
    const int sslot = lane & 7;

    // stage A1 (4), B1 (2), A2 (8) — A2 lands under GEMM1
#pragma unroll
    for (int t = 0; t < 4; ++t) {
        const int row = t * 32 + srow;
        const int gk = (sslot ^ (row & 7)) << 3;
        __builtin_amdgcn_global_load_lds(
            (const __attribute__((address_space(1))) unsigned int*)(W1e + (size_t)row * 64 + gk),
            (__attribute__((address_space(3))) unsigned int*)(A1s + t * 2048 + wave * 512),
            16, 0, 0);
    }
#pragma unroll
    for (int t = 0; t < 2; ++t) {
        const int row = t * 32 + srow;
        const int gk = (sslot ^ (row & 7)) << 3;
        __builtin_amdgcn_global_load_lds(
            (const __attribute__((address_space(1))) unsigned int*)(X + (size_t)(m_blk + row) * 64 + gk),
            (__attribute__((address_space(3))) unsigned int*)(B1s + t * 2048 + wave * 512),
            16, 0, 0);
    }
#pragma unroll
    for (int kt = 0; kt < 2; ++kt)
#pragma unroll
        for (int t = 0; t < 4; ++t) {
            const int row = t * 32 + srow;
            const int gk = kt * 64 + ((sslot ^ (row & 7)) << 3);
            __builtin_amdgcn_global_load_lds(
                (const __attribute__((address_space(1))) unsigned int*)(W2e + (size_t)row * 128 + gk),
                (__attribute__((address_space(3))) unsigned int*)(A2s + kt * 8192 + t * 2048 + wave * 512),
                16, 0, 0);
        }

    asm volatile("s_waitcnt vmcnt(8)" ::: "memory");   // A1+B1 landed; A2 still in flight
    __builtin_amdgcn_sched_barrier(0);
    __builtin_amdgcn_s_barrier();
    asm volatile("" ::: "memory");

    // GEMM1: t[m][o] = We1·x0
    f32x4 acc1[4][2];
#pragma unroll
    for (int a = 0; a < 4; ++a)
#pragma unroll
        for (int c = 0; c < 2; ++c) acc1[a][c] = (f32x4){0.f, 0.f, 0.f, 0.f};
#pragma unroll
    for (int ks = 0; ks < 2; ++ks) {
        f16x8 af[4], bf[2];
#pragma unroll
        for (int oi = 0; oi < 4; ++oi) {
            const int row = oh + oi * 16 + r;
            const int slot = (ks * 4 + quad) ^ (row & 7);
            af[oi] = *(const f16x8*)(A1s + row * 64 + slot * 8);
        }
#pragma unroll
        for (int mi = 0; mi < 2; ++mi) {
            const int row = mh + mi * 16 + r;
            const int slot = (ks * 4 + quad) ^ (row & 7);
            bf[mi] = *(const f16x8*)(B1s + row * 64 + slot * 8);
        }
#pragma unroll
        for (int oi = 0; oi < 4; ++oi)
#pragma unroll
            for (int mi = 0; mi < 2; ++mi)
                acc1[oi][mi] = __builtin_amdgcn_mfma_f32_16x16x32_f16(af[oi], bf[mi], acc1[oi][mi], 0, 0, 0);
    }

    // epilogue1: relu(acc1+b1) -> B2s in staged-B layout (chunk c stored at slot c^(row&7))
#pragma unroll
    for (int oi = 0; oi < 4; ++oi) {
        const int ob = oh + oi * 16 + quad * 4;        // t-channel = GEMM2 k, 0..127
        const f32x4 bv = *(const f32x4*)(b1v + ob);
        const int kt = ob >> 6, kk = ob & 63;
        const int chunk = kk >> 3, within = kk & 7;    // within in {0,4}
#pragma unroll
        for (int mi = 0; mi < 2; ++mi) {
            const int row = mh + mi * 16 + r;
            f32x4 v = acc1[oi][mi] + bv;
            f16x4 ov;
#pragma unroll
            for (int j = 0; j < 4; ++j) { float x = v[j]; ov[j] = (_Float16)((x > 0.f) ? x : 0.f); }
            *(f16x4*)(B2s + kt * 4096 + row * 64 + ((chunk ^ (row & 7)) << 3) + within) = ov;
        }
    }
    __syncthreads();   // B2s visible to all; full waitcnt also drains A2's loads

    // GEMM2: h[m][o2] = We2·t
    f32x4 acc2[4][2];
#pragma unroll
    for (int a = 0; a < 4; ++a)
#pragma unroll
        for (int c = 0; c < 2; ++c) acc2[a][c] = (f32x4){0.f, 0.f, 0.f, 0.f};
#pragma unroll
    for (int kt = 0; kt < 2; ++kt)
#pragma unroll
        for (int ks = 0; ks < 2; ++ks) {
            f16x8 af[4], bf[2];
#pragma unroll
            for (int oi = 0; oi < 4; ++oi) {
                const int row = oh + oi * 16 + r;
                const int slot = (ks * 4 + quad) ^ (row & 7);
                af[oi] = *(const f16x8*)(A2s + kt * 8192 + row * 64 + slot * 8);
            }
#pragma unroll
            for (int mi = 0; mi < 2; ++mi) {
                const int row = mh + mi * 16 + r;
                const int slot = (ks * 4 + quad) ^ (row & 7);
                bf[mi] = *(const f16x8*)(B2s + kt * 4096 + row * 64 + slot * 8);
            }
#pragma unroll
            for (int oi = 0; oi < 4; ++oi)
#pragma unroll
                for (int mi = 0; mi < 2; ++mi)
                    acc2[oi][mi] = __builtin_amdgcn_mfma_f32_16x16x32_f16(af[oi], bf[mi], acc2[oi][mi], 0, 0, 0);
        }
    __syncthreads();   // all GEMM2 reads done; SH reusable as OT

    // epilogue2: OT stage (reuse SH base) + coalesced write to Y (ld 128)
    _Float16* OT = SH;
#pragma unroll
    for (int oi = 0; oi < 4; ++oi) {
        const int ol = oh + oi * 16 + quad * 4;
        const f32x4 bv = *(const f32x4*)(b2v + ol);
#pragma unroll
        for (int mi = 0; mi < 2; ++mi) {
            const int row = mh + mi * 16 + r;
            f32x4 v = acc2[oi][mi] + bv;
            f16x4 ov;
#pragma unroll
            for (int j = 0; j < 4; ++j) { float x = v[j]; ov[j] = (_Float16)((x > 0.f) ? x : 0.f); }
            const int s = ((ol >> 2) ^ (row & 31)) << 2;
            *(f16x4*)(OT + row * 128 + s) = ov;
        }
    }
    __syncthreads();
#pragma unroll
    for (int it2 = 0; it2 < 4; ++it2) {
        const int row = it2 * 16 + (tid >> 4);
        const int c = tid & 15;
        const int s0 = ((c * 2) ^ (row & 31)) << 2;
        const int s1 = ((c * 2 + 1) ^ (row & 31)) << 2;
        f16x4 a  = *(const f16x4*)(OT + row * 128 + s0);
        f16x4 b2 = *(const f16x4*)(OT + row * 128 + s1);
        f16x8 o8;
        o8[0] = a[0]; o8[1] = a[1]; o8[2] = a[2]; o8[3] = a[3];
        o8[4] = b2[0]; o8[5] = b2[1]; o8[6] = b2[2]; o8[7] = b2[3];
        *(f16x8*)(Y + (size_t)(m_blk + row) * 128 + c * 8) = o8;
    }
}

// ---------------- GEMM v7 (256x256, 8-wave, dbuf counted-vmcnt): Wf + Wc1 ----------------
__global__ __launch_bounds__(512, 2) void gemm256(
    const _Float16* __restrict__ W, const _Float16* __restrict__ X,
    _Float16* __restrict__ Y, const float* __restrict__ bias,
    int Kp, int ldX, int ldY, int Opad, int act, int biasPerBatch,
    float* __restrict__ pmax, float* __restrict__ psum)
{
    constexpr int ASZ = 256 * 64;               // A-tile f16 elems (= B-tile)
    __shared__ _Float16 SH[65536];              // 2 x (ASZ + ASZ) = 128KB
    const int tid  = threadIdx.x;
    const int lane = tid & 63, wave = tid >> 6;
    const int r = lane & 15, quad = lane >> 4;
    const int wo = wave & 3, wm = wave >> 2;    // wave: o [wo*64,+64), m [wm*128,+128)
    const int m_blk = blockIdx.x * 256, o_blk = blockIdx.y * 256;
    const int nt = Kp >> 6;

    f32x4 acc[4][8];
#pragma unroll
    for (int a = 0; a < 4; ++a)
#pragma unroll
        for (int c = 0; c < 8; ++c) acc[a][c] = (f32x4){0.f, 0.f, 0.f, 0.f};

    const int srow  = wave * 8 + (lane >> 3);   // 0..63
    const int sslot = lane & 7;

    auto STAGE = [&](int bufi, int k0) {
        _Float16* As = SH + bufi * (2 * ASZ);
        _Float16* Bs = As + ASZ;
#pragma unroll
        for (int t = 0; t < 4; ++t) {           // A: 256 rows, 64/instr
            const int rowA = t * 64 + srow;
            const int gk = k0 + ((sslot ^ (rowA & 7)) << 3);
            const _Float16* gA = W + (size_t)(o_blk + rowA) * Kp + gk;
            __builtin_amdgcn_global_load_lds(
                (const __attribute__((address_space(1))) unsigned int*)gA,
                (__attribute__((address_space(3))) unsigned int*)(As + t * 4096 + wave * 512),
                16, 0, 0);
        }
#pragma unroll
        for (int t = 0; t < 4; ++t) {           // B: 256 rows
            const int rowB = t * 64 + srow;
            const int gk = k0 + ((sslot ^ (rowB & 7)) << 3);
            const _Float16* gB = X + (size_t)(m_blk + rowB) * ldX + gk;
            __builtin_amdgcn_global_load_lds(
                (const __attribute__((address_space(1))) unsigned int*)gB,
                (__attribute__((address_space(3))) unsigned int*)(Bs + t * 4096 + wave * 512),
                16, 0, 0);
        }
    };

    STAGE(0, 0);
    int cur = 0;
    for (int t = 0; t < nt; ++t) {
        if (t + 1 < nt) {
            STAGE(cur ^ 1, (t + 1) << 6);       // issue next tile's loads early
            asm volatile("s_waitcnt vmcnt(8)" ::: "memory");   // drain current tile only
        } else {
            asm volatile("s_waitcnt vmcnt(0)" ::: "memory");
        }
        __builtin_amdgcn_sched_barrier(0);
        __builtin_amdgcn_s_barrier();
        asm volatile("" ::: "memory");          // ds_reads stay BELOW the barrier

        const _Float16* As = SH + cur * (2 * ASZ);
        const _Float16* Bs = As + ASZ;
        __builtin_amdgcn_s_setprio(1);
#pragma unroll
        for (int ks = 0; ks < 2; ++ks) {
            f16x8 af[4], bf[8];
#pragma unroll
            for (int oi = 0; oi < 4; ++oi) {
                const int row = (wo << 6) + (oi << 4) + r;
                const int slot = (ks * 4 + quad) ^ (row & 7);
                af[oi] = *(const f16x8*)(As + row * 64 + slot * 8);
            }
#pragma unroll
            for (int mi = 0; mi < 8; ++mi) {
                const int row = (wm << 7) + (mi << 4) + r;
                const int slot = (ks * 4 + quad) ^ (row & 7);
                bf[mi] = *(const f16x8*)(Bs + row * 64 + slot * 8);
            }
#pragma unroll
            for (int oi = 0; oi < 4; ++oi)
#pragma unroll
                for (int mi = 0; mi < 8; ++mi)
                    acc[oi][mi] = __builtin_amdgcn_mfma_f32_16x16x32_f16(af[oi], bf[mi], acc[oi][mi], 0, 0, 0);
        }
        __builtin_amdgcn_s_setprio(0);
        asm volatile("" ::: "memory");          // ds_reads stay ABOVE the barrier
        __builtin_amdgcn_s_barrier();           // all waves done reading buf[cur]
        cur ^= 1;
    }
    __syncthreads();   // SH reusable as output tile

    // epilogue: stage [256m][256o] f16 tile in LDS (XOR-swizzled), coalesced writeback
    const int bb = biasPerBatch ? (m_blk >> 11) * Opad : 0;
    _Float16* OT = SH;
#pragma unroll
    for (int oi = 0; oi < 4; ++oi) {
        const int ol = (wo << 6) + (oi << 4) + (quad << 2);    // local o, 4-aligned
        const f32x4 bv = *(const f32x4*)(bias + bb + o_blk + ol);
#pragma unroll
        for (int mi = 0; mi < 8; ++mi) {
            const int row = (wm << 7) + (mi << 4) + r;         // local m
            f32x4 v = acc[oi][mi] + bv;
            f16x4 ov;
#pragma unroll
            for (int j = 0; j < 4; ++j) {
                float x = v[j];
                if (act == 1)      x = (x > 0.f) ? x : 0.0f;
                else if (act == 2) x = (x > 0.f) ? x : 0.2f * x;
                ov[j] = (_Float16)x;
            }
            const int s = (ol >> 2) ^ (row & 31);              // swizzled 8B slot (0..63)
            *(f16x4*)(OT + row * 256 + s * 4) = ov;
        }
    }
    __syncthreads();
#pragma unroll
    for (int p2 = 0; p2 < 16; ++p2) {
        const int g = (p2 << 9) + tid;
        const int row = g >> 5, c = g & 31;                    // 32 x 16B granules per row
        const int s0 = ((c << 1)) ^ (row & 31);
        const int s1 = ((c << 1) | 1) ^ (row & 31);
        f16x4 a  = *(const f16x4*)(OT + row * 256 + s0 * 4);
        f16x4 b2 = *(const f16x4*)(OT + row * 256 + s1 * 4);
        f16x8 o8;
        o8[0] = a[0]; o8[1] = a[1]; o8[2] = a[2]; o8[3] = a[3];
        o8[4] = b2[0]; o8[5] = b2[1]; o8[6] = b2[2]; o8[7] = b2[3];
        *(f16x8*)(Y + (size_t)(m_blk + row) * ldY + o_blk + (c << 3)) = o8;
    }

    // fused pooling (Wf only): per-block max/sum over 256 rows of this 256-o slice
    if (pmax) {
        const int cg = tid & 63, h8 = tid >> 6;   // 64 o-granules(4) x 8 row-groups(32)
        float mx0 = -3.4e38f, mx1 = -3.4e38f, mx2 = -3.4e38f, mx3 = -3.4e38f;
        float sm0 = 0.f, sm1 = 0.f, sm2 = 0.f, sm3 = 0.f;
#pragma unroll
        for (int rr = 0; rr < 32; ++rr) {
            const int row = (h8 << 5) + rr;
            const f16x4 v = *(const f16x4*)(OT + row * 256 + ((cg ^ (row & 31)) << 2));
            const float x0 = (float)v[0], x1 = (float)v[1], x2 = (float)v[2], x3 = (float)v[3];
            mx0 = fmaxf(mx0, x0); sm0 += x0;
            mx1 = fmaxf(mx1, x1); sm1 += x1;
            mx2 = fmaxf(mx2, x2); sm2 += x2;
            mx3 = fmaxf(mx3, x3); sm3 += x3;
        }
        __syncthreads();                 // done reading OT; reuse SH as partial buffer
        float* PR = (float*)SH;          // [8 h][256 o][2] f32 = 16KB
        float* pw = PR + (size_t)(((h8 << 8) + (cg << 2)) << 1);
        pw[0] = mx0; pw[1] = sm0; pw[2] = mx1; pw[3] = sm1;
        pw[4] = mx2; pw[5] = sm2; pw[6] = mx3; pw[7] = sm3;
        __syncthreads();
        if (tid < 256) {
            float M = -3.4e38f, S = 0.f;
#pragma unroll
            for (int h2 = 0; h2 < 8; ++h2) {
                M = fmaxf(M, PR[(size_t)(((h2 << 8) + tid) << 1)]);
                S += PR[(size_t)(((h2 << 8) + tid) << 1) + 1];
            }
            const int b2 = m_blk >> 11, mt = (m_blk >> 8) & 7;
            pmax[((size_t)((b2 << 3) + mt) << 10) + o_blk + tid] = M;
            psum[((size_t)((b2 << 3) + mt) << 10) + o_blk + tid] = S;
        }
    }
}

// ---------------- GEMM v5b: TM(64|128) x 128o tile, BK=64, dbuf, counted vmcnt ----------------
template<int TM>
__global__ __launch_bounds__(256) void gemm_tile(
    const _Float16* __restrict__ W, const _Float16* __restrict__ X,
    _Float16* __restrict__ Y, float* __restrict__ Y32,
    const float* __restrict__ bias, const _Float16* __restrict__ Res,
    int Kp, int ldX, int xoff, int ldY, int yoff, int Opad,
    int act, int biasPerBatch, int ldR, int roff, int Olimit)
{
    constexpr int MI = TM / 32;                 // m-frags per wave
    constexpr int ASZ = 128 * 64;               // A-tile f16 elems
    constexpr int BSZ = TM * 64;                // B-tile f16 elems
    __shared__ _Float16 SH[2 * (ASZ + BSZ)];    // double-buffered As|Bs ; reused as output tile

    const int tid  = threadIdx.x;
    const int lane = tid & 63, wave = tid >> 6;
    const int r = lane & 15, quad = lane >> 4;
    const int m_blk = blockIdx.x * TM, o_blk = blockIdx.y * 128;
    const int oh = (wave >> 1) * 64, mh = (wave & 1) * (TM / 2);

    f32x4 acc[4][MI];
#pragma unroll
    for (int a = 0; a < 4; ++a)
#pragma unroll
        for (int c = 0; c < MI; ++c) acc[a][c] = (f32x4){0.f, 0.f, 0.f, 0.f};

    const int srow  = wave * 8 + (lane >> 3);
    const int sslot = lane & 7;

    auto STAGE = [&](int bufi, int k0) {
        _Float16* As = SH + bufi * (ASZ + BSZ);
        _Float16* Bs = As + ASZ;
#pragma unroll
        for (int t = 0; t < 4; ++t) {           // A: 128 rows
            const int rowA = t * 32 + srow;
            const int gk = k0 + ((sslot ^ (rowA & 7)) << 3);
            const _Float16* gA = W + (size_t)(o_blk + rowA) * Kp + gk;
            __builtin_amdgcn_global_load_lds(
                (const __attribute__((address_space(1))) unsigned int*)gA,
                (__attribute__((address_space(3))) unsigned int*)(As + t * 2048 + wave * 512),
                16, 0, 0);
        }
#pragma unroll
        for (int t = 0; t < TM / 32; ++t) {     // B: TM rows
            const int rowB = t * 32 + srow;
            const int gk = k0 + ((sslot ^ (rowB & 7)) << 3);
            const _Float16* gB = X + (size_t)(m_blk + rowB) * ldX + xoff + gk;
            __builtin_amdgcn_global_load_lds(
                (const __attribute__((address_space(1))) unsigned int*)gB,
                (__attribute__((address_space(3))) unsigned int*)(Bs + t * 2048 + wave * 512),
                16, 0, 0);
        }
    };

    const int nt = Kp >> 6;
    STAGE(0, 0);
    int cur = 0;
    for (int t = 0; t < nt; ++t) {
        if (t + 1 < nt) {
            STAGE(cur ^ 1, (t + 1) << 6);       // issue next tile's loads early
            if constexpr (TM == 128) asm volatile("s_waitcnt vmcnt(8)" ::: "memory");
            else                     asm volatile("s_waitcnt vmcnt(6)" ::: "memory");
        } else {
            asm volatile("s_waitcnt vmcnt(0)" ::: "memory");
        }
        __builtin_amdgcn_sched_barrier(0);
        __builtin_amdgcn_s_barrier();
        asm volatile("" ::: "memory");

        const _Float16* As = SH + cur * (ASZ + BSZ);
        const _Float16* Bs = As + ASZ;
        __builtin_amdgcn_s_setprio(1);
#pragma unroll
        for (int ks = 0; ks < 2; ++ks) {
            f16x8 af[4], bf[MI];
#pragma unroll
            for (int oi = 0; oi < 4; ++oi) {
                const int row = oh + oi * 16 + r;
                const int slot = (ks * 4 + quad) ^ (row & 7);
                af[oi] = *(const f16x8*)(As + row * 64 + slot * 8);
            }
#pragma unroll
            for (int mi = 0; mi < MI; ++mi) {
                const int row = mh + mi * 16 + r;
                const int slot = (ks * 4 + quad) ^ (row & 7);
                bf[mi] = *(const f16x8*)(Bs + row * 64 + slot * 8);
            }
#pragma unroll
            for (int oi = 0; oi < 4; ++oi)
#pragma unroll
                for (int mi = 0; mi < MI; ++mi)
                    acc[oi][mi] = __builtin_amdgcn_mfma_f32_16x16x32_f16(af[oi], bf[mi], acc[oi][mi], 0, 0, 0);
        }
        __builtin_amdgcn_s_setprio(0);
        asm volatile("" ::: "memory");
        __builtin_amdgcn_s_barrier();
        cur ^= 1;
    }

    const int bb = biasPerBatch ? (m_blk >> 11) * Opad : 0;
    __syncthreads();   // done reading As/Bs; SH is reusable

    if (Y32) {
        // f32 path: store transposed to (B, 50, N): Y32[(b*50+o)*2048 + n], o < Olimit
#pragma unroll
        for (int oi = 0; oi < 4; ++oi) {
            const int og = o_blk + oh + oi * 16 + quad * 4;
            const f32x4 bv = *(const f32x4*)(bias + bb + og);
#pragma unroll
            for (int mi = 0; mi < MI; ++mi) {
                const int m = m_blk + mh + mi * 16 + r;
                const int bidx = m >> 11, n = m & 2047;
                f32x4 v = acc[oi][mi] + bv;
#pragma unroll
                for (int j = 0; j < 4; ++j) {
                    float x = v[j];
                    if (act == 1)      x = (x > 0.f) ? x : 0.0f;
                    else if (act == 2) x = (x > 0.f) ? x : 0.2f * x;
                    const int o = og + j;
                    if (o < Olimit)
                        Y32[((size_t)(bidx * 50 + o) << 11) + n] = x;
                }
            }
        }
        return;
    }

    // f16 path: stage [TM][128] tile in LDS (XOR-swizzled), then coalesced writeback
    _Float16* OT = SH;
#pragma unroll
    for (int oi = 0; oi < 4; ++oi) {
        const int ol = oh + oi * 16 + quad * 4;       // local o (0..127), 4-aligned
        const f32x4 bv = *(const f32x4*)(bias + bb + o_blk + ol);
#pragma unroll
        for (int mi = 0; mi < MI; ++mi) {
            const int row = mh + mi * 16 + r;         // local m
            f32x4 v = acc[oi][mi] + bv;
            if (Res) {
                f16x4 rr = *(const f16x4*)(Res + (size_t)(m_blk + row) * ldR + roff + o_blk + ol);
#pragma unroll
                for (int j = 0; j < 4; ++j) v[j] += (float)rr[j];
            }
            f16x4 ov;
#pragma unroll
            for (int j = 0; j < 4; ++j) {
                float x = v[j];
                if (act == 1)      x = (x > 0.f) ? x : 0.0f;
                else if (act == 2) x = (x > 0.f) ? x : 0.2f * x;
                ov[j] = (_Float16)x;
            }
            const int s = ((ol >> 2) ^ (row & 31)) << 2;   // swizzled 8B slot
            *(f16x4*)(OT + row * 128 + s) = ov;
        }
    }
    __syncthreads();
#pragma unroll
    for (int it2 = 0; it2 < TM / 16; ++it2) {
        const int row = it2 * 16 + (tid >> 4);
        const int c = tid & 15;                        // 8 f16 per lane, contiguous
        const int s0 = ((c * 2) ^ (row & 31)) << 2;
        const int s1 = ((c * 2 + 1) ^ (row & 31)) << 2;
        f16x4 a = *(const f16x4*)(OT + row * 128 + s0);
        f16x4 b2 = *(const f16x4*)(OT + row * 128 + s1);
        f16x8 o8;
        o8[0] = a[0]; o8[1] = a[1]; o8[2] = a[2]; o8[3] = a[3];
        o8[4] = b2[0]; o8[5] = b2[1]; o8[6] = b2[2]; o8[7] = b2[3];
        *(f16x8*)(Y + (size_t)(m_blk + row) * ldY + yoff + o_blk + c * 8) = o8;
    }
}

// ---------------- neighbor gather + channel max (relu outputs => ushort-monotonic f16 bits) ----------------
typedef short s16x8 __attribute__((ext_vector_type(8)));
__global__ __launch_bounds__(256) void gather_max_kernel(
    const short* __restrict__ T, const int* __restrict__ idx, short* __restrict__ Mo)
{
    const int tid = threadIdx.x;
    const int p = blockIdx.x * 16 + (tid >> 4);
    const int l = tid & 15;
    const int b = p >> 11;
    const int* ip = idx + (size_t)p * 16;
    size_t row = (size_t)((b << 11) + ip[0]);
    s16x8 cur = *(const s16x8*)(T + row * 128 + l * 8);
    unsigned short best[8];
#pragma unroll
    for (int e = 0; e < 8; ++e) best[e] = (unsigned short)cur[e];
#pragma unroll
    for (int j = 1; j < 16; ++j) {
        row = (size_t)((b << 11) + ip[j]);
        s16x8 v = *(const s16x8*)(T + row * 128 + l * 8);
#pragma unroll
        for (int e = 0; e < 8; ++e) {
            unsigned short u = (unsigned short)v[e];
            if (u > best[e]) best[e] = u;
        }
    }
    s16x8 ov;
#pragma unroll
    for (int e = 0; e < 8; ++e) ov[e] = (short)best[e];
    *(s16x8*)(Mo + (size_t)p * 128 + l * 8) = ov;
}

// ---------------- per-batch constant vector for Wc1 (absorbs reduce2 + label path) ----------------
__global__ __launch_bounds__(256) void cvec_kernel(
    const float* __restrict__ label, const float* __restrict__ Wl, const float* __restrict__ gl, const float* __restrict__ bl,
    const float* __restrict__ Wc1, const float* __restrict__ bc1, const float* __restrict__ gc1, const float* __restrict__ bb1,
    const float* __restrict__ pmax, const float* __restrict__ psum, float* __restrict__ cvec)
{
    __shared__ float v[2112];
    __shared__ float red[256];
    const int b = blockIdx.x, og = blockIdx.y, tid = threadIdx.x;
    for (int i = tid; i < 1024; i += 256) {
        float mx = -3.4e38f, sm = 0.f;
#pragma unroll
        for (int c = 0; c < 8; ++c) {
            mx = fmaxf(mx, pmax[((size_t)(b * 8 + c) << 10) + i]);
            sm += psum[((size_t)(b * 8 + c) << 10) + i];
        }
        v[i] = mx;
        v[1024 + i] = sm * (1.f / 2048.f);
    }
    if (tid < 64) {
        float s = 0.f;
        for (int i = 0; i < 16; ++i) s += Wl[tid * 16 + i] * label[b * 16 + i];
        s = gl[tid] * s + bl[tid];
        v[2048 + tid] = (s > 0.f) ? s : 0.2f * s;
    }
    __syncthreads();
    const int o = og * 64 + (tid >> 2), part = tid & 3;
    const float* wrow = Wc1 + (size_t)o * 3136 + 1024 + part * 528;
    float s = 0.f;
    for (int j = 0; j < 528; ++j) s += wrow[j] * v[part * 528 + j];
    red[tid] = s;
    __syncthreads();
    if (part == 0) {
        float tot = red[tid] + red[tid + 1] + red[tid + 2] + red[tid + 3];
        cvec[((size_t)b << 9) + o] = gc1[o] * (tot + bc1[o]) + bb1[o];
    }
}

// ---------------- launch ----------------
extern "C" void kernel_launch(void* const* d_in, const int* in_sizes, int n_in,
                              void* d_out, int out_size, void* d_ws, size_t ws_size,
                              hipStream_t stream)
{
    (void)in_sizes; (void)n_in; (void)out_size; (void)ws_size;
    const float* points = (const float*)d_in[0];
    const float* label  = (const float*)d_in[1];
    const float* We1 = (const float*)d_in[2];
    const float* ge1 = (const float*)d_in[3];
    const float* be1 = (const float*)d_in[4];
    const float* We2 = (const float*)d_in[5];
    const float* ge2 = (const float*)d_in[6];
    const float* be2 = (const float*)d_in[7];
    const float* W1  = (const float*)d_in[8];
    const float* g1  = (const float*)d_in[9];
    const float* b1  = (const float*)d_in[10];
    const float* W2  = (const float*)d_in[11];
    const float* g2  = (const float*)d_in[12];
    const float* b2  = (const float*)d_in[13];
    const float* Wf  = (const float*)d_in[14];
    const float* gf  = (const float*)d_in[15];
    const float* bfv = (const float*)d_in[16];
    const float* Wl  = (const float*)d_in[17];
    const float* gl  = (const float*)d_in[18];
    const float* bl  = (const float*)d_in[19];
    const float* Wc1 = (const float*)d_in[20];
    const float* bc1 = (const float*)d_in[21];
    const float* gc1 = (const float*)d_in[22];
    const float* bb1 = (const float*)d_in[23];
    const float* Wc2 = (const float*)d_in[24];
    const float* bc2 = (const float*)d_in[25];
    const float* gc2 = (const float*)d_in[26];
    const float* bb2 = (const float*)d_in[27];
    const float* Wc3 = (const float*)d_in[28];
    const float* bc3 = (const float*)d_in[29];

    char* ws = (char*)d_ws;
    _Float16* hT  = (_Float16*)(ws + OFF_HT);
    _Float16* tT  = (_Float16*)(ws + OFF_TT);
    _Float16* mT  = (_Float16*)(ws + OFF_MT);
    _Float16* xct = (_Float16*)(ws + OFF_XCAT);
    _Float16* xf  = (_Float16*)(ws + OFF_XF);
    _Float16* c1  = (_Float16*)(ws + OFF_C1);
    _Float16* c2  = (_Float16*)(ws + OFF_C2);
    int*      idx = (int*)     (ws + OFF_IDX);
    _Float16* x0  = (_Float16*)(ws + OFF_X0);

    _Float16* wE1 = (_Float16*)(ws + OFF_WE1);
    _Float16* wE2 = (_Float16*)(ws + OFF_WE2);
    _Float16* w1f = (_Float16*)(ws + OFF_W1);
    _Float16* w2f = (_Float16*)(ws + OFF_W2);
    _Float16* wF  = (_Float16*)(ws + OFF_WF);
    _Float16* wC1 = (_Float16*)(ws + OFF_WC1);
    _Float16* wC2 = (_Float16*)(ws + OFF_WC2);
    _Float16* wC3 = (_Float16*)(ws + OFF_WC3);
    float* bC2 = (float*)(ws + OFF_BC2);
    float* bC3 = (float*)(ws + OFF_BC3);
    float* cv  = (float*)(ws + OFF_CVEC);
    float* pmx = (float*)(ws + OFF_PMAX);
    float* psm = (float*)(ws + OFF_PSUM);

    // prep (weights + biases + x0, one launch)
    fold_all_kernel<<<dim3(4834), 256, 0, stream>>>(We1, ge1, We2, ge2, W1, g1, W2, g2,
                                                    Wf, gf, Wc1, gc1, Wc2, gc2, Wc3,
                                                    gc2, bc2, bb2, bc3, points, ws);
    knn_kernel<<<dim3(BB, NN / 32), 256, 0, stream>>>(points, idx);

    // fused e1+e2: x0 -> (t in LDS) -> hT, both relu
    e12_kernel<<<dim3(512), 256, 0, stream>>>(wE1, wE2, x0, hT, be1, be2);

    for (int i = 0; i < 3; ++i) {
        const _Float16* hin = (i == 0) ? hT : xct;
        int ldH  = (i == 0) ? 128 : 384;
        int offH = (i == 0) ? 0 : (i - 1) * 128;
        // t = relu(bn(W1 h))
        gemm_tile<64><<<dim3(512, 1), 256, 0, stream>>>(w1f + (size_t)i * 16384, hin, tT, nullptr, b1 + i * 128, nullptr,
                                                        128, ldH, offH, 128, 0, 128, 1, 0, 0, 0, 128);
        // m = neighbor max
        gather_max_kernel<<<dim3(MM / 16), 256, 0, stream>>>((const short*)tT, idx, (short*)mT);
        // h' = relu(bn(W2 m) + h) -> xcat slice i
        gemm_tile<64><<<dim3(512, 1), 256, 0, stream>>>(w2f + (size_t)i * 16384, mT, xct, nullptr, b2 + i * 128, hin,
                                                        128, 128, 0, 384, i * 128, 128, 1, 0, ldH, offH, 128);
    }

    // xf = leaky(bn(Wf xcat)) with fused pooling partials (max/sum per 256-row tile)
    gemm256<<<dim3(128, 4), 512, 0, stream>>>(wF, xct, xf, bfv, 384, 384, 1024, 1024, 2, 0, pmx, psm);

    // per-batch classifier constant (absorbs pooled stats + label path)
    cvec_kernel<<<dim3(BB, 8), 256, 0, stream>>>(label, Wl, gl, bl, Wc1, bc1, gc1, bb1, pmx, psm, cv);

    // c1 = relu(gc1*Wc1[:, :1024] xf + cvec[b])
    gemm256<<<dim3(128, 2), 512, 0, stream>>>(wC1, xf, c1, cv, 1024, 1024, 512, 512, 1, 1, nullptr, nullptr);

    // c2 = relu(bn(Wc2 c1 + bc2))
    gemm_tile<128><<<dim3(256, 2), 256, 0, stream>>>(wC2, c1, c2, nullptr, bC2, nullptr, 512, 512, 0, 256, 0, 256, 1, 0, 0, 0, 256);
    // c3 = Wc3 c2 + bc3 (no act), f32, stored transposed directly to (B,50,N) output
    gemm_tile<128><<<dim3(256, 1), 256, 0, stream>>>(wC3, c2, nullptr, (float*)d_out, bC3, nullptr, 256, 256, 0, 0, 0, 128, 0, 0, 0, 0, 50);
}

// Round 9
// 368.920 us; speedup vs baseline: 1.0876x; 1.0279x over previous
//
#include <hip/hip_runtime.h>
#include <cstdint>
#include <cstddef>

#define DEVINL __device__ __forceinline__

typedef float    f32x4 __attribute__((ext_vector_type(4)));
typedef _Float16 f16x8 __attribute__((ext_vector_type(8)));
typedef _Float16 f16x4 __attribute__((ext_vector_type(4)));

// ---------------- constants ----------------
constexpr int BB = 16, NN = 2048, MM = 32768;

// ---------------- ws layout (bytes) ----------------
constexpr size_t OFF_WE1 = 0;                           // 128x64 f16 (Kp padded 6->64)
constexpr size_t OFF_WE2 = OFF_WE1 + 128 * 64 * 2;
constexpr size_t OFF_W1  = OFF_WE2 + 128 * 128 * 2;
constexpr size_t OFF_W2  = OFF_W1  + 3 * 128 * 128 * 2;
constexpr size_t OFF_WF  = OFF_W2  + 3 * 128 * 128 * 2;
constexpr size_t OFF_WC1 = OFF_WF  + 1024 * 384 * 2;
constexpr size_t OFF_WC2 = OFF_WC1 + 512 * 1024 * 2;
constexpr size_t OFF_WC3 = OFF_WC2 + 256 * 512 * 2;     // 128x256 (Opad 50->128)
constexpr size_t OFF_BC2 = OFF_WC3 + 128 * 256 * 2;     // 256 f32
constexpr size_t OFF_BC3 = OFF_BC2 + 256 * 4;           // 128 f32
constexpr size_t OFF_CVEC= OFF_BC3 + 128 * 4;           // 16x512 f32
constexpr size_t OFF_PMAX= OFF_CVEC+ 16 * 512 * 4;      // 16 b x 8 mtile x 1024 o f32 (256-row tiles)
constexpr size_t OFF_PSUM= OFF_PMAX+ 16 * 16 * 1024 * 4;
constexpr size_t OFF_IDX = OFF_PSUM+ 16 * 16 * 1024 * 4;
constexpr size_t OFF_R1  = 8ull << 20;                  // > OFF_IDX + 2MB
constexpr size_t OFF_X0  = OFF_R1;                      // 4MB  (M x 64 f16, k-padded)
constexpr size_t OFF_HT  = OFF_R1 + (4ull  << 20);      // 8MB  (M x 128 f16)
constexpr size_t OFF_TT  = OFF_R1 + (12ull << 20);      // 8MB
constexpr size_t OFF_MT  = OFF_R1 + (20ull << 20);      // 8MB
constexpr size_t OFF_C1  = OFF_R1;                      // 32MB (M x 512 f16), aliases x0/h/t/m (dead)
constexpr size_t OFF_XCAT= OFF_R1 + (32ull << 20);      // 24MB (M x 384 f16)
constexpr size_t OFF_C2  = OFF_XCAT;                    // 16MB (M x 256 f16), aliases xcat (dead)
constexpr size_t OFF_XF  = OFF_XCAT + (24ull << 20);    // 64MB (M x 1024 f16)

// ---------------- fold-all: weights (f16, BN-folded), biases, x0 prep ----------------
__global__ __launch_bounds__(256) void fold_all_kernel(
    const float* We1, const float* ge1, const float* We2, const float* ge2,
    const float* W1,  const float* g1,  const float* W2,  const float* g2,
    const float* Wf,  const float* gf,  const float* Wc1, const float* gc1,
    const float* Wc2, const float* gc2, const float* Wc3,
    const float* gc2b, const float* bc2, const float* bb2, const float* bc3,
    const float* pts, char* ws)
{
    const int bid = blockIdx.x;
    const int tid = threadIdx.x;

    if (bid == 4704) {
        ((float*)(ws + OFF_BC2))[tid] = gc2b[tid] * bc2[tid] + bb2[tid];
        return;
    }
    if (bid == 4705) {
        if (tid < 128) ((float*)(ws + OFF_BC3))[tid] = (tid < 50) ? bc3[tid] : 0.f;
        return;
    }
    if (bid >= 4706) {           // x0 prep: (B,6,N) f32 -> (M x 64) f16 K-contig, zero pad
        int m = (bid - 4706) * 256 + tid;
        int b = m >> 11, n = m & 2047;
        const float* ps = pts + (size_t)b * 6 * 2048 + n;
        _Float16 tmp[64];
#pragma unroll
        for (int c = 0; c < 64; ++c) tmp[c] = (_Float16)0.f;
#pragma unroll
        for (int c = 0; c < 6; ++c) tmp[c] = (_Float16)ps[(size_t)c << 11];
        _Float16* dst = (_Float16*)(ws + OFF_X0) + (size_t)m * 64;
#pragma unroll
        for (int v = 0; v < 8; ++v) *(f16x8*)(dst + v * 8) = *(const f16x8*)(tmp + v * 8);
        return;
    }

    int id, base;
    if      (bid < 32)   { id = 0;  base = 0;    }
    else if (bid < 96)   { id = 1;  base = 32;   }
    else if (bid < 160)  { id = 2;  base = 96;   }
    else if (bid < 224)  { id = 3;  base = 160;  }
    else if (bid < 288)  { id = 4;  base = 224;  }
    else if (bid < 352)  { id = 5;  base = 288;  }
    else if (bid < 416)  { id = 6;  base = 352;  }
    else if (bid < 480)  { id = 7;  base = 416;  }
    else if (bid < 2016) { id = 8;  base = 480;  }
    else if (bid < 4064) { id = 9;  base = 2016; }
    else if (bid < 4576) { id = 10; base = 4064; }
    else                 { id = 11; base = 4576; }

    const float* src = nullptr; const float* g = nullptr; _Float16* dst = nullptr;
    int O = 0, K = 0, lds = 0, Kp = 0;
    switch (id) {
        case 0:  src = We1; g = ge1; O = 128; K = 6;    lds = 6;    Kp = 64;   dst = (_Float16*)(ws + OFF_WE1); break;
        case 1:  src = We2; g = ge2; O = 128; K = 128;  lds = 128;  Kp = 128;  dst = (_Float16*)(ws + OFF_WE2); break;
        case 2: case 3: case 4: {
            int i = id - 2;
            src = W1 + (size_t)i * 16384; g = g1 + i * 128; O = 128; K = 128; lds = 128; Kp = 128;
            dst = (_Float16*)(ws + OFF_W1) + (size_t)i * 16384; break; }
        case 5: case 6: case 7: {
            int i = id - 5;
            src = W2 + (size_t)i * 16384; g = g2 + i * 128; O = 128; K = 128; lds = 128; Kp = 128;
            dst = (_Float16*)(ws + OFF_W2) + (size_t)i * 16384; break; }
        case 8:  src = Wf;  g = gf;  O = 1024; K = 384;  lds = 384;  Kp = 384;  dst = (_Float16*)(ws + OFF_WF);  break;
        case 9:  src = Wc1; g = gc1; O = 512;  K = 1024; lds = 3136; Kp = 1024; dst = (_Float16*)(ws + OFF_WC1); break;
        case 10: src = Wc2; g = gc2; O = 256;  K = 512;  lds = 512;  Kp = 512;  dst = (_Float16*)(ws + OFF_WC2); break;
        default: src = Wc3; g = nullptr; O = 50; K = 256; lds = 256; Kp = 256;  dst = (_Float16*)(ws + OFF_WC3); break;
    }
    int e = (bid - base) * 256 + tid;
    int o = e / Kp, k = e - o * Kp;
    float v = 0.f;
    if (o < O && k < K) {
        v = src[(size_t)o * lds + k];
        if (g) v *= g[o];
    }
    dst[e] = (_Float16)v;
}

// ---------------- KNN v8: top-4 bound pass -> survivor buffer -> exact select ----------------
DEVINL float knn_dist(const float4 pq, const float4 pm) {
    float t = pq.x * pm.x;
    t = fmaf(pq.y, pm.y, t);
    t = fmaf(pq.z, pm.z, t);
    return fmaf(-2.f, t, pm.w);
}

#define KNN_DINS(X) do { \
    const float x_ = (X); \
    d15 = __builtin_amdgcn_fmed3f(x_, d14, d15); \
    d14 = __builtin_amdgcn_fmed3f(x_, d13, d14); \
    d13 = __builtin_amdgcn_fmed3f(x_, d12, d13); \
    d12 = __builtin_amdgcn_fmed3f(x_, d11, d12); \
    d11 = __builtin_amdgcn_fmed3f(x_, d10, d11); \
    d10 = __builtin_amdgcn_fmed3f(x_, d9,  d10); \
    d9  = __builtin_amdgcn_fmed3f(x_, d8,  d9);  \
    d8  = __builtin_amdgcn_fmed3f(x_, d7,  d8);  \
    d7  = __builtin_amdgcn_fmed3f(x_, d6,  d7);  \
    d6  = __builtin_amdgcn_fmed3f(x_, d5,  d6);  \
    d5  = __builtin_amdgcn_fmed3f(x_, d4,  d5);  \
    d4  = __builtin_amdgcn_fmed3f(x_, d3,  d4);  \
    d3  = __builtin_amdgcn_fmed3f(x_, d2,  d3);  \
    d2  = __builtin_amdgcn_fmed3f(x_, d1,  d2);  \
    d1  = __builtin_amdgcn_fmed3f(x_, d0,  d1);  \
    d0  = __builtin_amdgcn_fmed3f(x_, -3.4e38f, d0); \
} while (0)

// compare-exchange (ascending)
#define KNN_CE(A, B) { const float lo_ = fminf(A, B), hi_ = fmaxf(A, B); A = lo_; B = hi_; }

// merge own ascending d0..d15 with lane^OFF's ascending list, keep lowest 16 sorted.
#define KNN_MERGE(OFF) do { \
    const float n0  = __shfl_xor(d0,  OFF), n1  = __shfl_xor(d1,  OFF), \
                n2  = __shfl_xor(d2,  OFF), n3  = __shfl_xor(d3,  OFF), \
                n4  = __shfl_xor(d4,  OFF), n5  = __shfl_xor(d5,  OFF), \
                n6  = __shfl_xor(d6,  OFF), n7  = __shfl_xor(d7,  OFF), \
                n8  = __shfl_xor(d8,  OFF), n9  = __shfl_xor(d9,  OFF), \
                n10 = __shfl_xor(d10, OFF), n11 = __shfl_xor(d11, OFF), \
                n12 = __shfl_xor(d12, OFF), n13 = __shfl_xor(d13, OFF), \
                n14 = __shfl_xor(d14, OFF), n15 = __shfl_xor(d15, OFF); \
    d0  = fminf(d0,  n15); d1  = fminf(d1,  n14); d2  = fminf(d2,  n13); d3  = fminf(d3,  n12); \
    d4  = fminf(d4,  n11); d5  = fminf(d5,  n10); d6  = fminf(d6,  n9);  d7  = fminf(d7,  n8);  \
    d8  = fminf(d8,  n7);  d9  = fminf(d9,  n6);  d10 = fminf(d10, n5);  d11 = fminf(d11, n4);  \
    d12 = fminf(d12, n3);  d13 = fminf(d13, n2);  d14 = fminf(d14, n1);  d15 = fminf(d15, n0);  \
    KNN_CE(d0, d8)  KNN_CE(d1, d9)  KNN_CE(d2, d10) KNN_CE(d3, d11) \
    KNN_CE(d4, d12) KNN_CE(d5, d13) KNN_CE(d6, d14) KNN_CE(d7, d15) \
    KNN_CE(d0, d4)  KNN_CE(d1, d5)  KNN_CE(d2, d6)  KNN_CE(d3, d7)  \
    KNN_CE(d8, d12) KNN_CE(d9, d13) KNN_CE(d10,d14) KNN_CE(d11,d15) \
    KNN_CE(d0, d2)  KNN_CE(d1, d3)  KNN_CE(d4, d6)  KNN_CE(d5, d7)  \
    KNN_CE(d8, d10) KNN_CE(d9, d11) KNN_CE(d12,d14) KNN_CE(d13,d15) \
    KNN_CE(d0, d1)  KNN_CE(d2, d3)  KNN_CE(d4, d5)  KNN_CE(d6, d7)  \
    KNN_CE(d8, d9)  KNN_CE(d10,d11) KNN_CE(d12,d13) KNN_CE(d14,d15) \
} while (0)

__global__ __launch_bounds__(256) void knn_kernel(const float* __restrict__ pts, int* __restrict__ idxout)
{
    __shared__ float4 P[2048];              // 32KB, stays intact for all passes
    __shared__ unsigned short buf[32][96];  // 6KB survivor indices per query
    __shared__ int cnt[32];
    __shared__ int wcnt[32];
    const int tid = threadIdx.x;
    const int b = blockIdx.x;
    const float* pb = pts + (size_t)b * 6 * 2048;
    for (int i = tid; i < 2048; i += 256) {
        float x = pb[i];
        float y = pb[2048 + i];
        float z = pb[4096 + i];
        P[i] = make_float4(x, y, z, x * x + y * y + z * z);
    }
    if (tid < 32) { cnt[tid] = 0; wcnt[tid] = 0; }
    __syncthreads();

    const int p = tid & 7;          // candidate partition (m == 8*it + p)
    const int g = tid >> 3;         // query within block (0..31); group = 8 consecutive lanes
    const int q = blockIdx.y * 32 + g;
    const float4 pq = P[q];

    // ---- pass 1: per-lane top-4 over this lane's 256-candidate partition ----
    float d0 = 3.4e38f, d1 = 3.4e38f, d2 = 3.4e38f, d3 = 3.4e38f;
#pragma unroll 4
    for (int it = 0; it < 256; ++it) {
        const float4 pm = P[it * 8 + p];
        const float x = knn_dist(pq, pm);
        d3 = __builtin_amdgcn_fmed3f(x, d2, d3);
        d2 = __builtin_amdgcn_fmed3f(x, d1, d2);
        d1 = __builtin_amdgcn_fmed3f(x, d0, d1);
        d0 = fminf(x, d0);
    }
    float d4 = 3.4e38f, d5 = 3.4e38f, d6 = 3.4e38f, d7 = 3.4e38f,
          d8 = 3.4e38f, d9 = 3.4e38f, d10 = 3.4e38f, d11 = 3.4e38f,
          d12 = 3.4e38f, d13 = 3.4e38f, d14 = 3.4e38f, d15 = 3.4e38f;
    KNN_MERGE(1);
    KNN_MERGE(2);
    KNN_MERGE(4);
    const float tub = d15;          // 16th-smallest of union of top-4s; tub >= d*

    // ---- pass 2: collect survivor indices (d <= tub) ----
#pragma unroll 4
    for (int it = 0; it < 256; ++it) {
        const int m = it * 8 + p;
        const float d = knn_dist(pq, P[m]);
        if (d <= tub) {
            const int pos = atomicAdd(&cnt[g], 1);
            if (pos < 96) buf[g][pos] = (unsigned short)m;
        }
    }
    int C = cnt[g];                 // same-wave LDS ops: no barrier needed
    if (C > 96) C = 96;

    // ---- pass 3: exact top-16 among the C survivors (8 lanes split them) ----
    d0 = 3.4e38f; d1 = 3.4e38f; d2 = 3.4e38f; d3 = 3.4e38f;
    d4 = 3.4e38f; d5 = 3.4e38f; d6 = 3.4e38f; d7 = 3.4e38f;
    d8 = 3.4e38f; d9 = 3.4e38f; d10 = 3.4e38f; d11 = 3.4e38f;
    d12 = 3.4e38f; d13 = 3.4e38f; d14 = 3.4e38f; d15 = 3.4e38f;
    for (int j = p; j < C; j += 8) {
        const int m = buf[g][j];
        const float x = knn_dist(pq, P[m]);
        KNN_DINS(x);
    }
    KNN_MERGE(1);
    KNN_MERGE(2);
    KNN_MERGE(4);
    const float t = d15;            // exact 16th-smallest distance

    // ---- final write: survivors with d <= t, capped at 16 (tie-arbitrary, as before) ----
    int* op = idxout + (((size_t)(b << 11) + q) << 4);
    for (int j = p; j < C; j += 8) {
        const int m = buf[g][j];
        const float d = knn_dist(pq, P[m]);
        if (d <= t) {
            const int pos = atomicAdd(&wcnt[g], 1);
            if (pos < 16) op[pos] = m;   // order-scrambled: consumer is a max over the set
        }
    }
}

// ---------------- fused e1+e2: h = relu(We2 · relu(We1 · x0)) ; t stays in LDS ----------------
__global__ __launch_bounds__(256) void e12_kernel(
    const _Float16* __restrict__ W1e, const _Float16* __restrict__ W2e,
    const _Float16* __restrict__ X, _Float16* __restrict__ Y,
    const float* __restrict__ b1v, const float* __restrict__ b2v)
{
    __shared__ _Float16 SH[36864];
    _Float16* A1s = SH;             // 8192  (We1 128x64)
    _Float16* B1s = SH + 8192;      // 4096  (x0 64x64)
    _Float16* A2s = SH + 12288;     // 16384 (We2 128x128, 2 ktiles)
    _Float16* B2s = SH + 28672;     // 8192  (t 64x128, 2 ktiles)

    const int tid = threadIdx.x;
    const int lane = tid & 63, wave = tid >> 6;
    const int r = lane & 15, quad = lane >> 4;
    const int m_blk = blockIdx.x * 64;
    const int oh = (wave >> 1) * 64, mh = (wave & 1) * 32;

    const int srow  = wave * 8 + (lane >> 3);
    const int sslot = lane & 7;

    // stage A1 (4), B1 (2), A2 (8) — A2 lands under GEMM1
#pragma unroll
    for (int t = 0; t < 4; ++t) {
        const int row = t * 32 + srow;
        const int gk = (sslot ^ (row & 7)) << 3;
        __builtin_amdgcn_global_load_lds(
            (const __attribute__((address_space(1))) unsigned int*)(W1e + (size_t)row * 64 + gk),
            (__attribute__((address_space(3))) unsigned int*)(A1s + t * 2048 + wave * 512),
            16, 0, 0);
    }
#pragma unroll
    for (int t = 0; t < 2; ++t) {
        const int row = t * 32 + srow;
        const int gk = (sslot ^ (row & 7)) << 3;
        __builtin_amdgcn_global_load_lds(
            (const __attribute__((address_space(1))) unsigned int*)(X + (size_t)(m_blk + row) * 64 + gk),
            (__attribute__((address_space(3))) unsigned int*)(B1s + t * 2048 + wave * 512),
            16, 0, 0);
    }
#pragma unroll
    for (int kt = 0; kt < 2; ++kt)
#pragma unroll
        for (int t = 0; t < 4; ++t) {
            const int row = t * 32 + srow;
            const int gk = kt * 64 + ((sslot ^ (row & 7)) << 3);
            __builtin_amdgcn_global_load_lds(
                (const __attribute__((address_space(1))) unsigned int*)(W2e + (size_t)row * 128 + gk),
                (__attribute__((address_space(3))) unsigned int*)(A2s + kt * 8192 + t * 2048 + wave * 512),
                16, 0, 0);
        }

    asm volatile("s_waitcnt vmcnt(8)" ::: "memory");   // A1+B1 landed; A2 still in flight
    __builtin_amdgcn_sched_barrier(0);
    __builtin_amdgcn_s_barrier();
    asm volatile("" ::: "memory");

    // GEMM1: t[m][o] = We1·x0
    f32x4 acc1[4][2];
#pragma unroll
    for (int a = 0; a < 4; ++a)
#pragma unroll
        for (int c = 0; c < 2; ++c) acc1[a][c] = (f32x4){0.f, 0.f, 0.f, 0.f};
#pragma unroll
    for (int ks = 0; ks < 2; ++ks) {
        f16x8 af[4], bf[2];
#pragma unroll
        for (int oi = 0; oi < 4; ++oi) {
            const int row = oh + oi * 16 + r;
            const int slot = (ks * 4 + quad) ^ (row & 7);
            af[oi] = *(const f16x8*)(A1s + row * 64 + slot * 8);
        }
#pragma unroll
        for (int mi = 0; mi < 2; ++mi) {
            const int row = mh + mi * 16 + r;
            const int slot = (ks * 4 + quad) ^ (row & 7);
            bf[mi] = *(const f16x8*)(B1s + row * 64 + slot * 8);
        }
#pragma unroll
        for (int oi = 0; oi < 4; ++oi)
#pragma unroll
            for (int mi = 0; mi < 2; ++mi)
                acc1[oi][mi] = __builtin_amdgcn_mfma_f32_16x16x32_f16(af[oi], bf[mi], acc1[oi][mi], 0, 0, 0);
    }

    // epilogue1: relu(acc1+b1) -> B2s in staged-B layout (chunk c stored at slot c^(row&7))
#pragma unroll
    for (int oi = 0; oi < 4; ++oi) {
        const int ob = oh + oi * 16 + quad * 4;        // t-channel = GEMM2 k, 0..127
        const f32x4 bv = *(const f32x4*)(b1v + ob);
        const int kt = ob >> 6, kk = ob & 63;
        const int chunk = kk >> 3, within = kk & 7;    // within in {0,4}
#pragma unroll
        for (int mi = 0; mi < 2; ++mi) {
            const int row = mh + mi * 16 + r;
            f32x4 v = acc1[oi][mi] + bv;
            f16x4 ov;
#pragma unroll
            for (int j = 0; j < 4; ++j) { float x = v[j]; ov[j] = (_Float16)((x > 0.f) ? x : 0.f); }
            *(f16x4*)(B2s + kt * 4096 + row * 64 + ((chunk ^ (row & 7)) << 3) + within) = ov;
        }
    }
    __syncthreads();   // B2s visible to all; full waitcnt also drains A2's loads

    // GEMM2: h[m][o2] = We2·t
    f32x4 acc2[4][2];
#pragma unroll
    for (int a = 0; a < 4; ++a)
#pragma unroll
        for (int c = 0; c < 2; ++c) acc2[a][c] = (f32x4){0.f, 0.f, 0.f, 0.f};
#pragma unroll
    for (int kt = 0; kt < 2; ++kt)
#pragma unroll
        for (int ks = 0; ks < 2; ++ks) {
            f16x8 af[4], bf[2];
#pragma unroll
            for (int oi = 0; oi < 4; ++oi) {
                const int row = oh + oi * 16 + r;
                const int slot = (ks * 4 + quad) ^ (row & 7);
                af[oi] = *(const f16x8*)(A2s + kt * 8192 + row * 64 + slot * 8);
            }
#pragma unroll
            for (int mi = 0; mi < 2; ++mi) {
                const int row = mh + mi * 16 + r;
                const int slot = (ks * 4 + quad) ^ (row & 7);
                bf[mi] = *(const f16x8*)(B2s + kt * 4096 + row * 64 + slot * 8);
            }
#pragma unroll
            for (int oi = 0; oi < 4; ++oi)
#pragma unroll
                for (int mi = 0; mi < 2; ++mi)
                    acc2[oi][mi] = __builtin_amdgcn_mfma_f32_16x16x32_f16(af[oi], bf[mi], acc2[oi][mi], 0, 0, 0);
        }
    __syncthreads();   // all GEMM2 reads done; SH reusable as OT

    // epilogue2: OT stage (reuse SH base) + coalesced write to Y (ld 128)
    _Float16* OT = SH;
#pragma unroll
    for (int oi = 0; oi < 4; ++oi) {
        const int ol = oh + oi * 16 + quad * 4;
        const f32x4 bv = *(const f32x4*)(b2v + ol);
#pragma unroll
        for (int mi = 0; mi < 2; ++mi) {
            const int row = mh + mi * 16 + r;
            f32x4 v = acc2[oi][mi] + bv;
            f16x4 ov;
#pragma unroll
            for (int j = 0; j < 4; ++j) { float x = v[j]; ov[j] = (_Float16)((x > 0.f) ? x : 0.f); }
            const int s = ((ol >> 2) ^ (row & 31)) << 2;
            *(f16x4*)(OT + row * 128 + s) = ov;
        }
    }
    __syncthreads();
#pragma unroll
    for (int it2 = 0; it2 < 4; ++it2) {
        const int row = it2 * 16 + (tid >> 4);
        const int c = tid & 15;
        const int s0 = ((c * 2) ^ (row & 31)) << 2;
        const int s1 = ((c * 2 + 1) ^ (row & 31)) << 2;
        f16x4 a  = *(const f16x4*)(OT + row * 128 + s0);
        f16x4 b2 = *(const f16x4*)(OT + row * 128 + s1);
        f16x8 o8;
        o8[0] = a[0]; o8[1] = a[1]; o8[2] = a[2]; o8[3] = a[3];
        o8[4] = b2[0]; o8[5] = b2[1]; o8[6] = b2[2]; o8[7] = b2[3];
        *(f16x8*)(Y + (size_t)(m_blk + row) * 128 + c * 8) = o8;
    }
}

// ---------------- fused pair: Y1 = relu(Wa·X + Res + ba) -> xcat ; Y2 = relu(Wb·Y1 + bb) -> tT ----------------
// 256 threads, 64 m-rows/block, grid 512. K=128 both. LDS 64KB (2 blocks/CU):
// Aa/Ab 32K (Wb overlays Wa after GEMM1) | Bx 16K (X; reused as OT2) | By1 16K (Y1 staged-B).
// Y1 is written to global AND kept in LDS in the staged-B layout (e12-proven), so GEMM2's
// fragment reads are the verified zero-conflict pattern. Math is op-identical to the split
// kernels (same f16 round of Y1, same add order) => bit-identical results.
__global__ __launch_bounds__(256) void pair_kernel(
    const _Float16* __restrict__ Wa, const _Float16* __restrict__ Wb,
    const _Float16* __restrict__ X, const _Float16* __restrict__ Res,
    _Float16* __restrict__ Y1, _Float16* __restrict__ Y2,
    const float* __restrict__ ba, const float* __restrict__ bb,
    int ldR, int roff, int yoff1)
{
    __shared__ _Float16 SH[32768];   // 64 KB
    _Float16* Aa  = SH;              // 16384 f16: Wa 2kt x [128][64]
    _Float16* Bx  = SH + 16384;      // 8192 f16 : X 2kt x [64][64]
    _Float16* By1 = SH + 24576;      // 8192 f16 : Y1 staged-B 2kt x [64][64]
    _Float16* Ab  = SH;              // overlays Aa after GEMM1
    _Float16* OT2 = SH + 16384;      // overlays Bx for epilogue2

    const int tid = threadIdx.x;
    const int lane = tid & 63, wave = tid >> 6;
    const int r = lane & 15, quad = lane >> 4;
    const int m_blk = blockIdx.x * 64;
    const int oh = (wave >> 1) * 64, mh = (wave & 1) * 32;

    const int srow  = wave * 8 + (lane >> 3);
    const int sslot = lane & 7;

    // prologue: stage Aa (8) + Bx (4)
#pragma unroll
    for (int kt = 0; kt < 2; ++kt)
#pragma unroll
        for (int t = 0; t < 4; ++t) {
            const int row = t * 32 + srow;
            const int gk = kt * 64 + ((sslot ^ (row & 7)) << 3);
            __builtin_amdgcn_global_load_lds(
                (const __attribute__((address_space(1))) unsigned int*)(Wa + (size_t)row * 128 + gk),
                (__attribute__((address_space(3))) unsigned int*)(Aa + kt * 8192 + t * 2048 + wave * 512),
                16, 0, 0);
        }
#pragma unroll
    for (int kt = 0; kt < 2; ++kt)
#pragma unroll
        for (int t = 0; t < 2; ++t) {
            const int row = t * 32 + srow;
            const int gk = kt * 64 + ((sslot ^ (row & 7)) << 3);
            __builtin_amdgcn_global_load_lds(
                (const __attribute__((address_space(1))) unsigned int*)(X + (size_t)(m_blk + row) * 128 + gk),
                (__attribute__((address_space(3))) unsigned int*)(Bx + kt * 4096 + t * 2048 + wave * 512),
                16, 0, 0);
        }
    __syncthreads();   // drains vmcnt; Aa/Bx staged

    // GEMM1: acc1 = Wa·X
    f32x4 acc1[4][2];
#pragma unroll
    for (int a = 0; a < 4; ++a)
#pragma unroll
        for (int c = 0; c < 2; ++c) acc1[a][c] = (f32x4){0.f, 0.f, 0.f, 0.f};
#pragma unroll
    for (int kt = 0; kt < 2; ++kt)
#pragma unroll
        for (int ks = 0; ks < 2; ++ks) {
            f16x8 af[4], bf[2];
#pragma unroll
            for (int oi = 0; oi < 4; ++oi) {
                const int row = oh + oi * 16 + r;
                const int slot = (ks * 4 + quad) ^ (row & 7);
                af[oi] = *(const f16x8*)(Aa + kt * 8192 + row * 64 + slot * 8);
            }
#pragma unroll
            for (int mi = 0; mi < 2; ++mi) {
                const int row = mh + mi * 16 + r;
                const int slot = (ks * 4 + quad) ^ (row & 7);
                bf[mi] = *(const f16x8*)(Bx + kt * 4096 + row * 64 + slot * 8);
            }
#pragma unroll
            for (int oi = 0; oi < 4; ++oi)
#pragma unroll
                for (int mi = 0; mi < 2; ++mi)
                    acc1[oi][mi] = __builtin_amdgcn_mfma_f32_16x16x32_f16(af[oi], bf[mi], acc1[oi][mi], 0, 0, 0);
        }
    __syncthreads();   // all waves done reading Aa/Bx; Aa region reusable

    // stage Ab into Aa region (lands under epilogue1's Res loads + compute)
#pragma unroll
    for (int kt = 0; kt < 2; ++kt)
#pragma unroll
        for (int t = 0; t < 4; ++t) {
            const int row = t * 32 + srow;
            const int gk = kt * 64 + ((sslot ^ (row & 7)) << 3);
            __builtin_amdgcn_global_load_lds(
                (const __attribute__((address_space(1))) unsigned int*)(Wb + (size_t)row * 128 + gk),
                (__attribute__((address_space(3))) unsigned int*)(Ab + kt * 8192 + t * 2048 + wave * 512),
                16, 0, 0);
        }

    // epilogue1: Y1 = relu(acc1 + ba + Res) -> By1 (staged-B layout)
#pragma unroll
    for (int oi = 0; oi < 4; ++oi) {
        const int ol = oh + oi * 16 + quad * 4;        // Y1 channel = GEMM2 k, 0..127
        const f32x4 bv = *(const f32x4*)(ba + ol);
        const int kt = ol >> 6, kk = ol & 63;
        const int chunk = kk >> 3, within = kk & 7;    // within in {0,4}
#pragma unroll
        for (int mi = 0; mi < 2; ++mi) {
            const int row = mh + mi * 16 + r;
            f32x4 v = acc1[oi][mi] + bv;
            f16x4 rr = *(const f16x4*)(Res + (size_t)(m_blk + row) * ldR + roff + ol);
#pragma unroll
            for (int j = 0; j < 4; ++j) v[j] += (float)rr[j];
            f16x4 ov;
#pragma unroll
            for (int j = 0; j < 4; ++j) { float x = v[j]; ov[j] = (_Float16)((x > 0.f) ? x : 0.f); }
            *(f16x4*)(By1 + kt * 4096 + row * 64 + ((chunk ^ (row & 7)) << 3) + within) = ov;
        }
    }
    __syncthreads();   // By1 visible; Ab's loads drained (vmcnt 0 in syncthreads)

    // Y1 coalesced global write (read By1 chunks) — fire-and-forget stores
#pragma unroll
    for (int it = 0; it < 4; ++it) {
        const int g = it * 256 + tid;
        const int row = g >> 4, c = g & 15;            // chunk c covers k [8c,8c+8)
        const int kt = c >> 3, cc = c & 7;
        f16x8 o8 = *(const f16x8*)(By1 + kt * 4096 + row * 64 + ((cc ^ (row & 7)) << 3));
        *(f16x8*)(Y1 + (size_t)(m_blk + row) * 384 + yoff1 + c * 8) = o8;
    }

    // GEMM2: acc2 = Wb·Y1
    f32x4 acc2[4][2];
#pragma unroll
    for (int a = 0; a < 4; ++a)
#pragma unroll
        for (int c = 0; c < 2; ++c) acc2[a][c] = (f32x4){0.f, 0.f, 0.f, 0.f};
#pragma unroll
    for (int kt = 0; kt < 2; ++kt)
#pragma unroll
        for (int ks = 0; ks < 2; ++ks) {
            f16x8 af[4], bf[2];
#pragma unroll
            for (int oi = 0; oi < 4; ++oi) {
                const int row = oh + oi * 16 + r;
                const int slot = (ks * 4 + quad) ^ (row & 7);
                af[oi] = *(const f16x8*)(Ab + kt * 8192 + row * 64 + slot * 8);
            }
#pragma unroll
            for (int mi = 0; mi < 2; ++mi) {
                const int row = mh + mi * 16 + r;
                const int slot = (ks * 4 + quad) ^ (row & 7);
                bf[mi] = *(const f16x8*)(By1 + kt * 4096 + row * 64 + slot * 8);
            }
#pragma unroll
            for (int oi = 0; oi < 4; ++oi)
#pragma unroll
                for (int mi = 0; mi < 2; ++mi)
                    acc2[oi][mi] = __builtin_amdgcn_mfma_f32_16x16x32_f16(af[oi], bf[mi], acc2[oi][mi], 0, 0, 0);
        }

    // epilogue2: OT2 (over Bx region — dead since GEMM1) + coalesced Y2 write
#pragma unroll
    for (int oi = 0; oi < 4; ++oi) {
        const int ol = oh + oi * 16 + quad * 4;
        const f32x4 bv = *(const f32x4*)(bb + ol);
#pragma unroll
        for (int mi = 0; mi < 2; ++mi) {
            const int row = mh + mi * 16 + r;
            f32x4 v = acc2[oi][mi] + bv;
            f16x4 ov;
#pragma unroll
            for (int j = 0; j < 4; ++j) { float x = v[j]; ov[j] = (_Float16)((x > 0.f) ? x : 0.f); }
            const int s = ((ol >> 2) ^ (row & 31)) << 2;
            *(f16x4*)(OT2 + row * 128 + s) = ov;
        }
    }
    __syncthreads();
#pragma unroll
    for (int it2 = 0; it2 < 4; ++it2) {
        const int row = it2 * 16 + (tid >> 4);
        const int c = tid & 15;
        const int s0 = ((c * 2) ^ (row & 31)) << 2;
        const int s1 = ((c * 2 + 1) ^ (row & 31)) << 2;
        f16x4 a  = *(const f16x4*)(OT2 + row * 128 + s0);
        f16x4 b2 = *(const f16x4*)(OT2 + row * 128 + s1);
        f16x8 o8;
        o8[0] = a[0]; o8[1] = a[1]; o8[2] = a[2]; o8[3] = a[3];
        o8[4] = b2[0]; o8[5] = b2[1]; o8[6] = b2[2]; o8[7] = b2[3];
        *(f16x8*)(Y2 + (size_t)(m_blk + row) * 128 + c * 8) = o8;
    }
}

// ---------------- GEMM v7 (256x256, 8-wave, dbuf counted-vmcnt): Wf + Wc1 ----------------
__global__ __launch_bounds__(512, 2) void gemm256(
    const _Float16* __restrict__ W, const _Float16* __restrict__ X,
    _Float16* __restrict__ Y, const float* __restrict__ bias,
    int Kp, int ldX, int ldY, int Opad, int act, int biasPerBatch,
    float* __restrict__ pmax, float* __restrict__ psum)
{
    constexpr int ASZ = 256 * 64;               // A-tile f16 elems (= B-tile)
    __shared__ _Float16 SH[65536];              // 2 x (ASZ + ASZ) = 128KB
    const int tid  = threadIdx.x;
    const int lane = tid & 63, wave = tid >> 6;
    const int r = lane & 15, quad = lane >> 4;
    const int wo = wave & 3, wm = wave >> 2;    // wave: o [wo*64,+64), m [wm*128,+128)
    const int m_blk = blockIdx.x * 256, o_blk = blockIdx.y * 256;
    const int nt = Kp >> 6;

    f32x4 acc[4][8];
#pragma unroll
    for (int a = 0; a < 4; ++a)
#pragma unroll
        for (int c = 0; c < 8; ++c) acc[a][c] = (f32x4){0.f, 0.f, 0.f, 0.f};

    const int srow  = wave * 8 + (lane >> 3);   // 0..63
    const int sslot = lane & 7;

    auto STAGE = [&](int bufi, int k0) {
        _Float16* As = SH + bufi * (2 * ASZ);
        _Float16* Bs = As + ASZ;
#pragma unroll
        for (int t = 0; t < 4; ++t) {           // A: 256 rows, 64/instr
            const int rowA = t * 64 + srow;
            const int gk = k0 + ((sslot ^ (rowA & 7)) << 3);
            const _Float16* gA = W + (size_t)(o_blk + rowA) * Kp + gk;
            __builtin_amdgcn_global_load_lds(
                (const __attribute__((address_space(1))) unsigned int*)gA,
                (__attribute__((address_space(3))) unsigned int*)(As + t * 4096 + wave * 512),
                16, 0, 0);
        }
#pragma unroll
        for (int t = 0; t < 4; ++t) {           // B: 256 rows
            const int rowB = t * 64 + srow;
            const int gk = k0 + ((sslot ^ (rowB & 7)) << 3);
            const _Float16* gB = X + (size_t)(m_blk + rowB) * ldX + gk;
            __builtin_amdgcn_global_load_lds(
                (const __attribute__((address_space(1))) unsigned int*)gB,
                (__attribute__((address_space(3))) unsigned int*)(Bs + t * 4096 + wave * 512),
                16, 0, 0);
        }
    };

    STAGE(0, 0);
    int cur = 0;
    for (int t = 0; t < nt; ++t) {
        if (t + 1 < nt) {
            STAGE(cur ^ 1, (t + 1) << 6);       // issue next tile's loads early
            asm volatile("s_waitcnt vmcnt(8)" ::: "memory");   // drain current tile only
        } else {
            asm volatile("s_waitcnt vmcnt(0)" ::: "memory");
        }
        __builtin_amdgcn_sched_barrier(0);
        __builtin_amdgcn_s_barrier();
        asm volatile("" ::: "memory");          // ds_reads stay BELOW the barrier

        const _Float16* As = SH + cur * (2 * ASZ);
        const _Float16* Bs = As + ASZ;
        __builtin_amdgcn_s_setprio(1);
#pragma unroll
        for (int ks = 0; ks < 2; ++ks) {
            f16x8 af[4], bf[8];
#pragma unroll
            for (int oi = 0; oi < 4; ++oi) {
                const int row = (wo << 6) + (oi << 4) + r;
                const int slot = (ks * 4 + quad) ^ (row & 7);
                af[oi] = *(const f16x8*)(As + row * 64 + slot * 8);
            }
#pragma unroll
            for (int mi = 0; mi < 8; ++mi) {
                const int row = (wm << 7) + (mi << 4) + r;
                const int slot = (ks * 4 + quad) ^ (row & 7);
                bf[mi] = *(const f16x8*)(Bs + row * 64 + slot * 8);
            }
#pragma unroll
            for (int oi = 0; oi < 4; ++oi)
#pragma unroll
                for (int mi = 0; mi < 8; ++mi)
                    acc[oi][mi] = __builtin_amdgcn_mfma_f32_16x16x32_f16(af[oi], bf[mi], acc[oi][mi], 0, 0, 0);
        }
        __builtin_amdgcn_s_setprio(0);
        asm volatile("" ::: "memory");          // ds_reads stay ABOVE the barrier
        __builtin_amdgcn_s_barrier();           // all waves done reading buf[cur]
        cur ^= 1;
    }
    __syncthreads();   // SH reusable as output tile

    // epilogue: stage [256m][256o] f16 tile in LDS (XOR-swizzled), coalesced writeback
    const int bb = biasPerBatch ? (m_blk >> 11) * Opad : 0;
    _Float16* OT = SH;
#pragma unroll
    for (int oi = 0; oi < 4; ++oi) {
        const int ol = (wo << 6) + (oi << 4) + (quad << 2);    // local o, 4-aligned
        const f32x4 bv = *(const f32x4*)(bias + bb + o_blk + ol);
#pragma unroll
        for (int mi = 0; mi < 8; ++mi) {
            const int row = (wm << 7) + (mi << 4) + r;         // local m
            f32x4 v = acc[oi][mi] + bv;
            f16x4 ov;
#pragma unroll
            for (int j = 0; j < 4; ++j) {
                float x = v[j];
                if (act == 1)      x = (x > 0.f) ? x : 0.0f;
                else if (act == 2) x = (x > 0.f) ? x : 0.2f * x;
                ov[j] = (_Float16)x;
            }
            const int s = (ol >> 2) ^ (row & 31);              // swizzled 8B slot (0..63)
            *(f16x4*)(OT + row * 256 + s * 4) = ov;
        }
    }
    __syncthreads();
#pragma unroll
    for (int p2 = 0; p2 < 16; ++p2) {
        const int g = (p2 << 9) + tid;
        const int row = g >> 5, c = g & 31;                    // 32 x 16B granules per row
        const int s0 = ((c << 1)) ^ (row & 31);
        const int s1 = ((c << 1) | 1) ^ (row & 31);
        f16x4 a  = *(const f16x4*)(OT + row * 256 + s0 * 4);
        f16x4 b2 = *(const f16x4*)(OT + row * 256 + s1 * 4);
        f16x8 o8;
        o8[0] = a[0]; o8[1] = a[1]; o8[2] = a[2]; o8[3] = a[3];
        o8[4] = b2[0]; o8[5] = b2[1]; o8[6] = b2[2]; o8[7] = b2[3];
        *(f16x8*)(Y + (size_t)(m_blk + row) * ldY + o_blk + (c << 3)) = o8;
    }

    // fused pooling (Wf only): per-block max/sum over 256 rows of this 256-o slice
    if (pmax) {
        const int cg = tid & 63, h8 = tid >> 6;   // 64 o-granules(4) x 8 row-groups(32)
        float mx0 = -3.4e38f, mx1 = -3.4e38f, mx2 = -3.4e38f, mx3 = -3.4e38f;
        float sm0 = 0.f, sm1 = 0.f, sm2 = 0.f, sm3 = 0.f;
#pragma unroll
        for (int rr = 0; rr < 32; ++rr) {
            const int row = (h8 << 5) + rr;
            const f16x4 v = *(const f16x4*)(OT + row * 256 + ((cg ^ (row & 31)) << 2));
            const float x0 = (float)v[0], x1 = (float)v[1], x2 = (float)v[2], x3 = (float)v[3];
            mx0 = fmaxf(mx0, x0); sm0 += x0;
            mx1 = fmaxf(mx1, x1); sm1 += x1;
            mx2 = fmaxf(mx2, x2); sm2 += x2;
            mx3 = fmaxf(mx3, x3); sm3 += x3;
        }
        __syncthreads();                 // done reading OT; reuse SH as partial buffer
        float* PR = (float*)SH;          // [8 h][256 o][2] f32 = 16KB
        float* pw = PR + (size_t)(((h8 << 8) + (cg << 2)) << 1);
        pw[0] = mx0; pw[1] = sm0; pw[2] = mx1; pw[3] = sm1;
        pw[4] = mx2; pw[5] = sm2; pw[6] = mx3; pw[7] = sm3;
        __syncthreads();
        if (tid < 256) {
            float M = -3.4e38f, S = 0.f;
#pragma unroll
            for (int h2 = 0; h2 < 8; ++h2) {
                M = fmaxf(M, PR[(size_t)(((h2 << 8) + tid) << 1)]);
                S += PR[(size_t)(((h2 << 8) + tid) << 1) + 1];
            }
            const int b2 = m_blk >> 11, mt = (m_blk >> 8) & 7;
            pmax[((size_t)((b2 << 3) + mt) << 10) + o_blk + tid] = M;
            psum[((size_t)((b2 << 3) + mt) << 10) + o_blk + tid] = S;
        }
    }
}

// ---------------- GEMM v5b: TM(64|128) x 128o tile, BK=64, dbuf, counted vmcnt ----------------
template<int TM>
__global__ __launch_bounds__(256) void gemm_tile(
    const _Float16* __restrict__ W, const _Float16* __restrict__ X,
    _Float16* __restrict__ Y, float* __restrict__ Y32,
    const float* __restrict__ bias, const _Float16* __restrict__ Res,
    int Kp, int ldX, int xoff, int ldY, int yoff, int Opad,
    int act, int biasPerBatch, int ldR, int roff, int Olimit)
{
    constexpr int MI = TM / 32;                 // m-frags per wave
    constexpr int ASZ = 128 * 64;               // A-tile f16 elems
    constexpr int BSZ = TM * 64;                // B-tile f16 elems
    __shared__ _Float16 SH[2 * (ASZ + BSZ)];    // double-buffered As|Bs ; reused as output tile

    const int tid  = threadIdx.x;
    const int lane = tid & 63, wave = tid >> 6;
    const int r = lane & 15, quad = lane >> 4;
    const int m_blk = blockIdx.x * TM, o_blk = blockIdx.y * 128;
    const int oh = (wave >> 1) * 64, mh = (wave & 1) * (TM / 2);

    f32x4 acc[4][MI];
#pragma unroll
    for (int a = 0; a < 4; ++a)
#pragma unroll
        for (int c = 0; c < MI; ++c) acc[a][c] = (f32x4){0.f, 0.f, 0.f, 0.f};

    const int srow  = wave * 8 + (lane >> 3);
    const int sslot = lane & 7;

    auto STAGE = [&](int bufi, int k0) {
        _Float16* As = SH + bufi * (ASZ + BSZ);
        _Float16* Bs = As + ASZ;
#pragma unroll
        for (int t = 0; t < 4; ++t) {           // A: 128 rows
            const int rowA = t * 32 + srow;
            const int gk = k0 + ((sslot ^ (rowA & 7)) << 3);
            const _Float16* gA = W + (size_t)(o_blk + rowA) * Kp + gk;
            __builtin_amdgcn_global_load_lds(
                (const __attribute__((address_space(1))) unsigned int*)gA,
                (__attribute__((address_space(3))) unsigned int*)(As + t * 2048 + wave * 512),
                16, 0, 0);
        }
#pragma unroll
        for (int t = 0; t < TM / 32; ++t) {     // B: TM rows
            const int rowB = t * 32 + srow;
            const int gk = k0 + ((sslot ^ (rowB & 7)) << 3);
            const _Float16* gB = X + (size_t)(m_blk + rowB) * ldX + xoff + gk;
            __builtin_amdgcn_global_load_lds(
                (const __attribute__((address_space(1))) unsigned int*)gB,
                (__attribute__((address_space(3))) unsigned int*)(Bs + t * 2048 + wave * 512),
                16, 0, 0);
        }
    };

    const int nt = Kp >> 6;
    STAGE(0, 0);
    int cur = 0;
    for (int t = 0; t < nt; ++t) {
        if (t + 1 < nt) {
            STAGE(cur ^ 1, (t + 1) << 6);       // issue next tile's loads early
            if constexpr (TM == 128) asm volatile("s_waitcnt vmcnt(8)" ::: "memory");
            else                     asm volatile("s_waitcnt vmcnt(6)" ::: "memory");
        } else {
            asm volatile("s_waitcnt vmcnt(0)" ::: "memory");
        }
        __builtin_amdgcn_sched_barrier(0);
        __builtin_amdgcn_s_barrier();
        asm volatile("" ::: "memory");

        const _Float16* As = SH + cur * (ASZ + BSZ);
        const _Float16* Bs = As + ASZ;
        __builtin_amdgcn_s_setprio(1);
#pragma unroll
        for (int ks = 0; ks < 2; ++ks) {
            f16x8 af[4], bf[MI];
#pragma unroll
            for (int oi = 0; oi < 4; ++oi) {
                const int row = oh + oi * 16 + r;
                const int slot = (ks * 4 + quad) ^ (row & 7);
                af[oi] = *(const f16x8*)(As + row * 64 + slot * 8);
            }
#pragma unroll
            for (int mi = 0; mi < MI; ++mi) {
                const int row = mh + mi * 16 + r;
                const int slot = (ks * 4 + quad) ^ (row & 7);
                bf[mi] = *(const f16x8*)(Bs + row * 64 + slot * 8);
            }
#pragma unroll
            for (int oi = 0; oi < 4; ++oi)
#pragma unroll
                for (int mi = 0; mi < MI; ++mi)
                    acc[oi][mi] = __builtin_amdgcn_mfma_f32_16x16x32_f16(af[oi], bf[mi], acc[oi][mi], 0, 0, 0);
        }
        __builtin_amdgcn_s_setprio(0);
        asm volatile("" ::: "memory");
        __builtin_amdgcn_s_barrier();
        cur ^= 1;
    }

    const int bb = biasPerBatch ? (m_blk >> 11) * Opad : 0;
    __syncthreads();   // done reading As/Bs; SH is reusable

    if (Y32) {
        // f32 path: store transposed to (B, 50, N): Y32[(b*50+o)*2048 + n], o < Olimit
#pragma unroll
        for (int oi = 0; oi < 4; ++oi) {
            const int og = o_blk + oh + oi * 16 + quad * 4;
            const f32x4 bv = *(const f32x4*)(bias + bb + og);
#pragma unroll
            for (int mi = 0; mi < MI; ++mi) {
                const int m = m_blk + mh + mi * 16 + r;
                const int bidx = m >> 11, n = m & 2047;
                f32x4 v = acc[oi][mi] + bv;
#pragma unroll
                for (int j = 0; j < 4; ++j) {
                    float x = v[j];
                    if (act == 1)      x = (x > 0.f) ? x : 0.0f;
                    else if (act == 2) x = (x > 0.f) ? x : 0.2f * x;
                    const int o = og + j;
                    if (o < Olimit)
                        Y32[((size_t)(bidx * 50 + o) << 11) + n] = x;
                }
            }
        }
        return;
    }

    // f16 path: stage [TM][128] tile in LDS (XOR-swizzled), then coalesced writeback
    _Float16* OT = SH;
#pragma unroll
    for (int oi = 0; oi < 4; ++oi) {
        const int ol = oh + oi * 16 + quad * 4;       // local o (0..127), 4-aligned
        const f32x4 bv = *(const f32x4*)(bias + bb + o_blk + ol);
#pragma unroll
        for (int mi = 0; mi < MI; ++mi) {
            const int row = mh + mi * 16 + r;         // local m
            f32x4 v = acc[oi][mi] + bv;
            if (Res) {
                f16x4 rr = *(const f16x4*)(Res + (size_t)(m_blk + row) * ldR + roff + o_blk + ol);
#pragma unroll
                for (int j = 0; j < 4; ++j) v[j] += (float)rr[j];
            }
            f16x4 ov;
#pragma unroll
            for (int j = 0; j < 4; ++j) {
                float x = v[j];
                if (act == 1)      x = (x > 0.f) ? x : 0.0f;
                else if (act == 2) x = (x > 0.f) ? x : 0.2f * x;
                ov[j] = (_Float16)x;
            }
            const int s = ((ol >> 2) ^ (row & 31)) << 2;   // swizzled 8B slot
            *(f16x4*)(OT + row * 128 + s) = ov;
        }
    }
    __syncthreads();
#pragma unroll
    for (int it2 = 0; it2 < TM / 16; ++it2) {
        const int row = it2 * 16 + (tid >> 4);
        const int c = tid & 15;                        // 8 f16 per lane, contiguous
        const int s0 = ((c * 2) ^ (row & 31)) << 2;
        const int s1 = ((c * 2 + 1) ^ (row & 31)) << 2;
        f16x4 a = *(const f16x4*)(OT + row * 128 + s0);
        f16x4 b2 = *(const f16x4*)(OT + row * 128 + s1);
        f16x8 o8;
        o8[0] = a[0]; o8[1] = a[1]; o8[2] = a[2]; o8[3] = a[3];
        o8[4] = b2[0]; o8[5] = b2[1]; o8[6] = b2[2]; o8[7] = b2[3];
        *(f16x8*)(Y + (size_t)(m_blk + row) * ldY + yoff + o_blk + c * 8) = o8;
    }
}

// ---------------- neighbor gather + channel max (relu outputs => ushort-monotonic f16 bits) ----------------
typedef short s16x8 __attribute__((ext_vector_type(8)));
__global__ __launch_bounds__(256) void gather_max_kernel(
    const short* __restrict__ T, const int* __restrict__ idx, short* __restrict__ Mo)
{
    const int tid = threadIdx.x;
    const int p = blockIdx.x * 16 + (tid >> 4);
    const int l = tid & 15;
    const int b = p >> 11;
    const int* ip = idx + (size_t)p * 16;
    size_t row = (size_t)((b << 11) + ip[0]);
    s16x8 cur = *(const s16x8*)(T + row * 128 + l * 8);
    unsigned short best[8];
#pragma unroll
    for (int e = 0; e < 8; ++e) best[e] = (unsigned short)cur[e];
#pragma unroll
    for (int j = 1; j < 16; ++j) {
        row = (size_t)((b << 11) + ip[j]);
        s16x8 v = *(const s16x8*)(T + row * 128 + l * 8);
#pragma unroll
        for (int e = 0; e < 8; ++e) {
            unsigned short u = (unsigned short)v[e];
            if (u > best[e]) best[e] = u;
        }
    }
    s16x8 ov;
#pragma unroll
    for (int e = 0; e < 8; ++e) ov[e] = (short)best[e];
    *(s16x8*)(Mo + (size_t)p * 128 + l * 8) = ov;
}

// ---------------- per-batch constant vector for Wc1 (absorbs reduce2 + label path) ----------------
__global__ __launch_bounds__(256) void cvec_kernel(
    const float* __restrict__ label, const float* __restrict__ Wl, const float* __restrict__ gl, const float* __restrict__ bl,
    const float* __restrict__ Wc1, const float* __restrict__ bc1, const float* __restrict__ gc1, const float* __restrict__ bb1,
    const float* __restrict__ pmax, const float* __restrict__ psum, float* __restrict__ cvec)
{
    __shared__ float v[2112];
    __shared__ float red[256];
    const int b = blockIdx.x, og = blockIdx.y, tid = threadIdx.x;
    for (int i = tid; i < 1024; i += 256) {
        float mx = -3.4e38f, sm = 0.f;
#pragma unroll
        for (int c = 0; c < 8; ++c) {
            mx = fmaxf(mx, pmax[((size_t)(b * 8 + c) << 10) + i]);
            sm += psum[((size_t)(b * 8 + c) << 10) + i];
        }
        v[i] = mx;
        v[1024 + i] = sm * (1.f / 2048.f);
    }
    if (tid < 64) {
        float s = 0.f;
        for (int i = 0; i < 16; ++i) s += Wl[tid * 16 + i] * label[b * 16 + i];
        s = gl[tid] * s + bl[tid];
        v[2048 + tid] = (s > 0.f) ? s : 0.2f * s;
    }
    __syncthreads();
    const int o = og * 64 + (tid >> 2), part = tid & 3;
    const float* wrow = Wc1 + (size_t)o * 3136 + 1024 + part * 528;
    float s = 0.f;
    for (int j = 0; j < 528; ++j) s += wrow[j] * v[part * 528 + j];
    red[tid] = s;
    __syncthreads();
    if (part == 0) {
        float tot = red[tid] + red[tid + 1] + red[tid + 2] + red[tid + 3];
        cvec[((size_t)b << 9) + o] = gc1[o] * (tot + bc1[o]) + bb1[o];
    }
}

// ---------------- launch ----------------
extern "C" void kernel_launch(void* const* d_in, const int* in_sizes, int n_in,
                              void* d_out, int out_size, void* d_ws, size_t ws_size,
                              hipStream_t stream)
{
    (void)in_sizes; (void)n_in; (void)out_size; (void)ws_size;
    const float* points = (const float*)d_in[0];
    const float* label  = (const float*)d_in[1];
    const float* We1 = (const float*)d_in[2];
    const float* ge1 = (const float*)d_in[3];
    const float* be1 = (const float*)d_in[4];
    const float* We2 = (const float*)d_in[5];
    const float* ge2 = (const float*)d_in[6];
    const float* be2 = (const float*)d_in[7];
    const float* W1  = (const float*)d_in[8];
    const float* g1  = (const float*)d_in[9];
    const float* b1  = (const float*)d_in[10];
    const float* W2  = (const float*)d_in[11];
    const float* g2  = (const float*)d_in[12];
    const float* b2  = (const float*)d_in[13];
    const float* Wf  = (const float*)d_in[14];
    const float* gf  = (const float*)d_in[15];
    const float* bfv = (const float*)d_in[16];
    const float* Wl  = (const float*)d_in[17];
    const float* gl  = (const float*)d_in[18];
    const float* bl  = (const float*)d_in[19];
    const float* Wc1 = (const float*)d_in[20];
    const float* bc1 = (const float*)d_in[21];
    const float* gc1 = (const float*)d_in[22];
    const float* bb1 = (const float*)d_in[23];
    const float* Wc2 = (const float*)d_in[24];
    const float* bc2 = (const float*)d_in[25];
    const float* gc2 = (const float*)d_in[26];
    const float* bb2 = (const float*)d_in[27];
    const float* Wc3 = (const float*)d_in[28];
    const float* bc3 = (const float*)d_in[29];

    char* ws = (char*)d_ws;
    _Float16* hT  = (_Float16*)(ws + OFF_HT);
    _Float16* tT  = (_Float16*)(ws + OFF_TT);
    _Float16* mT  = (_Float16*)(ws + OFF_MT);
    _Float16* xct = (_Float16*)(ws + OFF_XCAT);
    _Float16* xf  = (_Float16*)(ws + OFF_XF);
    _Float16* c1  = (_Float16*)(ws + OFF_C1);
    _Float16* c2  = (_Float16*)(ws + OFF_C2);
    int*      idx = (int*)     (ws + OFF_IDX);
    _Float16* x0  = (_Float16*)(ws + OFF_X0);

    _Float16* wE1 = (_Float16*)(ws + OFF_WE1);
    _Float16* wE2 = (_Float16*)(ws + OFF_WE2);
    _Float16* w1f = (_Float16*)(ws + OFF_W1);
    _Float16* w2f = (_Float16*)(ws + OFF_W2);
    _Float16* wF  = (_Float16*)(ws + OFF_WF);
    _Float16* wC1 = (_Float16*)(ws + OFF_WC1);
    _Float16* wC2 = (_Float16*)(ws + OFF_WC2);
    _Float16* wC3 = (_Float16*)(ws + OFF_WC3);
    float* bC2 = (float*)(ws + OFF_BC2);
    float* bC3 = (float*)(ws + OFF_BC3);
    float* cv  = (float*)(ws + OFF_CVEC);
    float* pmx = (float*)(ws + OFF_PMAX);
    float* psm = (float*)(ws + OFF_PSUM);

    // prep (weights + biases + x0, one launch)
    fold_all_kernel<<<dim3(4834), 256, 0, stream>>>(We1, ge1, We2, ge2, W1, g1, W2, g2,
                                                    Wf, gf, Wc1, gc1, Wc2, gc2, Wc3,
                                                    gc2, bc2, bb2, bc3, points, ws);
    knn_kernel<<<dim3(BB, NN / 32), 256, 0, stream>>>(points, idx);

    // fused e1+e2: x0 -> (t in LDS) -> hT, both relu
    e12_kernel<<<dim3(512), 256, 0, stream>>>(wE1, wE2, x0, hT, be1, be2);

    // W1[0]: t = relu(bn(W1[0] h))
    gemm_tile<64><<<dim3(512, 1), 256, 0, stream>>>(w1f, hT, tT, nullptr, b1, nullptr,
                                                    128, 128, 0, 128, 0, 128, 1, 0, 0, 0, 128);
    gather_max_kernel<<<dim3(MM / 16), 256, 0, stream>>>((const short*)tT, idx, (short*)mT);

    // pair 0: xcat0 = relu(W2[0] m + hT) ; t = relu(W1[1] xcat0)
    pair_kernel<<<dim3(512), 256, 0, stream>>>(w2f, w1f + 16384, mT, hT, xct, tT,
                                               b2, b1 + 128, 128, 0, 0);
    gather_max_kernel<<<dim3(MM / 16), 256, 0, stream>>>((const short*)tT, idx, (short*)mT);

    // pair 1: xcat1 = relu(W2[1] m + xcat0) ; t = relu(W1[2] xcat1)
    pair_kernel<<<dim3(512), 256, 0, stream>>>(w2f + 16384, w1f + 2 * 16384, mT, xct, xct, tT,
                                               b2 + 128, b1 + 256, 384, 0, 128);
    gather_max_kernel<<<dim3(MM / 16), 256, 0, stream>>>((const short*)tT, idx, (short*)mT);

    // W2[2]: xcat2 = relu(W2[2] m + xcat1)
    gemm_tile<64><<<dim3(512, 1), 256, 0, stream>>>(w2f + 2 * 16384, mT, xct, nullptr, b2 + 256, xct,
                                                    128, 128, 0, 384, 256, 128, 1, 0, 384, 128, 128);

    // xf = leaky(bn(Wf xcat)) with fused pooling partials (max/sum per 256-row tile)
    gemm256<<<dim3(128, 4), 512, 0, stream>>>(wF, xct, xf, bfv, 384, 384, 1024, 1024, 2, 0, pmx, psm);

    // per-batch classifier constant (absorbs pooled stats + label path)
    cvec_kernel<<<dim3(BB, 8), 256, 0, stream>>>(label, Wl, gl, bl, Wc1, bc1, gc1, bb1, pmx, psm, cv);

    // c1 = relu(gc1*Wc1[:, :1024] xf + cvec[b])
    gemm256<<<dim3(128, 2), 512, 0, stream>>>(wC1, xf, c1, cv, 1024, 1024, 512, 512, 1, 1, nullptr, nullptr);

    // c2 = relu(bn(Wc2 c1 + bc2))
    gemm_tile<128><<<dim3(256, 2), 256, 0, stream>>>(wC2, c1, c2, nullptr, bC2, nullptr, 512, 512, 0, 256, 0, 256, 1, 0, 0, 0, 256);
    // c3 = Wc3 c2 + bc3 (no act), f32, stored transposed directly to (B,50,N) output
    gemm_tile<128><<<dim3(256, 1), 256, 0, stream>>>(wC3, c2, nullptr, (float*)d_out, bC3, nullptr, 256, 256, 0, 0, 0, 128, 0, 0, 0, 0, 50);
}

// Round 10
// 366.182 us; speedup vs baseline: 1.0957x; 1.0075x over previous
//
#include <hip/hip_runtime.h>
#include <cstdint>
#include <cstddef>

#define DEVINL __device__ __forceinline__

typedef float    f32x4 __attribute__((ext_vector_type(4)));
typedef _Float16 f16x8 __attribute__((ext_vector_type(8)));
typedef _Float16 f16x4 __attribute__((ext_vector_type(4)));
typedef short    s16x8 __attribute__((ext_vector_type(8)));

// ---------------- constants ----------------
constexpr int BB = 16, NN = 2048, MM = 32768;

// ---------------- ws layout (bytes) ----------------
constexpr size_t OFF_WE1 = 0;                           // 128x64 f16 (Kp padded 6->64)
constexpr size_t OFF_WE2 = OFF_WE1 + 128 * 64 * 2;
constexpr size_t OFF_W1  = OFF_WE2 + 128 * 128 * 2;
constexpr size_t OFF_W2  = OFF_W1  + 3 * 128 * 128 * 2;
constexpr size_t OFF_WF  = OFF_W2  + 3 * 128 * 128 * 2;
constexpr size_t OFF_WC1 = OFF_WF  + 1024 * 384 * 2;
constexpr size_t OFF_WC2 = OFF_WC1 + 512 * 1024 * 2;
constexpr size_t OFF_WC3 = OFF_WC2 + 256 * 512 * 2;     // 128x256 (Opad 50->128)
constexpr size_t OFF_BC2 = OFF_WC3 + 128 * 256 * 2;     // 256 f32
constexpr size_t OFF_BC3 = OFF_BC2 + 256 * 4;           // 128 f32
constexpr size_t OFF_CVEC= OFF_BC3 + 128 * 4;           // 16x512 f32
constexpr size_t OFF_PMAX= OFF_CVEC+ 16 * 512 * 4;      // 16 b x 8 mtile x 1024 o f32 (256-row tiles)
constexpr size_t OFF_PSUM= OFF_PMAX+ 16 * 16 * 1024 * 4;
constexpr size_t OFF_IDX = OFF_PSUM+ 16 * 16 * 1024 * 4;
constexpr size_t OFF_R1  = 8ull << 20;                  // > OFF_IDX + 2MB
constexpr size_t OFF_X0  = OFF_R1;                      // 4MB  (M x 64 f16, k-padded)
constexpr size_t OFF_HT  = OFF_R1 + (4ull  << 20);      // 8MB  (M x 128 f16)
constexpr size_t OFF_TT  = OFF_R1 + (12ull << 20);      // 8MB  (t ping)
constexpr size_t OFF_MT  = OFF_R1 + (20ull << 20);      // 8MB  (t pong)
constexpr size_t OFF_C1  = OFF_R1;                      // 32MB (M x 512 f16), aliases x0/h/t/m (dead)
constexpr size_t OFF_XCAT= OFF_R1 + (32ull << 20);      // 24MB (M x 384 f16)
constexpr size_t OFF_C2  = OFF_XCAT;                    // 16MB (M x 256 f16), aliases xcat (dead)
constexpr size_t OFF_XF  = OFF_XCAT + (24ull << 20);    // 64MB (M x 1024 f16)

// ---------------- fold-all: weights (f16, BN-folded), biases, x0 prep ----------------
__global__ __launch_bounds__(256) void fold_all_kernel(
    const float* We1, const float* ge1, const float* We2, const float* ge2,
    const float* W1,  const float* g1,  const float* W2,  const float* g2,
    const float* Wf,  const float* gf,  const float* Wc1, const float* gc1,
    const float* Wc2, const float* gc2, const float* Wc3,
    const float* gc2b, const float* bc2, const float* bb2, const float* bc3,
    const float* pts, char* ws)
{
    const int bid = blockIdx.x;
    const int tid = threadIdx.x;

    if (bid == 4704) {
        ((float*)(ws + OFF_BC2))[tid] = gc2b[tid] * bc2[tid] + bb2[tid];
        return;
    }
    if (bid == 4705) {
        if (tid < 128) ((float*)(ws + OFF_BC3))[tid] = (tid < 50) ? bc3[tid] : 0.f;
        return;
    }
    if (bid >= 4706) {           // x0 prep: (B,6,N) f32 -> (M x 64) f16 K-contig, zero pad
        int m = (bid - 4706) * 256 + tid;
        int b = m >> 11, n = m & 2047;
        const float* ps = pts + (size_t)b * 6 * 2048 + n;
        _Float16 tmp[64];
#pragma unroll
        for (int c = 0; c < 64; ++c) tmp[c] = (_Float16)0.f;
#pragma unroll
        for (int c = 0; c < 6; ++c) tmp[c] = (_Float16)ps[(size_t)c << 11];
        _Float16* dst = (_Float16*)(ws + OFF_X0) + (size_t)m * 64;
#pragma unroll
        for (int v = 0; v < 8; ++v) *(f16x8*)(dst + v * 8) = *(const f16x8*)(tmp + v * 8);
        return;
    }

    int id, base;
    if      (bid < 32)   { id = 0;  base = 0;    }
    else if (bid < 96)   { id = 1;  base = 32;   }
    else if (bid < 160)  { id = 2;  base = 96;   }
    else if (bid < 224)  { id = 3;  base = 160;  }
    else if (bid < 288)  { id = 4;  base = 224;  }
    else if (bid < 352)  { id = 5;  base = 288;  }
    else if (bid < 416)  { id = 6;  base = 352;  }
    else if (bid < 480)  { id = 7;  base = 416;  }
    else if (bid < 2016) { id = 8;  base = 480;  }
    else if (bid < 4064) { id = 9;  base = 2016; }
    else if (bid < 4576) { id = 10; base = 4064; }
    else                 { id = 11; base = 4576; }

    const float* src = nullptr; const float* g = nullptr; _Float16* dst = nullptr;
    int O = 0, K = 0, lds = 0, Kp = 0;
    switch (id) {
        case 0:  src = We1; g = ge1; O = 128; K = 6;    lds = 6;    Kp = 64;   dst = (_Float16*)(ws + OFF_WE1); break;
        case 1:  src = We2; g = ge2; O = 128; K = 128;  lds = 128;  Kp = 128;  dst = (_Float16*)(ws + OFF_WE2); break;
        case 2: case 3: case 4: {
            int i = id - 2;
            src = W1 + (size_t)i * 16384; g = g1 + i * 128; O = 128; K = 128; lds = 128; Kp = 128;
            dst = (_Float16*)(ws + OFF_W1) + (size_t)i * 16384; break; }
        case 5: case 6: case 7: {
            int i = id - 5;
            src = W2 + (size_t)i * 16384; g = g2 + i * 128; O = 128; K = 128; lds = 128; Kp = 128;
            dst = (_Float16*)(ws + OFF_W2) + (size_t)i * 16384; break; }
        case 8:  src = Wf;  g = gf;  O = 1024; K = 384;  lds = 384;  Kp = 384;  dst = (_Float16*)(ws + OFF_WF);  break;
        case 9:  src = Wc1; g = gc1; O = 512;  K = 1024; lds = 3136; Kp = 1024; dst = (_Float16*)(ws + OFF_WC1); break;
        case 10: src = Wc2; g = gc2; O = 256;  K = 512;  lds = 512;  Kp = 512;  dst = (_Float16*)(ws + OFF_WC2); break;
        default: src = Wc3; g = nullptr; O = 50; K = 256; lds = 256; Kp = 256;  dst = (_Float16*)(ws + OFF_WC3); break;
    }
    int e = (bid - base) * 256 + tid;
    int o = e / Kp, k = e - o * Kp;
    float v = 0.f;
    if (o < O && k < K) {
        v = src[(size_t)o * lds + k];
        if (g) v *= g[o];
    }
    dst[e] = (_Float16)v;
}

// ---------------- KNN v8: top-4 bound pass -> survivor buffer -> exact select ----------------
DEVINL float knn_dist(const float4 pq, const float4 pm) {
    float t = pq.x * pm.x;
    t = fmaf(pq.y, pm.y, t);
    t = fmaf(pq.z, pm.z, t);
    return fmaf(-2.f, t, pm.w);
}

#define KNN_DINS(X) do { \
    const float x_ = (X); \
    d15 = __builtin_amdgcn_fmed3f(x_, d14, d15); \
    d14 = __builtin_amdgcn_fmed3f(x_, d13, d14); \
    d13 = __builtin_amdgcn_fmed3f(x_, d12, d13); \
    d12 = __builtin_amdgcn_fmed3f(x_, d11, d12); \
    d11 = __builtin_amdgcn_fmed3f(x_, d10, d11); \
    d10 = __builtin_amdgcn_fmed3f(x_, d9,  d10); \
    d9  = __builtin_amdgcn_fmed3f(x_, d8,  d9);  \
    d8  = __builtin_amdgcn_fmed3f(x_, d7,  d8);  \
    d7  = __builtin_amdgcn_fmed3f(x_, d6,  d7);  \
    d6  = __builtin_amdgcn_fmed3f(x_, d5,  d6);  \
    d5  = __builtin_amdgcn_fmed3f(x_, d4,  d5);  \
    d4  = __builtin_amdgcn_fmed3f(x_, d3,  d4);  \
    d3  = __builtin_amdgcn_fmed3f(x_, d2,  d3);  \
    d2  = __builtin_amdgcn_fmed3f(x_, d1,  d2);  \
    d1  = __builtin_amdgcn_fmed3f(x_, d0,  d1);  \
    d0  = __builtin_amdgcn_fmed3f(x_, -3.4e38f, d0); \
} while (0)

// compare-exchange (ascending)
#define KNN_CE(A, B) { const float lo_ = fminf(A, B), hi_ = fmaxf(A, B); A = lo_; B = hi_; }

// merge own ascending d0..d15 with lane^OFF's ascending list, keep lowest 16 sorted.
#define KNN_MERGE(OFF) do { \
    const float n0  = __shfl_xor(d0,  OFF), n1  = __shfl_xor(d1,  OFF), \
                n2  = __shfl_xor(d2,  OFF), n3  = __shfl_xor(d3,  OFF), \
                n4  = __shfl_xor(d4,  OFF), n5  = __shfl_xor(d5,  OFF), \
                n6  = __shfl_xor(d6,  OFF), n7  = __shfl_xor(d7,  OFF), \
                n8  = __shfl_xor(d8,  OFF), n9  = __shfl_xor(d9,  OFF), \
                n10 = __shfl_xor(d10, OFF), n11 = __shfl_xor(d11, OFF), \
                n12 = __shfl_xor(d12, OFF), n13 = __shfl_xor(d13, OFF), \
                n14 = __shfl_xor(d14, OFF), n15 = __shfl_xor(d15, OFF); \
    d0  = fminf(d0,  n15); d1  = fminf(d1,  n14); d2  = fminf(d2,  n13); d3  = fminf(d3,  n12); \
    d4  = fminf(d4,  n11); d5  = fminf(d5,  n10); d6  = fminf(d6,  n9);  d7  = fminf(d7,  n8);  \
    d8  = fminf(d8,  n7);  d9  = fminf(d9,  n6);  d10 = fminf(d10, n5);  d11 = fminf(d11, n4);  \
    d12 = fminf(d12, n3);  d13 = fminf(d13, n2);  d14 = fminf(d14, n1);  d15 = fminf(d15, n0);  \
    KNN_CE(d0, d8)  KNN_CE(d1, d9)  KNN_CE(d2, d10) KNN_CE(d3, d11) \
    KNN_CE(d4, d12) KNN_CE(d5, d13) KNN_CE(d6, d14) KNN_CE(d7, d15) \
    KNN_CE(d0, d4)  KNN_CE(d1, d5)  KNN_CE(d2, d6)  KNN_CE(d3, d7)  \
    KNN_CE(d8, d12) KNN_CE(d9, d13) KNN_CE(d10,d14) KNN_CE(d11,d15) \
    KNN_CE(d0, d2)  KNN_CE(d1, d3)  KNN_CE(d4, d6)  KNN_CE(d5, d7)  \
    KNN_CE(d8, d10) KNN_CE(d9, d11) KNN_CE(d12,d14) KNN_CE(d13,d15) \
    KNN_CE(d0, d1)  KNN_CE(d2, d3)  KNN_CE(d4, d5)  KNN_CE(d6, d7)  \
    KNN_CE(d8, d9)  KNN_CE(d10,d11) KNN_CE(d12,d13) KNN_CE(d14,d15) \
} while (0)

__global__ __launch_bounds__(256) void knn_kernel(const float* __restrict__ pts, int* __restrict__ idxout)
{
    __shared__ float4 P[2048];              // 32KB, stays intact for all passes
    __shared__ unsigned short buf[32][96];  // 6KB survivor indices per query
    __shared__ int cnt[32];
    __shared__ int wcnt[32];
    const int tid = threadIdx.x;
    const int b = blockIdx.x;
    const float* pb = pts + (size_t)b * 6 * 2048;
    for (int i = tid; i < 2048; i += 256) {
        float x = pb[i];
        float y = pb[2048 + i];
        float z = pb[4096 + i];
        P[i] = make_float4(x, y, z, x * x + y * y + z * z);
    }
    if (tid < 32) { cnt[tid] = 0; wcnt[tid] = 0; }
    __syncthreads();

    const int p = tid & 7;          // candidate partition (m == 8*it + p)
    const int g = tid >> 3;         // query within block (0..31); group = 8 consecutive lanes
    const int q = blockIdx.y * 32 + g;
    const float4 pq = P[q];

    // ---- pass 1: per-lane top-4 over this lane's 256-candidate partition ----
    float d0 = 3.4e38f, d1 = 3.4e38f, d2 = 3.4e38f, d3 = 3.4e38f;
#pragma unroll 4
    for (int it = 0; it < 256; ++it) {
        const float4 pm = P[it * 8 + p];
        const float x = knn_dist(pq, pm);
        d3 = __builtin_amdgcn_fmed3f(x, d2, d3);
        d2 = __builtin_amdgcn_fmed3f(x, d1, d2);
        d1 = __builtin_amdgcn_fmed3f(x, d0, d1);
        d0 = fminf(x, d0);
    }
    float d4 = 3.4e38f, d5 = 3.4e38f, d6 = 3.4e38f, d7 = 3.4e38f,
          d8 = 3.4e38f, d9 = 3.4e38f, d10 = 3.4e38f, d11 = 3.4e38f,
          d12 = 3.4e38f, d13 = 3.4e38f, d14 = 3.4e38f, d15 = 3.4e38f;
    KNN_MERGE(1);
    KNN_MERGE(2);
    KNN_MERGE(4);
    const float tub = d15;          // 16th-smallest of union of top-4s; tub >= d*

    // ---- pass 2: collect survivor indices (d <= tub) ----
#pragma unroll 4
    for (int it = 0; it < 256; ++it) {
        const int m = it * 8 + p;
        const float d = knn_dist(pq, P[m]);
        if (d <= tub) {
            const int pos = atomicAdd(&cnt[g], 1);
            if (pos < 96) buf[g][pos] = (unsigned short)m;
        }
    }
    int C = cnt[g];                 // same-wave LDS ops: no barrier needed
    if (C > 96) C = 96;

    // ---- pass 3: exact top-16 among the C survivors (8 lanes split them) ----
    d0 = 3.4e38f; d1 = 3.4e38f; d2 = 3.4e38f; d3 = 3.4e38f;
    d4 = 3.4e38f; d5 = 3.4e38f; d6 = 3.4e38f; d7 = 3.4e38f;
    d8 = 3.4e38f; d9 = 3.4e38f; d10 = 3.4e38f; d11 = 3.4e38f;
    d12 = 3.4e38f; d13 = 3.4e38f; d14 = 3.4e38f; d15 = 3.4e38f;
    for (int j = p; j < C; j += 8) {
        const int m = buf[g][j];
        const float x = knn_dist(pq, P[m]);
        KNN_DINS(x);
    }
    KNN_MERGE(1);
    KNN_MERGE(2);
    KNN_MERGE(4);
    const float t = d15;            // exact 16th-smallest distance

    // ---- final write: survivors with d <= t, capped at 16 (tie-arbitrary, as before) ----
    int* op = idxout + (((size_t)(b << 11) + q) << 4);
    for (int j = p; j < C; j += 8) {
        const int m = buf[g][j];
        const float d = knn_dist(pq, P[m]);
        if (d <= t) {
            const int pos = atomicAdd(&wcnt[g], 1);
            if (pos < 16) op[pos] = m;   // order-scrambled: consumer is a max over the set
        }
    }
}

// ---------------- fused e1+e2: h = relu(We2 · relu(We1 · x0)) ; t stays in LDS ----------------
__global__ __launch_bounds__(256) void e12_kernel(
    const _Float16* __restrict__ W1e, const _Float16* __restrict__ W2e,
    const _Float16* __restrict__ X, _Float16* __restrict__ Y,
    const float* __restrict__ b1v, const float* __restrict__ b2v)
{
    __shared__ _Float16 SH[36864];
    _Float16* A1s = SH;             // 8192  (We1 128x64)
    _Float16* B1s = SH + 8192;      // 4096  (x0 64x64)
    _Float16* A2s = SH + 12288;     // 16384 (We2 128x128, 2 ktiles)
    _Float16* B2s = SH + 28672;     // 8192  (t 64x128, 2 ktiles)

    const int tid = threadIdx.x;
    const int lane = tid & 63, wave = tid >> 6;
    const int r = lane & 15, quad = lane >> 4;
    const int m_blk = blockIdx.x * 64;
    const int oh = (wave >> 1) * 64, mh = (wave & 1) * 32;

    const int srow  = wave * 8 + (lane >> 3);
    const int sslot = lane & 7;

    // stage A1 (4), B1 (2), A2 (8) — A2 lands under GEMM1
#pragma unroll
    for (int t = 0; t < 4; ++t) {
        const int row = t * 32 + srow;
        const int gk = (sslot ^ (row & 7)) << 3;
        __builtin_amdgcn_global_load_lds(
            (const __attribute__((address_space(1))) unsigned int*)(W1e + (size_t)row * 64 + gk),
            (__attribute__((address_space(3))) unsigned int*)(A1s + t * 2048 + wave * 512),
            16, 0, 0);
    }
#pragma unroll
    for (int t = 0; t < 2; ++t) {
        const int row = t * 32 + srow;
        const int gk = (sslot ^ (row & 7)) << 3;
        __builtin_amdgcn_global_load_lds(
            (const __attribute__((address_space(1))) unsigned int*)(X + (size_t)(m_blk + row) * 64 + gk),
            (__attribute__((address_space(3))) unsigned int*)(B1s + t * 2048 + wave * 512),
            16, 0, 0);
    }
#pragma unroll
    for (int kt = 0; kt < 2; ++kt)
#pragma unroll
        for (int t = 0; t < 4; ++t) {
            const int row = t * 32 + srow;
            const int gk = kt * 64 + ((sslot ^ (row & 7)) << 3);
            __builtin_amdgcn_global_load_lds(
                (const __attribute__((address_space(1))) unsigned int*)(W2e + (size_t)row * 128 + gk),
                (__attribute__((address_space(3))) unsigned int*)(A2s + kt * 8192 + t * 2048 + wave * 512),
                16, 0, 0);
        }

    asm volatile("s_waitcnt vmcnt(8)" ::: "memory");   // A1+B1 landed; A2 still in flight
    __builtin_amdgcn_sched_barrier(0);
    __builtin_amdgcn_s_barrier();
    asm volatile("" ::: "memory");

    // GEMM1: t[m][o] = We1·x0
    f32x4 acc1[4][2];
#pragma unroll
    for (int a = 0; a < 4; ++a)
#pragma unroll
        for (int c = 0; c < 2; ++c) acc1[a][c] = (f32x4){0.f, 0.f, 0.f, 0.f};
#pragma unroll
    for (int ks = 0; ks < 2; ++ks) {
        f16x8 af[4], bf[2];
#pragma unroll
        for (int oi = 0; oi < 4; ++oi) {
            const int row = oh + oi * 16 + r;
            const int slot = (ks * 4 + quad) ^ (row & 7);
            af[oi] = *(const f16x8*)(A1s + row * 64 + slot * 8);
        }
#pragma unroll
        for (int mi = 0; mi < 2; ++mi) {
            const int row = mh + mi * 16 + r;
            const int slot = (ks * 4 + quad) ^ (row & 7);
            bf[mi] = *(const f16x8*)(B1s + row * 64 + slot * 8);
        }
#pragma unroll
        for (int oi = 0; oi < 4; ++oi)
#pragma unroll
            for (int mi = 0; mi < 2; ++mi)
                acc1[oi][mi] = __builtin_amdgcn_mfma_f32_16x16x32_f16(af[oi], bf[mi], acc1[oi][mi], 0, 0, 0);
    }

    // epilogue1: relu(acc1+b1) -> B2s in staged-B layout (chunk c stored at slot c^(row&7))
#pragma unroll
    for (int oi = 0; oi < 4; ++oi) {
        const int ob = oh + oi * 16 + quad * 4;        // t-channel = GEMM2 k, 0..127
        const f32x4 bv = *(const f32x4*)(b1v + ob);
        const int kt = ob >> 6, kk = ob & 63;
        const int chunk = kk >> 3, within = kk & 7;    // within in {0,4}
#pragma unroll
        for (int mi = 0; mi < 2; ++mi) {
            const int row = mh + mi * 16 + r;
            f32x4 v = acc1[oi][mi] + bv;
            f16x4 ov;
#pragma unroll
            for (int j = 0; j < 4; ++j) { float x = v[j]; ov[j] = (_Float16)((x > 0.f) ? x : 0.f); }
            *(f16x4*)(B2s + kt * 4096 + row * 64 + ((chunk ^ (row & 7)) << 3) + within) = ov;
        }
    }
    __syncthreads();   // B2s visible to all; full waitcnt also drains A2's loads

    // GEMM2: h[m][o2] = We2·t
    f32x4 acc2[4][2];
#pragma unroll
    for (int a = 0; a < 4; ++a)
#pragma unroll
        for (int c = 0; c < 2; ++c) acc2[a][c] = (f32x4){0.f, 0.f, 0.f, 0.f};
#pragma unroll
    for (int kt = 0; kt < 2; ++kt)
#pragma unroll
        for (int ks = 0; ks < 2; ++ks) {
            f16x8 af[4], bf[2];
#pragma unroll
            for (int oi = 0; oi < 4; ++oi) {
                const int row = oh + oi * 16 + r;
                const int slot = (ks * 4 + quad) ^ (row & 7);
                af[oi] = *(const f16x8*)(A2s + kt * 8192 + row * 64 + slot * 8);
            }
#pragma unroll
            for (int mi = 0; mi < 2; ++mi) {
                const int row = mh + mi * 16 + r;
                const int slot = (ks * 4 + quad) ^ (row & 7);
                bf[mi] = *(const f16x8*)(B2s + kt * 4096 + row * 64 + slot * 8);
            }
#pragma unroll
            for (int oi = 0; oi < 4; ++oi)
#pragma unroll
                for (int mi = 0; mi < 2; ++mi)
                    acc2[oi][mi] = __builtin_amdgcn_mfma_f32_16x16x32_f16(af[oi], bf[mi], acc2[oi][mi], 0, 0, 0);
        }
    __syncthreads();   // all GEMM2 reads done; SH reusable as OT

    // epilogue2: OT stage (reuse SH base) + coalesced write to Y (ld 128)
    _Float16* OT = SH;
#pragma unroll
    for (int oi = 0; oi < 4; ++oi) {
        const int ol = oh + oi * 16 + quad * 4;
        const f32x4 bv = *(const f32x4*)(b2v + ol);
#pragma unroll
        for (int mi = 0; mi < 2; ++mi) {
            const int row = mh + mi * 16 + r;
            f32x4 v = acc2[oi][mi] + bv;
            f16x4 ov;
#pragma unroll
            for (int j = 0; j < 4; ++j) { float x = v[j]; ov[j] = (_Float16)((x > 0.f) ? x : 0.f); }
            const int s = ((ol >> 2) ^ (row & 31)) << 2;
            *(f16x4*)(OT + row * 128 + s) = ov;
        }
    }
    __syncthreads();
#pragma unroll
    for (int it2 = 0; it2 < 4; ++it2) {
        const int row = it2 * 16 + (tid >> 4);
        const int c = tid & 15;
        const int s0 = ((c * 2) ^ (row & 31)) << 2;
        const int s1 = ((c * 2 + 1) ^ (row & 31)) << 2;
        f16x4 a  = *(const f16x4*)(OT + row * 128 + s0);
        f16x4 b2 = *(const f16x4*)(OT + row * 128 + s1);
        f16x8 o8;
        o8[0] = a[0]; o8[1] = a[1]; o8[2] = a[2]; o8[3] = a[3];
        o8[4] = b2[0]; o8[5] = b2[1]; o8[6] = b2[2]; o8[7] = b2[3];
        *(f16x8*)(Y + (size_t)(m_blk + row) * 128 + c * 8) = o8;
    }
}

// ---------------- fused gather+pair: m = nbr-max(T, idx) in LDS ; Y1 = relu(Wa·m + Res + ba) ;
// [HAS_G2] Y2 = relu(Wb·Y1 + bb). 256 threads, 64 m-rows/block, grid 512. LDS 64KB (2/CU):
// Aa/Ab 32K | Bm 16K (gathered m, staged-B; reused as OT2) | By1 16K (Y1 staged-B).
// Gather uses gather_max's exact ushort-monotonic compare (relu outputs) => bit-identical m.
// ds_writes use the same chunk^(row&7) involution the GEMM reads are verified conflict-free on.
template<bool HAS_G2>
__global__ __launch_bounds__(256) void pairg_kernel(
    const _Float16* __restrict__ Wa, const _Float16* __restrict__ Wb,
    const short* __restrict__ T, const int* __restrict__ idxp,
    const _Float16* __restrict__ Res,
    _Float16* __restrict__ Y1, _Float16* __restrict__ Y2,
    const float* __restrict__ ba, const float* __restrict__ bb,
    int ldR, int roff, int yoff1)
{
    __shared__ _Float16 SH[32768];   // 64 KB
    _Float16* Aa  = SH;              // 16384 f16: Wa 2kt x [128][64]
    _Float16* Bm  = SH + 16384;      // 8192 f16 : gathered m, staged-B 2kt x [64][64]
    _Float16* By1 = SH + 24576;      // 8192 f16 : Y1 staged-B 2kt x [64][64]
    _Float16* Ab  = SH;              // overlays Aa after GEMM1
    _Float16* OT2 = SH + 16384;      // overlays Bm for epilogue2

    const int tid = threadIdx.x;
    const int lane = tid & 63, wave = tid >> 6;
    const int r = lane & 15, quad = lane >> 4;
    const int m_blk = blockIdx.x * 64;
    const int oh = (wave >> 1) * 64, mh = (wave & 1) * 32;

    const int srow  = wave * 8 + (lane >> 3);
    const int sslot = lane & 7;

    // prologue: issue Aa staging (8 gld_lds) — lands under the gather
#pragma unroll
    for (int kt = 0; kt < 2; ++kt)
#pragma unroll
        for (int t = 0; t < 4; ++t) {
            const int row = t * 32 + srow;
            const int gk = kt * 64 + ((sslot ^ (row & 7)) << 3);
            __builtin_amdgcn_global_load_lds(
                (const __attribute__((address_space(1))) unsigned int*)(Wa + (size_t)row * 128 + gk),
                (__attribute__((address_space(3))) unsigned int*)(Aa + kt * 8192 + t * 2048 + wave * 512),
                16, 0, 0);
        }

    // gather: m[row][l*8..l*8+8] = nbr-max over 16 idx rows of T (ushort-monotonic)
    {
        const int l = tid & 15;
        const int kt = l >> 3, cc = l & 7;
#pragma unroll
        for (int it = 0; it < 4; ++it) {
            const int row = it * 16 + (tid >> 4);      // local m row 0..63
            const int gm = m_blk + row;
            const int b = gm >> 11;
            const int* ip = idxp + (size_t)gm * 16;
            size_t rr = (size_t)((b << 11) + ip[0]);
            s16x8 cur = *(const s16x8*)(T + rr * 128 + l * 8);
            unsigned short best[8];
#pragma unroll
            for (int e = 0; e < 8; ++e) best[e] = (unsigned short)cur[e];
#pragma unroll
            for (int j = 1; j < 16; ++j) {
                rr = (size_t)((b << 11) + ip[j]);
                s16x8 v = *(const s16x8*)(T + rr * 128 + l * 8);
#pragma unroll
                for (int e = 0; e < 8; ++e) {
                    unsigned short u = (unsigned short)v[e];
                    if (u > best[e]) best[e] = u;
                }
            }
            s16x8 ov;
#pragma unroll
            for (int e = 0; e < 8; ++e) ov[e] = (short)best[e];
            *(s16x8*)((short*)Bm + kt * 4096 + row * 64 + ((cc ^ (row & 7)) << 3)) = ov;
        }
    }
    __syncthreads();   // drains Aa's gld_lds + gather ds_writes

    // GEMM1: acc1 = Wa·m
    f32x4 acc1[4][2];
#pragma unroll
    for (int a = 0; a < 4; ++a)
#pragma unroll
        for (int c = 0; c < 2; ++c) acc1[a][c] = (f32x4){0.f, 0.f, 0.f, 0.f};
#pragma unroll
    for (int kt = 0; kt < 2; ++kt)
#pragma unroll
        for (int ks = 0; ks < 2; ++ks) {
            f16x8 af[4], bf[2];
#pragma unroll
            for (int oi = 0; oi < 4; ++oi) {
                const int row = oh + oi * 16 + r;
                const int slot = (ks * 4 + quad) ^ (row & 7);
                af[oi] = *(const f16x8*)(Aa + kt * 8192 + row * 64 + slot * 8);
            }
#pragma unroll
            for (int mi = 0; mi < 2; ++mi) {
                const int row = mh + mi * 16 + r;
                const int slot = (ks * 4 + quad) ^ (row & 7);
                bf[mi] = *(const f16x8*)(Bm + kt * 4096 + row * 64 + slot * 8);
            }
#pragma unroll
            for (int oi = 0; oi < 4; ++oi)
#pragma unroll
                for (int mi = 0; mi < 2; ++mi)
                    acc1[oi][mi] = __builtin_amdgcn_mfma_f32_16x16x32_f16(af[oi], bf[mi], acc1[oi][mi], 0, 0, 0);
        }
    __syncthreads();   // all waves done reading Aa/Bm

    if constexpr (HAS_G2) {
        // stage Ab into Aa region (lands under epilogue1's Res loads + compute)
#pragma unroll
        for (int kt = 0; kt < 2; ++kt)
#pragma unroll
            for (int t = 0; t < 4; ++t) {
                const int row = t * 32 + srow;
                const int gk = kt * 64 + ((sslot ^ (row & 7)) << 3);
                __builtin_amdgcn_global_load_lds(
                    (const __attribute__((address_space(1))) unsigned int*)(Wb + (size_t)row * 128 + gk),
                    (__attribute__((address_space(3))) unsigned int*)(Ab + kt * 8192 + t * 2048 + wave * 512),
                    16, 0, 0);
            }
    }

    // epilogue1: Y1 = relu(acc1 + ba + Res) -> By1 (staged-B layout)
#pragma unroll
    for (int oi = 0; oi < 4; ++oi) {
        const int ol = oh + oi * 16 + quad * 4;        // Y1 channel = GEMM2 k, 0..127
        const f32x4 bv = *(const f32x4*)(ba + ol);
        const int kt = ol >> 6, kk = ol & 63;
        const int chunk = kk >> 3, within = kk & 7;    // within in {0,4}
#pragma unroll
        for (int mi = 0; mi < 2; ++mi) {
            const int row = mh + mi * 16 + r;
            f32x4 v = acc1[oi][mi] + bv;
            f16x4 rr = *(const f16x4*)(Res + (size_t)(m_blk + row) * ldR + roff + ol);
#pragma unroll
            for (int j = 0; j < 4; ++j) v[j] += (float)rr[j];
            f16x4 ov;
#pragma unroll
            for (int j = 0; j < 4; ++j) { float x = v[j]; ov[j] = (_Float16)((x > 0.f) ? x : 0.f); }
            *(f16x4*)(By1 + kt * 4096 + row * 64 + ((chunk ^ (row & 7)) << 3) + within) = ov;
        }
    }
    __syncthreads();   // By1 visible; Ab's loads drained

    // Y1 coalesced global write (read By1 chunks)
#pragma unroll
    for (int it = 0; it < 4; ++it) {
        const int g = it * 256 + tid;
        const int row = g >> 4, c = g & 15;            // chunk c covers k [8c,8c+8)
        const int kt = c >> 3, cc = c & 7;
        f16x8 o8 = *(const f16x8*)(By1 + kt * 4096 + row * 64 + ((cc ^ (row & 7)) << 3));
        *(f16x8*)(Y1 + (size_t)(m_blk + row) * 384 + yoff1 + c * 8) = o8;
    }

    if constexpr (HAS_G2) {
        // GEMM2: acc2 = Wb·Y1
        f32x4 acc2[4][2];
#pragma unroll
        for (int a = 0; a < 4; ++a)
#pragma unroll
            for (int c = 0; c < 2; ++c) acc2[a][c] = (f32x4){0.f, 0.f, 0.f, 0.f};
#pragma unroll
        for (int kt = 0; kt < 2; ++kt)
#pragma unroll
            for (int ks = 0; ks < 2; ++ks) {
                f16x8 af[4], bf[2];
#pragma unroll
                for (int oi = 0; oi < 4; ++oi) {
                    const int row = oh + oi * 16 + r;
                    const int slot = (ks * 4 + quad) ^ (row & 7);
                    af[oi] = *(const f16x8*)(Ab + kt * 8192 + row * 64 + slot * 8);
                }
#pragma unroll
                for (int mi = 0; mi < 2; ++mi) {
                    const int row = mh + mi * 16 + r;
                    const int slot = (ks * 4 + quad) ^ (row & 7);
                    bf[mi] = *(const f16x8*)(By1 + kt * 4096 + row * 64 + slot * 8);
                }
#pragma unroll
                for (int oi = 0; oi < 4; ++oi)
#pragma unroll
                    for (int mi = 0; mi < 2; ++mi)
                        acc2[oi][mi] = __builtin_amdgcn_mfma_f32_16x16x32_f16(af[oi], bf[mi], acc2[oi][mi], 0, 0, 0);
            }

        // epilogue2: OT2 (over Bm region — dead since GEMM1) + coalesced Y2 write
#pragma unroll
        for (int oi = 0; oi < 4; ++oi) {
            const int ol = oh + oi * 16 + quad * 4;
            const f32x4 bv = *(const f32x4*)(bb + ol);
#pragma unroll
            for (int mi = 0; mi < 2; ++mi) {
                const int row = mh + mi * 16 + r;
                f32x4 v = acc2[oi][mi] + bv;
                f16x4 ov;
#pragma unroll
                for (int j = 0; j < 4; ++j) { float x = v[j]; ov[j] = (_Float16)((x > 0.f) ? x : 0.f); }
                const int s = ((ol >> 2) ^ (row & 31)) << 2;
                *(f16x4*)(OT2 + row * 128 + s) = ov;
            }
        }
        __syncthreads();
#pragma unroll
        for (int it2 = 0; it2 < 4; ++it2) {
            const int row = it2 * 16 + (tid >> 4);
            const int c = tid & 15;
            const int s0 = ((c * 2) ^ (row & 31)) << 2;
            const int s1 = ((c * 2 + 1) ^ (row & 31)) << 2;
            f16x4 a  = *(const f16x4*)(OT2 + row * 128 + s0);
            f16x4 b2 = *(const f16x4*)(OT2 + row * 128 + s1);
            f16x8 o8;
            o8[0] = a[0]; o8[1] = a[1]; o8[2] = a[2]; o8[3] = a[3];
            o8[4] = b2[0]; o8[5] = b2[1]; o8[6] = b2[2]; o8[7] = b2[3];
            *(f16x8*)(Y2 + (size_t)(m_blk + row) * 128 + c * 8) = o8;
        }
    }
}

// ---------------- GEMM v7 (256x256, 8-wave, dbuf counted-vmcnt): Wf + Wc1 ----------------
__global__ __launch_bounds__(512, 2) void gemm256(
    const _Float16* __restrict__ W, const _Float16* __restrict__ X,
    _Float16* __restrict__ Y, const float* __restrict__ bias,
    int Kp, int ldX, int ldY, int Opad, int act, int biasPerBatch,
    float* __restrict__ pmax, float* __restrict__ psum)
{
    constexpr int ASZ = 256 * 64;               // A-tile f16 elems (= B-tile)
    __shared__ _Float16 SH[65536];              // 2 x (ASZ + ASZ) = 128KB
    const int tid  = threadIdx.x;
    const int lane = tid & 63, wave = tid >> 6;
    const int r = lane & 15, quad = lane >> 4;
    const int wo = wave & 3, wm = wave >> 2;    // wave: o [wo*64,+64), m [wm*128,+128)
    const int m_blk = blockIdx.x * 256, o_blk = blockIdx.y * 256;
    const int nt = Kp >> 6;

    f32x4 acc[4][8];
#pragma unroll
    for (int a = 0; a < 4; ++a)
#pragma unroll
        for (int c = 0; c < 8; ++c) acc[a][c] = (f32x4){0.f, 0.f, 0.f, 0.f};

    const int srow  = wave * 8 + (lane >> 3);   // 0..63
    const int sslot = lane & 7;

    auto STAGE = [&](int bufi, int k0) {
        _Float16* As = SH + bufi * (2 * ASZ);
        _Float16* Bs = As + ASZ;
#pragma unroll
        for (int t = 0; t < 4; ++t) {           // A: 256 rows, 64/instr
            const int rowA = t * 64 + srow;
            const int gk = k0 + ((sslot ^ (rowA & 7)) << 3);
            const _Float16* gA = W + (size_t)(o_blk + rowA) * Kp + gk;
            __builtin_amdgcn_global_load_lds(
                (const __attribute__((address_space(1))) unsigned int*)gA,
                (__attribute__((address_space(3))) unsigned int*)(As + t * 4096 + wave * 512),
                16, 0, 0);
        }
#pragma unroll
        for (int t = 0; t < 4; ++t) {           // B: 256 rows
            const int rowB = t * 64 + srow;
            const int gk = k0 + ((sslot ^ (rowB & 7)) << 3);
            const _Float16* gB = X + (size_t)(m_blk + rowB) * ldX + gk;
            __builtin_amdgcn_global_load_lds(
                (const __attribute__((address_space(1))) unsigned int*)gB,
                (__attribute__((address_space(3))) unsigned int*)(Bs + t * 4096 + wave * 512),
                16, 0, 0);
        }
    };

    STAGE(0, 0);
    int cur = 0;
    for (int t = 0; t < nt; ++t) {
        if (t + 1 < nt) {
            STAGE(cur ^ 1, (t + 1) << 6);       // issue next tile's loads early
            asm volatile("s_waitcnt vmcnt(8)" ::: "memory");   // drain current tile only
        } else {
            asm volatile("s_waitcnt vmcnt(0)" ::: "memory");
        }
        __builtin_amdgcn_sched_barrier(0);
        __builtin_amdgcn_s_barrier();
        asm volatile("" ::: "memory");          // ds_reads stay BELOW the barrier

        const _Float16* As = SH + cur * (2 * ASZ);
        const _Float16* Bs = As + ASZ;
        __builtin_amdgcn_s_setprio(1);
#pragma unroll
        for (int ks = 0; ks < 2; ++ks) {
            f16x8 af[4], bf[8];
#pragma unroll
            for (int oi = 0; oi < 4; ++oi) {
                const int row = (wo << 6) + (oi << 4) + r;
                const int slot = (ks * 4 + quad) ^ (row & 7);
                af[oi] = *(const f16x8*)(As + row * 64 + slot * 8);
            }
#pragma unroll
            for (int mi = 0; mi < 8; ++mi) {
                const int row = (wm << 7) + (mi << 4) + r;
                const int slot = (ks * 4 + quad) ^ (row & 7);
                bf[mi] = *(const f16x8*)(Bs + row * 64 + slot * 8);
            }
#pragma unroll
            for (int oi = 0; oi < 4; ++oi)
#pragma unroll
                for (int mi = 0; mi < 8; ++mi)
                    acc[oi][mi] = __builtin_amdgcn_mfma_f32_16x16x32_f16(af[oi], bf[mi], acc[oi][mi], 0, 0, 0);
        }
        __builtin_amdgcn_s_setprio(0);
        asm volatile("" ::: "memory");          // ds_reads stay ABOVE the barrier
        __builtin_amdgcn_s_barrier();           // all waves done reading buf[cur]
        cur ^= 1;
    }
    __syncthreads();   // SH reusable as output tile

    // epilogue: stage [256m][256o] f16 tile in LDS (XOR-swizzled), coalesced writeback
    const int bb = biasPerBatch ? (m_blk >> 11) * Opad : 0;
    _Float16* OT = SH;
#pragma unroll
    for (int oi = 0; oi < 4; ++oi) {
        const int ol = (wo << 6) + (oi << 4) + (quad << 2);    // local o, 4-aligned
        const f32x4 bv = *(const f32x4*)(bias + bb + o_blk + ol);
#pragma unroll
        for (int mi = 0; mi < 8; ++mi) {
            const int row = (wm << 7) + (mi << 4) + r;         // local m
            f32x4 v = acc[oi][mi] + bv;
            f16x4 ov;
#pragma unroll
            for (int j = 0; j < 4; ++j) {
                float x = v[j];
                if (act == 1)      x = (x > 0.f) ? x : 0.0f;
                else if (act == 2) x = (x > 0.f) ? x : 0.2f * x;
                ov[j] = (_Float16)x;
            }
            const int s = (ol >> 2) ^ (row & 31);              // swizzled 8B slot (0..63)
            *(f16x4*)(OT + row * 256 + s * 4) = ov;
        }
    }
    __syncthreads();
#pragma unroll
    for (int p2 = 0; p2 < 16; ++p2) {
        const int g = (p2 << 9) + tid;
        const int row = g >> 5, c = g & 31;                    // 32 x 16B granules per row
        const int s0 = ((c << 1)) ^ (row & 31);
        const int s1 = ((c << 1) | 1) ^ (row & 31);
        f16x4 a  = *(const f16x4*)(OT + row * 256 + s0 * 4);
        f16x4 b2 = *(const f16x4*)(OT + row * 256 + s1 * 4);
        f16x8 o8;
        o8[0] = a[0]; o8[1] = a[1]; o8[2] = a[2]; o8[3] = a[3];
        o8[4] = b2[0]; o8[5] = b2[1]; o8[6] = b2[2]; o8[7] = b2[3];
        *(f16x8*)(Y + (size_t)(m_blk + row) * ldY + o_blk + (c << 3)) = o8;
    }

    // fused pooling (Wf only): per-block max/sum over 256 rows of this 256-o slice
    if (pmax) {
        const int cg = tid & 63, h8 = tid >> 6;   // 64 o-granules(4) x 8 row-groups(32)
        float mx0 = -3.4e38f, mx1 = -3.4e38f, mx2 = -3.4e38f, mx3 = -3.4e38f;
        float sm0 = 0.f, sm1 = 0.f, sm2 = 0.f, sm3 = 0.f;
#pragma unroll
        for (int rr = 0; rr < 32; ++rr) {
            const int row = (h8 << 5) + rr;
            const f16x4 v = *(const f16x4*)(OT + row * 256 + ((cg ^ (row & 31)) << 2));
            const float x0 = (float)v[0], x1 = (float)v[1], x2 = (float)v[2], x3 = (float)v[3];
            mx0 = fmaxf(mx0, x0); sm0 += x0;
            mx1 = fmaxf(mx1, x1); sm1 += x1;
            mx2 = fmaxf(mx2, x2); sm2 += x2;
            mx3 = fmaxf(mx3, x3); sm3 += x3;
        }
        __syncthreads();                 // done reading OT; reuse SH as partial buffer
        float* PR = (float*)SH;          // [8 h][256 o][2] f32 = 16KB
        float* pw = PR + (size_t)(((h8 << 8) + (cg << 2)) << 1);
        pw[0] = mx0; pw[1] = sm0; pw[2] = mx1; pw[3] = sm1;
        pw[4] = mx2; pw[5] = sm2; pw[6] = mx3; pw[7] = sm3;
        __syncthreads();
        if (tid < 256) {
            float M = -3.4e38f, S = 0.f;
#pragma unroll
            for (int h2 = 0; h2 < 8; ++h2) {
                M = fmaxf(M, PR[(size_t)(((h2 << 8) + tid) << 1)]);
                S += PR[(size_t)(((h2 << 8) + tid) << 1) + 1];
            }
            const int b2 = m_blk >> 11, mt = (m_blk >> 8) & 7;
            pmax[((size_t)((b2 << 3) + mt) << 10) + o_blk + tid] = M;
            psum[((size_t)((b2 << 3) + mt) << 10) + o_blk + tid] = S;
        }
    }
}

// ---------------- GEMM v5b: TM(64|128) x 128o tile, BK=64, dbuf, counted vmcnt ----------------
template<int TM>
__global__ __launch_bounds__(256) void gemm_tile(
    const _Float16* __restrict__ W, const _Float16* __restrict__ X,
    _Float16* __restrict__ Y, float* __restrict__ Y32,
    const float* __restrict__ bias, const _Float16* __restrict__ Res,
    int Kp, int ldX, int xoff, int ldY, int yoff, int Opad,
    int act, int biasPerBatch, int ldR, int roff, int Olimit)
{
    constexpr int MI = TM / 32;                 // m-frags per wave
    constexpr int ASZ = 128 * 64;               // A-tile f16 elems
    constexpr int BSZ = TM * 64;                // B-tile f16 elems
    __shared__ _Float16 SH[2 * (ASZ + BSZ)];    // double-buffered As|Bs ; reused as output tile

    const int tid  = threadIdx.x;
    const int lane = tid & 63, wave = tid >> 6;
    const int r = lane & 15, quad = lane >> 4;
    const int m_blk = blockIdx.x * TM, o_blk = blockIdx.y * 128;
    const int oh = (wave >> 1) * 64, mh = (wave & 1) * (TM / 2);

    f32x4 acc[4][MI];
#pragma unroll
    for (int a = 0; a < 4; ++a)
#pragma unroll
        for (int c = 0; c < MI; ++c) acc[a][c] = (f32x4){0.f, 0.f, 0.f, 0.f};

    const int srow  = wave * 8 + (lane >> 3);
    const int sslot = lane & 7;

    auto STAGE = [&](int bufi, int k0) {
        _Float16* As = SH + bufi * (ASZ + BSZ);
        _Float16* Bs = As + ASZ;
#pragma unroll
        for (int t = 0; t < 4; ++t) {           // A: 128 rows
            const int rowA = t * 32 + srow;
            const int gk = k0 + ((sslot ^ (rowA & 7)) << 3);
            const _Float16* gA = W + (size_t)(o_blk + rowA) * Kp + gk;
            __builtin_amdgcn_global_load_lds(
                (const __attribute__((address_space(1))) unsigned int*)gA,
                (__attribute__((address_space(3))) unsigned int*)(As + t * 2048 + wave * 512),
                16, 0, 0);
        }
#pragma unroll
        for (int t = 0; t < TM / 32; ++t) {     // B: TM rows
            const int rowB = t * 32 + srow;
            const int gk = k0 + ((sslot ^ (rowB & 7)) << 3);
            const _Float16* gB = X + (size_t)(m_blk + rowB) * ldX + xoff + gk;
            __builtin_amdgcn_global_load_lds(
                (const __attribute__((address_space(1))) unsigned int*)gB,
                (__attribute__((address_space(3))) unsigned int*)(Bs + t * 2048 + wave * 512),
                16, 0, 0);
        }
    };

    const int nt = Kp >> 6;
    STAGE(0, 0);
    int cur = 0;
    for (int t = 0; t < nt; ++t) {
        if (t + 1 < nt) {
            STAGE(cur ^ 1, (t + 1) << 6);       // issue next tile's loads early
            if constexpr (TM == 128) asm volatile("s_waitcnt vmcnt(8)" ::: "memory");
            else                     asm volatile("s_waitcnt vmcnt(6)" ::: "memory");
        } else {
            asm volatile("s_waitcnt vmcnt(0)" ::: "memory");
        }
        __builtin_amdgcn_sched_barrier(0);
        __builtin_amdgcn_s_barrier();
        asm volatile("" ::: "memory");

        const _Float16* As = SH + cur * (ASZ + BSZ);
        const _Float16* Bs = As + ASZ;
        __builtin_amdgcn_s_setprio(1);
#pragma unroll
        for (int ks = 0; ks < 2; ++ks) {
            f16x8 af[4], bf[MI];
#pragma unroll
            for (int oi = 0; oi < 4; ++oi) {
                const int row = oh + oi * 16 + r;
                const int slot = (ks * 4 + quad) ^ (row & 7);
                af[oi] = *(const f16x8*)(As + row * 64 + slot * 8);
            }
#pragma unroll
            for (int mi = 0; mi < MI; ++mi) {
                const int row = mh + mi * 16 + r;
                const int slot = (ks * 4 + quad) ^ (row & 7);
                bf[mi] = *(const f16x8*)(Bs + row * 64 + slot * 8);
            }
#pragma unroll
            for (int oi = 0; oi < 4; ++oi)
#pragma unroll
                for (int mi = 0; mi < MI; ++mi)
                    acc[oi][mi] = __builtin_amdgcn_mfma_f32_16x16x32_f16(af[oi], bf[mi], acc[oi][mi], 0, 0, 0);
        }
        __builtin_amdgcn_s_setprio(0);
        asm volatile("" ::: "memory");
        __builtin_amdgcn_s_barrier();
        cur ^= 1;
    }

    const int bb = biasPerBatch ? (m_blk >> 11) * Opad : 0;
    __syncthreads();   // done reading As/Bs; SH is reusable

    if (Y32) {
        // f32 path: store transposed to (B, 50, N): Y32[(b*50+o)*2048 + n], o < Olimit
#pragma unroll
        for (int oi = 0; oi < 4; ++oi) {
            const int og = o_blk + oh + oi * 16 + quad * 4;
            const f32x4 bv = *(const f32x4*)(bias + bb + og);
#pragma unroll
            for (int mi = 0; mi < MI; ++mi) {
                const int m = m_blk + mh + mi * 16 + r;
                const int bidx = m >> 11, n = m & 2047;
                f32x4 v = acc[oi][mi] + bv;
#pragma unroll
                for (int j = 0; j < 4; ++j) {
                    float x = v[j];
                    if (act == 1)      x = (x > 0.f) ? x : 0.0f;
                    else if (act == 2) x = (x > 0.f) ? x : 0.2f * x;
                    const int o = og + j;
                    if (o < Olimit)
                        Y32[((size_t)(bidx * 50 + o) << 11) + n] = x;
                }
            }
        }
        return;
    }

    // f16 path: stage [TM][128] tile in LDS (XOR-swizzled), then coalesced writeback
    _Float16* OT = SH;
#pragma unroll
    for (int oi = 0; oi < 4; ++oi) {
        const int ol = oh + oi * 16 + quad * 4;       // local o (0..127), 4-aligned
        const f32x4 bv = *(const f32x4*)(bias + bb + o_blk + ol);
#pragma unroll
        for (int mi = 0; mi < MI; ++mi) {
            const int row = mh + mi * 16 + r;         // local m
            f32x4 v = acc[oi][mi] + bv;
            if (Res) {
                f16x4 rr = *(const f16x4*)(Res + (size_t)(m_blk + row) * ldR + roff + o_blk + ol);
#pragma unroll
                for (int j = 0; j < 4; ++j) v[j] += (float)rr[j];
            }
            f16x4 ov;
#pragma unroll
            for (int j = 0; j < 4; ++j) {
                float x = v[j];
                if (act == 1)      x = (x > 0.f) ? x : 0.0f;
                else if (act == 2) x = (x > 0.f) ? x : 0.2f * x;
                ov[j] = (_Float16)x;
            }
            const int s = ((ol >> 2) ^ (row & 31)) << 2;   // swizzled 8B slot
            *(f16x4*)(OT + row * 128 + s) = ov;
        }
    }
    __syncthreads();
#pragma unroll
    for (int it2 = 0; it2 < TM / 16; ++it2) {
        const int row = it2 * 16 + (tid >> 4);
        const int c = tid & 15;                        // 8 f16 per lane, contiguous
        const int s0 = ((c * 2) ^ (row & 31)) << 2;
        const int s1 = ((c * 2 + 1) ^ (row & 31)) << 2;
        f16x4 a = *(const f16x4*)(OT + row * 128 + s0);
        f16x4 b2 = *(const f16x4*)(OT + row * 128 + s1);
        f16x8 o8;
        o8[0] = a[0]; o8[1] = a[1]; o8[2] = a[2]; o8[3] = a[3];
        o8[4] = b2[0]; o8[5] = b2[1]; o8[6] = b2[2]; o8[7] = b2[3];
        *(f16x8*)(Y + (size_t)(m_blk + row) * ldY + yoff + o_blk + c * 8) = o8;
    }
}

// ---------------- per-batch constant vector for Wc1 (absorbs reduce2 + label path) ----------------
__global__ __launch_bounds__(256) void cvec_kernel(
    const float* __restrict__ label, const float* __restrict__ Wl, const float* __restrict__ gl, const float* __restrict__ bl,
    const float* __restrict__ Wc1, const float* __restrict__ bc1, const float* __restrict__ gc1, const float* __restrict__ bb1,
    const float* __restrict__ pmax, const float* __restrict__ psum, float* __restrict__ cvec)
{
    __shared__ float v[2112];
    __shared__ float red[256];
    const int b = blockIdx.x, og = blockIdx.y, tid = threadIdx.x;
    for (int i = tid; i < 1024; i += 256) {
        float mx = -3.4e38f, sm = 0.f;
#pragma unroll
        for (int c = 0; c < 8; ++c) {
            mx = fmaxf(mx, pmax[((size_t)(b * 8 + c) << 10) + i]);
            sm += psum[((size_t)(b * 8 + c) << 10) + i];
        }
        v[i] = mx;
        v[1024 + i] = sm * (1.f / 2048.f);
    }
    if (tid < 64) {
        float s = 0.f;
        for (int i = 0; i < 16; ++i) s += Wl[tid * 16 + i] * label[b * 16 + i];
        s = gl[tid] * s + bl[tid];
        v[2048 + tid] = (s > 0.f) ? s : 0.2f * s;
    }
    __syncthreads();
    const int o = og * 64 + (tid >> 2), part = tid & 3;
    const float* wrow = Wc1 + (size_t)o * 3136 + 1024 + part * 528;
    float s = 0.f;
    for (int j = 0; j < 528; ++j) s += wrow[j] * v[part * 528 + j];
    red[tid] = s;
    __syncthreads();
    if (part == 0) {
        float tot = red[tid] + red[tid + 1] + red[tid + 2] + red[tid + 3];
        cvec[((size_t)b << 9) + o] = gc1[o] * (tot + bc1[o]) + bb1[o];
    }
}

// ---------------- launch ----------------
extern "C" void kernel_launch(void* const* d_in, const int* in_sizes, int n_in,
                              void* d_out, int out_size, void* d_ws, size_t ws_size,
                              hipStream_t stream)
{
    (void)in_sizes; (void)n_in; (void)out_size; (void)ws_size;
    const float* points = (const float*)d_in[0];
    const float* label  = (const float*)d_in[1];
    const float* We1 = (const float*)d_in[2];
    const float* ge1 = (const float*)d_in[3];
    const float* be1 = (const float*)d_in[4];
    const float* We2 = (const float*)d_in[5];
    const float* ge2 = (const float*)d_in[6];
    const float* be2 = (const float*)d_in[7];
    const float* W1  = (const float*)d_in[8];
    const float* g1  = (const float*)d_in[9];
    const float* b1  = (const float*)d_in[10];
    const float* W2  = (const float*)d_in[11];
    const float* g2  = (const float*)d_in[12];
    const float* b2  = (const float*)d_in[13];
    const float* Wf  = (const float*)d_in[14];
    const float* gf  = (const float*)d_in[15];
    const float* bfv = (const float*)d_in[16];
    const float* Wl  = (const float*)d_in[17];
    const float* gl  = (const float*)d_in[18];
    const float* bl  = (const float*)d_in[19];
    const float* Wc1 = (const float*)d_in[20];
    const float* bc1 = (const float*)d_in[21];
    const float* gc1 = (const float*)d_in[22];
    const float* bb1 = (const float*)d_in[23];
    const float* Wc2 = (const float*)d_in[24];
    const float* bc2 = (const float*)d_in[25];
    const float* gc2 = (const float*)d_in[26];
    const float* bb2 = (const float*)d_in[27];
    const float* Wc3 = (const float*)d_in[28];
    const float* bc3 = (const float*)d_in[29];

    char* ws = (char*)d_ws;
    _Float16* hT  = (_Float16*)(ws + OFF_HT);
    _Float16* tT  = (_Float16*)(ws + OFF_TT);
    _Float16* tT2 = (_Float16*)(ws + OFF_MT);
    _Float16* xct = (_Float16*)(ws + OFF_XCAT);
    _Float16* xf  = (_Float16*)(ws + OFF_XF);
    _Float16* c1  = (_Float16*)(ws + OFF_C1);
    _Float16* c2  = (_Float16*)(ws + OFF_C2);
    int*      idx = (int*)     (ws + OFF_IDX);
    _Float16* x0  = (_Float16*)(ws + OFF_X0);

    _Float16* wE1 = (_Float16*)(ws + OFF_WE1);
    _Float16* wE2 = (_Float16*)(ws + OFF_WE2);
    _Float16* w1f = (_Float16*)(ws + OFF_W1);
    _Float16* w2f = (_Float16*)(ws + OFF_W2);
    _Float16* wF  = (_Float16*)(ws + OFF_WF);
    _Float16* wC1 = (_Float16*)(ws + OFF_WC1);
    _Float16* wC2 = (_Float16*)(ws + OFF_WC2);
    _Float16* wC3 = (_Float16*)(ws + OFF_WC3);
    float* bC2 = (float*)(ws + OFF_BC2);
    float* bC3 = (float*)(ws + OFF_BC3);
    float* cv  = (float*)(ws + OFF_CVEC);
    float* pmx = (float*)(ws + OFF_PMAX);
    float* psm = (float*)(ws + OFF_PSUM);

    // prep (weights + biases + x0, one launch)
    fold_all_kernel<<<dim3(4834), 256, 0, stream>>>(We1, ge1, We2, ge2, W1, g1, W2, g2,
                                                    Wf, gf, Wc1, gc1, Wc2, gc2, Wc3,
                                                    gc2, bc2, bb2, bc3, points, ws);
    knn_kernel<<<dim3(BB, NN / 32), 256, 0, stream>>>(points, idx);

    // fused e1+e2: x0 -> (t in LDS) -> hT, both relu
    e12_kernel<<<dim3(512), 256, 0, stream>>>(wE1, wE2, x0, hT, be1, be2);

    // W1[0]: t = relu(bn(W1[0] h)) -> tT
    gemm_tile<64><<<dim3(512, 1), 256, 0, stream>>>(w1f, hT, tT, nullptr, b1, nullptr,
                                                    128, 128, 0, 128, 0, 128, 1, 0, 0, 0, 128);

    // pair 0 (gather fused): m=max16(tT) ; xcat0 = relu(W2[0] m + hT) ; t' = relu(W1[1] xcat0) -> tT2
    pairg_kernel<true><<<dim3(512), 256, 0, stream>>>(w2f, w1f + 16384, (const short*)tT, idx, hT,
                                                      xct, tT2, b2, b1 + 128, 128, 0, 0);

    // pair 1 (gather fused): m=max16(tT2) ; xcat1 = relu(W2[1] m + xcat0) ; t'' = relu(W1[2] xcat1) -> tT
    pairg_kernel<true><<<dim3(512), 256, 0, stream>>>(w2f + 16384, w1f + 2 * 16384, (const short*)tT2, idx, xct,
                                                      xct, tT, b2 + 128, b1 + 256, 384, 0, 128);

    // last (gather fused, no G2): m=max16(tT) ; xcat2 = relu(W2[2] m + xcat1)
    pairg_kernel<false><<<dim3(512), 256, 0, stream>>>(w2f + 2 * 16384, nullptr, (const short*)tT, idx, xct,
                                                       xct, nullptr, b2 + 256, nullptr, 384, 128, 256);

    // xf = leaky(bn(Wf xcat)) with fused pooling partials (max/sum per 256-row tile)
    gemm256<<<dim3(128, 4), 512, 0, stream>>>(wF, xct, xf, bfv, 384, 384, 1024, 1024, 2, 0, pmx, psm);

    // per-batch classifier constant (absorbs pooled stats + label path)
    cvec_kernel<<<dim3(BB, 8), 256, 0, stream>>>(label, Wl, gl, bl, Wc1, bc1, gc1, bb1, pmx, psm, cv);

    // c1 = relu(gc1*Wc1[:, :1024] xf + cvec[b])
    gemm256<<<dim3(128, 2), 512, 0, stream>>>(wC1, xf, c1, cv, 1024, 1024, 512, 512, 1, 1, nullptr, nullptr);

    // c2 = relu(bn(Wc2 c1 + bc2))
    gemm_tile<128><<<dim3(256, 2), 256, 0, stream>>>(wC2, c1, c2, nullptr, bC2, nullptr, 512, 512, 0, 256, 0, 256, 1, 0, 0, 0, 256);
    // c3 = Wc3 c2 + bc3 (no act), f32, stored transposed directly to (B,50,N) output
    gemm_tile<128><<<dim3(256, 1), 256, 0, stream>>>(wC3, c2, nullptr, (float*)d_out, bC3, nullptr, 256, 256, 0, 0, 0, 128, 0, 0, 0, 0, 50);
}